// Round 11
// baseline (200.529 us; speedup 1.0000x reference)
//
#include <hip/hip_runtime.h>
#include <hip/hip_bf16.h>

typedef __hip_bfloat16 bf16;
typedef __attribute__((ext_vector_type(8))) short bfrag;    // 8 x bf16 (16 B)
typedef __attribute__((ext_vector_type(4))) short s16x4;    // 4 x bf16 (8 B)
typedef __attribute__((ext_vector_type(4))) float f32x4;
typedef __attribute__((ext_vector_type(16))) float f32x16;

#define MFMA32(a,b,c) __builtin_amdgcn_mfma_f32_32x32x16_bf16((a),(b),(c),0,0,0)

__device__ __forceinline__ float b2f(bf16 x){ return __bfloat162float(x); }
__device__ __forceinline__ bf16 f2b(float x){ return __float2bfloat16(x); }
__device__ __forceinline__ float fexp2(float x){ return __builtin_amdgcn_exp2f(x); }

#define NN   3136   // 56*56 = 98 tiles of 32
#define NBH  8      // B * NH
#define MCH  448    // m chunk = 14 tiles of 32
#define LDP  40     // LDS row stride in elements (80 B; known-good)
#define LOG2E 1.44269504f

// ---------------- zero accumulators ----------------
__global__ __launch_bounds__(256) void k_zero(float* __restrict__ p, int n4)
{
    int i = blockIdx.x * 256 + threadIdx.x;
    if (i < n4) reinterpret_cast<f32x4*>(p)[i] = (f32x4){0.f, 0.f, 0.f, 0.f};
}

// ---------------- QKV 1x1 conv projections, LDS-tiled ----------------
// kt: [bh][N][32] (pre-scaled by log2e), qt: [bh][N][32], vt: [bh][32][N]
__global__ __launch_bounds__(256) void k_proj(
    const float* __restrict__ x,
    const float* __restrict__ wk, const float* __restrict__ bk,
    const float* __restrict__ wq, const float* __restrict__ bq,
    const float* __restrict__ wv, const float* __restrict__ bv,
    bf16* __restrict__ kt, bf16* __restrict__ qt, bf16* __restrict__ vt)
{
    __shared__ float xl[64 * 65];
    __shared__ float wl[96 * 64];
    __shared__ float bl[96];
    int n0 = blockIdx.x * 64;
    int b  = blockIdx.y;
    int z  = blockIdx.z;
    int tid = threadIdx.x;

    for (int i = tid; i < 4096; i += 256) {
        int c = i >> 6, n = i & 63;
        xl[c * 65 + n] = x[((size_t)b * 64 + c) * NN + n0 + n];
    }
    const float* wp_[3] = {wk, wq, wv};
    const float* bp_[3] = {bk, bq, bv};
    for (int i = tid; i < 96 * 64; i += 256) {
        int j = i >> 6, c = i & 63;
        int ch = z * 96 + j, pr = ch >> 7, oc = ch & 127;
        wl[i] = wp_[pr][oc * 64 + c];
    }
    if (tid < 96) { int ch = z * 96 + tid; bl[tid] = bp_[ch >> 7][ch & 127]; }
    __syncthreads();

    int n = tid & 63, jg = tid >> 6;
    for (int j0 = jg * 24; j0 < (jg + 1) * 24; j0 += 4) {
        float s0 = bl[j0+0], s1 = bl[j0+1], s2 = bl[j0+2], s3 = bl[j0+3];
        for (int c = 0; c < 64; ++c) {
            float xv = xl[c * 65 + n];
            s0 += xv * wl[(j0+0) * 64 + c];
            s1 += xv * wl[(j0+1) * 64 + c];
            s2 += xv * wl[(j0+2) * 64 + c];
            s3 += xv * wl[(j0+3) * 64 + c];
        }
        float sv[4] = {s0, s1, s2, s3};
        #pragma unroll
        for (int q = 0; q < 4; ++q) {
            int ch = z * 96 + j0 + q;
            int pr = ch >> 7, oc = ch & 127, h = oc >> 5, d = oc & 31;
            size_t bh = (size_t)b * 4 + h;
            if (pr == 0)      kt[(bh * NN + n0 + n) * 32 + d] = f2b(sv[q] * LOG2E);
            else if (pr == 1) qt[(bh * NN + n0 + n) * 32 + d] = f2b(sv[q]);
            else              vt[(bh * 32 + d) * NN + n0 + n] = f2b(sv[q]);
        }
    }
}

// ---------------- k_stats: den[m] += sum_{n-chunk} exp2(S'[n,m]) ----------------
// 4 waves own 4 m-tiles (Q in regs); block stages K n-tiles in LDS; split-n 7 chunks of 14 tiles.
__global__ __launch_bounds__(256) void k_stats(const bf16* __restrict__ kt,
                                               const bf16* __restrict__ qt,
                                               float* __restrict__ den)
{
    __shared__ __align__(16) bf16 Kb[2][32 * LDP];
    int tid = threadIdx.x, w = tid >> 6, lane = tid & 63;
    int l31 = lane & 31, lsel = lane >> 5;
    int bh = blockIdx.z;
    int mt = blockIdx.x * 4 + w;
    bool act = (mt < 98);
    int m0 = (act ? mt : 97) * 32;
    int ns = blockIdx.y * MCH;   // 14 tiles per chunk

    const bf16* qp = qt + ((size_t)bh * NN + m0 + l31) * 32 + lsel * 8;
    bfrag qb0 = *(const bfrag*)qp;
    bfrag qb1 = *(const bfrag*)(qp + 16);
    const bf16* kt_bh = kt + (size_t)bh * NN * 32;

    int sr = (tid & 127) >> 2, sc = (tid & 3) * 8;
    const bf16* sbase = kt_bh + (size_t)(ns + sr) * 32 + sc;
    bool st = (tid < 128);

    if (st) *(bfrag*)(&Kb[0][sr * LDP + sc]) = *(const bfrag*)sbase;
    __syncthreads();

    float dacc = 0.f;
    for (int t = 0; t < 14; ++t) {
        bfrag pre;
        bool hn = st && (t + 1 < 14);
        if (hn) pre = *(const bfrag*)(sbase + (size_t)(t + 1) * 1024);
        const bf16* kl = &Kb[t & 1][0];
        bfrag kb0 = *(const bfrag*)(kl + l31 * LDP + lsel * 8);
        bfrag kb1 = *(const bfrag*)(kl + l31 * LDP + 16 + lsel * 8);
        f32x16 s;
        #pragma unroll
        for (int r = 0; r < 16; ++r) s[r] = 0.f;
        s = MFMA32(kb0, qb0, s);
        s = MFMA32(kb1, qb1, s);
        float ps = 0.f;
        #pragma unroll
        for (int r = 0; r < 16; ++r) ps += fexp2(s[r]);
        dacc += ps;
        __syncthreads();
        if (hn) *(bfrag*)(&Kb[(t + 1) & 1][sr * LDP + sc]) = pre;
        __syncthreads();
    }
    dacc += __shfl_xor(dacc, 32);
    if (act && lane < 32) atomicAdd(&den[(size_t)bh * NN + m0 + l31], dacc);
}

__global__ __launch_bounds__(256) void k_recip(float* __restrict__ den)
{
    int i = blockIdx.x * 256 + threadIdx.x;
    if (i < NBH * NN) den[i] = 1.0f / den[i];
}

__global__ __launch_bounds__(256) void k_scalev(bf16* __restrict__ vt, const float* __restrict__ rden)
{
    int by = blockIdx.y;
    const float* rdp = rden + ((size_t)(by >> 5)) * NN;
    bf16* vp = vt + (size_t)by * NN;
    for (int m = blockIdx.x * MCH + threadIdx.x; m < blockIdx.x * MCH + MCH && m < NN; m += 256)
        vp[m] = f2b(b2f(vp[m]) * rdp[m]);
}

// ---------------- k_av: 2 n-tiles per wave; av[n,0:32] += P * V' ----------------
__global__ __launch_bounds__(256) void k_av(const bf16* __restrict__ kt,
    const bf16* __restrict__ qt, const bf16* __restrict__ vtp,
    float* __restrict__ av_acc)
{
    __shared__ __align__(16) bf16 Qb[2][32 * LDP];
    __shared__ __align__(16) bf16 Vb[2][32 * LDP];
    int tid = threadIdx.x, w = tid >> 6, lane = tid & 63;
    int l31 = lane & 31, lsel = lane >> 5;
    int bh = blockIdx.z;
    int nt0 = blockIdx.x * 8 + w * 2;
    int nt1 = nt0 + 1;
    bool act0 = (nt0 < 98), act1 = (nt1 < 98);
    int n0a = (act0 ? nt0 : 97) * 32;
    int n0b = (act1 ? nt1 : 97) * 32;
    int ms = blockIdx.y * MCH;

    const bf16* kpA = kt + ((size_t)bh * NN + n0a + l31) * 32 + lsel * 8;
    const bf16* kpB = kt + ((size_t)bh * NN + n0b + l31) * 32 + lsel * 8;
    bfrag kbA0 = *(const bfrag*)kpA;
    bfrag kbA1 = *(const bfrag*)(kpA + 16);
    bfrag kbB0 = *(const bfrag*)kpB;
    bfrag kbB1 = *(const bfrag*)(kpB + 16);
    const bf16* qt_bh = qt + (size_t)bh * NN * 32;
    const bf16* vt_bh = vtp + (size_t)bh * 32 * NN;

    int sr = (tid & 127) >> 2, sc = (tid & 3) * 8;
    bool isQ = (tid < 128);   // wave-uniform
    const bf16* sbase = isQ ? (qt_bh + (size_t)(ms + sr) * 32 + sc)
                            : (vt_bh + (size_t)sr * NN + ms + sc);
    size_t sstep = isQ ? 1024 : 32;
    bf16* ld0 = isQ ? &Qb[0][sr * LDP + sc] : &Vb[0][sr * LDP + sc];
    bf16* ld1 = isQ ? &Qb[1][sr * LDP + sc] : &Vb[1][sr * LDP + sc];

    *(bfrag*)ld0 = *(const bfrag*)sbase;
    __syncthreads();

    f32x16 accA, accB;
    #pragma unroll
    for (int r = 0; r < 16; ++r) { accA[r] = 0.f; accB[r] = 0.f; }

    for (int t = 0; t < 14; ++t) {
        bfrag pre;
        bool hn = (t + 1 < 14);
        if (hn) pre = *(const bfrag*)(sbase + (size_t)(t + 1) * sstep);
        const bf16* ql = &Qb[t & 1][0];
        const bf16* vl = &Vb[t & 1][0];
        bfrag qb0 = *(const bfrag*)(ql + l31 * LDP + lsel * 8);
        bfrag qb1 = *(const bfrag*)(ql + l31 * LDP + 16 + lsel * 8);
        const bf16* vrow = vl + l31 * LDP + lsel * 4;
        union { s16x4 h[2]; bfrag v; } vb0, vb1;
        vb0.h[0] = *(const s16x4*)(vrow);
        vb0.h[1] = *(const s16x4*)(vrow + 8);
        vb1.h[0] = *(const s16x4*)(vrow + 16);
        vb1.h[1] = *(const s16x4*)(vrow + 24);
        // tile A
        {
            f32x16 s;
            #pragma unroll
            for (int r = 0; r < 16; ++r) s[r] = 0.f;
            s = MFMA32(qb0, kbA0, s);
            s = MFMA32(qb1, kbA1, s);
            union { unsigned short us[8]; bfrag v; } pa0, pa1;
            #pragma unroll
            for (int i = 0; i < 8; ++i) {
                bf16 e0 = f2b(fexp2(s[i]));
                bf16 e1 = f2b(fexp2(s[8 + i]));
                pa0.us[i] = *(unsigned short*)&e0;
                pa1.us[i] = *(unsigned short*)&e1;
            }
            accA = MFMA32(pa0.v, vb0.v, accA);
            accA = MFMA32(pa1.v, vb1.v, accA);
        }
        // tile B
        {
            f32x16 s;
            #pragma unroll
            for (int r = 0; r < 16; ++r) s[r] = 0.f;
            s = MFMA32(qb0, kbB0, s);
            s = MFMA32(qb1, kbB1, s);
            union { unsigned short us[8]; bfrag v; } pa0, pa1;
            #pragma unroll
            for (int i = 0; i < 8; ++i) {
                bf16 e0 = f2b(fexp2(s[i]));
                bf16 e1 = f2b(fexp2(s[8 + i]));
                pa0.us[i] = *(unsigned short*)&e0;
                pa1.us[i] = *(unsigned short*)&e1;
            }
            accB = MFMA32(pa0.v, vb0.v, accB);
            accB = MFMA32(pa1.v, vb1.v, accB);
        }
        __syncthreads();
        if (hn) *(bfrag*)((t & 1) ? ld0 : ld1) = pre;
        __syncthreads();
    }
    if (act0) {
        float* dst = av_acc + ((size_t)bh * NN + n0a) * 32 + l31;
        #pragma unroll
        for (int r = 0; r < 16; ++r) {
            int nl = (r & 3) + 8 * (r >> 2) + 4 * lsel;
            atomicAdd(dst + (size_t)nl * 32, accA[r]);
        }
    }
    if (act1) {
        float* dst = av_acc + ((size_t)bh * NN + n0b) * 32 + l31;
        #pragma unroll
        for (int r = 0; r < 16; ++r) {
            int nl = (r & 3) + 8 * (r >> 2) + 4 * lsel;
            atomicAdd(dst + (size_t)nl * 32, accB[r]);
        }
    }
}

// ---------------- k_av2: 2 n-tiles per wave; av2[n,0:64] += P * awts' ----------------
__global__ __launch_bounds__(256) void k_av2(const bf16* __restrict__ kt,
    const bf16* __restrict__ qt, const bf16* __restrict__ awts,
    float* __restrict__ av2_acc)
{
    __shared__ __align__(16) bf16 Qb[2][32 * LDP];
    __shared__ __align__(16) bf16 Ab[2][64 * LDP];
    int tid = threadIdx.x, w = tid >> 6, lane = tid & 63;
    int l31 = lane & 31, lsel = lane >> 5;
    int bh = blockIdx.z;
    int nt0 = blockIdx.x * 8 + w * 2;
    int nt1 = nt0 + 1;
    bool act0 = (nt0 < 98), act1 = (nt1 < 98);
    int n0a = (act0 ? nt0 : 97) * 32;
    int n0b = (act1 ? nt1 : 97) * 32;
    int ms = blockIdx.y * MCH;

    const bf16* kpA = kt + ((size_t)bh * NN + n0a + l31) * 32 + lsel * 8;
    const bf16* kpB = kt + ((size_t)bh * NN + n0b + l31) * 32 + lsel * 8;
    bfrag kbA0 = *(const bfrag*)kpA;
    bfrag kbA1 = *(const bfrag*)(kpA + 16);
    bfrag kbB0 = *(const bfrag*)kpB;
    bfrag kbB1 = *(const bfrag*)(kpB + 16);
    const bf16* qt_bh = qt + (size_t)bh * NN * 32;
    const bf16* aw_bh = awts + (size_t)bh * 64 * NN;

    int ar = tid >> 2, acs = (tid & 3) * 8;
    int qr = (tid & 127) >> 2;
    const bf16* abase = aw_bh + (size_t)ar * NN + ms + acs;
    const bf16* qbase = qt_bh + (size_t)(ms + qr) * 32 + acs;
    bool st = (tid < 128);

    *(bfrag*)(&Ab[0][ar * LDP + acs]) = *(const bfrag*)abase;
    if (st) *(bfrag*)(&Qb[0][qr * LDP + acs]) = *(const bfrag*)qbase;
    __syncthreads();

    f32x16 accA0, accA1, accB0, accB1;
    #pragma unroll
    for (int r = 0; r < 16; ++r) { accA0[r] = 0.f; accA1[r] = 0.f; accB0[r] = 0.f; accB1[r] = 0.f; }

    for (int t = 0; t < 14; ++t) {
        bfrag preA, preQ;
        bool hn = (t + 1 < 14);
        if (hn) {
            preA = *(const bfrag*)(abase + (size_t)(t + 1) * 32);
            if (st) preQ = *(const bfrag*)(qbase + (size_t)(t + 1) * 1024);
        }
        const bf16* ql = &Qb[t & 1][0];
        const bf16* al = &Ab[t & 1][0];
        bfrag qb0 = *(const bfrag*)(ql + l31 * LDP + lsel * 8);
        bfrag qb1 = *(const bfrag*)(ql + l31 * LDP + 16 + lsel * 8);
        const bf16* a0 = al + l31 * LDP + lsel * 4;
        const bf16* a1 = al + (l31 + 32) * LDP + lsel * 4;
        union { s16x4 h[2]; bfrag v; } e00, e01, e10, e11;
        e00.h[0] = *(const s16x4*)(a0);
        e00.h[1] = *(const s16x4*)(a0 + 8);
        e01.h[0] = *(const s16x4*)(a0 + 16);
        e01.h[1] = *(const s16x4*)(a0 + 24);
        e10.h[0] = *(const s16x4*)(a1);
        e10.h[1] = *(const s16x4*)(a1 + 8);
        e11.h[0] = *(const s16x4*)(a1 + 16);
        e11.h[1] = *(const s16x4*)(a1 + 24);
        // tile A
        {
            f32x16 s;
            #pragma unroll
            for (int r = 0; r < 16; ++r) s[r] = 0.f;
            s = MFMA32(qb0, kbA0, s);
            s = MFMA32(qb1, kbA1, s);
            union { unsigned short us[8]; bfrag v; } pa0, pa1;
            #pragma unroll
            for (int i = 0; i < 8; ++i) {
                bf16 e0 = f2b(fexp2(s[i]));
                bf16 e1 = f2b(fexp2(s[8 + i]));
                pa0.us[i] = *(unsigned short*)&e0;
                pa1.us[i] = *(unsigned short*)&e1;
            }
            accA0 = MFMA32(pa0.v, e00.v, accA0);
            accA0 = MFMA32(pa1.v, e01.v, accA0);
            accA1 = MFMA32(pa0.v, e10.v, accA1);
            accA1 = MFMA32(pa1.v, e11.v, accA1);
        }
        // tile B
        {
            f32x16 s;
            #pragma unroll
            for (int r = 0; r < 16; ++r) s[r] = 0.f;
            s = MFMA32(qb0, kbB0, s);
            s = MFMA32(qb1, kbB1, s);
            union { unsigned short us[8]; bfrag v; } pa0, pa1;
            #pragma unroll
            for (int i = 0; i < 8; ++i) {
                bf16 e0 = f2b(fexp2(s[i]));
                bf16 e1 = f2b(fexp2(s[8 + i]));
                pa0.us[i] = *(unsigned short*)&e0;
                pa1.us[i] = *(unsigned short*)&e1;
            }
            accB0 = MFMA32(pa0.v, e00.v, accB0);
            accB0 = MFMA32(pa1.v, e01.v, accB0);
            accB1 = MFMA32(pa0.v, e10.v, accB1);
            accB1 = MFMA32(pa1.v, e11.v, accB1);
        }
        __syncthreads();
        if (hn) {
            *(bfrag*)(&Ab[(t + 1) & 1][ar * LDP + acs]) = preA;
            if (st) *(bfrag*)(&Qb[(t + 1) & 1][qr * LDP + acs]) = preQ;
        }
        __syncthreads();
    }
    if (act0) {
        float* dst = av2_acc + ((size_t)bh * NN + n0a) * 64 + l31;
        #pragma unroll
        for (int r = 0; r < 16; ++r) {
            int nl = (r & 3) + 8 * (r >> 2) + 4 * lsel;
            atomicAdd(dst + (size_t)nl * 64, accA0[r]);
            atomicAdd(dst + (size_t)nl * 64 + 32, accA1[r]);
        }
    }
    if (act1) {
        float* dst = av2_acc + ((size_t)bh * NN + n0b) * 64 + l31;
        #pragma unroll
        for (int r = 0; r < 16; ++r) {
            int nl = (r & 3) + 8 * (r >> 2) + 4 * lsel;
            atomicAdd(dst + (size_t)nl * 64, accB0[r]);
            atomicAdd(dst + (size_t)nl * 64 + 32, accB1[r]);
        }
    }
}

// ---------------- reduce1: awts' = relu(bn1(av @ w1^T + b1)) * rden -> [bh][64][N] bf16 ----------------
__global__ __launch_bounds__(256) void k_red1(const float* __restrict__ av_acc,
    const float* __restrict__ w1, const float* __restrict__ b1,
    const float* __restrict__ g1, const float* __restrict__ be1,
    const float* __restrict__ rm1, const float* __restrict__ rv1,
    const float* __restrict__ rds,
    bf16* __restrict__ awts)
{
    __shared__ float avl[64 * 33];
    __shared__ float w1l[64 * 33];
    __shared__ float sc[64], sh[64], bb[64];
    int n0 = blockIdx.x * 64, bh = blockIdx.y, h = bh & 3;
    int tid = threadIdx.x;
    const float* ap = av_acc + ((size_t)bh * NN + n0) * 32;
    for (int i = tid; i < 2048; i += 256) {
        avl[(i >> 5) * 33 + (i & 31)] = ap[i];
        w1l[(i >> 5) * 33 + (i & 31)] = w1[i];
    }
    if (tid < 64) {
        int ch = h * 64 + tid;
        float s = g1[ch] * rsqrtf(rv1[ch] + 1e-5f);
        sc[tid] = s; sh[tid] = be1[ch] - rm1[ch] * s; bb[tid] = b1[tid];
    }
    __syncthreads();
    int nb = (tid & 15) * 4, eb = (tid >> 4) * 4;
    float rsc[4];
    {
        const float* rp = rds + (size_t)bh * NN + n0 + nb;
        rsc[0] = rp[0]; rsc[1] = rp[1]; rsc[2] = rp[2]; rsc[3] = rp[3];
    }
    float s[4][4];
    #pragma unroll
    for (int i = 0; i < 4; ++i)
        #pragma unroll
        for (int j = 0; j < 4; ++j) s[i][j] = bb[eb + j];
    for (int d = 0; d < 32; ++d) {
        float a0 = avl[(nb+0)*33+d], a1 = avl[(nb+1)*33+d], a2 = avl[(nb+2)*33+d], a3 = avl[(nb+3)*33+d];
        float w0 = w1l[(eb+0)*33+d], w1v = w1l[(eb+1)*33+d], w2v = w1l[(eb+2)*33+d], w3 = w1l[(eb+3)*33+d];
        s[0][0]+=a0*w0; s[0][1]+=a0*w1v; s[0][2]+=a0*w2v; s[0][3]+=a0*w3;
        s[1][0]+=a1*w0; s[1][1]+=a1*w1v; s[1][2]+=a1*w2v; s[1][3]+=a1*w3;
        s[2][0]+=a2*w0; s[2][1]+=a2*w1v; s[2][2]+=a2*w2v; s[2][3]+=a2*w3;
        s[3][0]+=a3*w0; s[3][1]+=a3*w1v; s[3][2]+=a3*w2v; s[3][3]+=a3*w3;
    }
    #pragma unroll
    for (int j = 0; j < 4; ++j) {
        int e = eb + j;
        ushort4 pk;
        float v0 = fmaxf(s[0][j] * sc[e] + sh[e], 0.f) * rsc[0];
        float v1 = fmaxf(s[1][j] * sc[e] + sh[e], 0.f) * rsc[1];
        float v2 = fmaxf(s[2][j] * sc[e] + sh[e], 0.f) * rsc[2];
        float v3 = fmaxf(s[3][j] * sc[e] + sh[e], 0.f) * rsc[3];
        bf16 b0 = f2b(v0), b1b = f2b(v1), b2b = f2b(v2), b3 = f2b(v3);
        pk.x = *(unsigned short*)&b0; pk.y = *(unsigned short*)&b1b;
        pk.z = *(unsigned short*)&b2b; pk.w = *(unsigned short*)&b3;
        *reinterpret_cast<ushort4*>(awts + ((size_t)bh * 64 + e) * NN + n0 + nb) = pk;
    }
}

// ---------------- reduce2: avw2 = relu(bn2(av2 @ w2^T + b2)) -> y[b][256][N] bf16 ----------------
__global__ __launch_bounds__(256) void k_red2(const float* __restrict__ av2_acc,
    const float* __restrict__ w2, const float* __restrict__ b2,
    const float* __restrict__ g2, const float* __restrict__ be2,
    const float* __restrict__ rm2, const float* __restrict__ rv2,
    bf16* __restrict__ y)
{
    __shared__ float a2l[64 * 65];
    __shared__ float w2l[64 * 65];
    __shared__ float sc[64], sh[64], bb[64];
    int n0 = blockIdx.x * 64, bh = blockIdx.y, h = bh & 3, b = bh >> 2;
    int tid = threadIdx.x;
    const float* ap = av2_acc + ((size_t)bh * NN + n0) * 64;
    for (int i = tid; i < 4096; i += 256) {
        a2l[(i >> 6) * 65 + (i & 63)] = ap[i];
        w2l[(i >> 6) * 65 + (i & 63)] = w2[i];
    }
    if (tid < 64) {
        int ch = h * 64 + tid;
        float s = g2[ch] * rsqrtf(rv2[ch] + 1e-5f);
        sc[tid] = s; sh[tid] = be2[ch] - rm2[ch] * s; bb[tid] = b2[tid];
    }
    __syncthreads();
    int nb = (tid & 15) * 4, eb = (tid >> 4) * 4;
    float s[4][4];
    #pragma unroll
    for (int i = 0; i < 4; ++i)
        #pragma unroll
        for (int j = 0; j < 4; ++j) s[i][j] = bb[eb + j];
    for (int d = 0; d < 64; ++d) {
        float a0 = a2l[(nb+0)*65+d], a1 = a2l[(nb+1)*65+d], a2 = a2l[(nb+2)*65+d], a3 = a2l[(nb+3)*65+d];
        float w0 = w2l[(eb+0)*65+d], w1v = w2l[(eb+1)*65+d], w2v = w2l[(eb+2)*65+d], w3 = w2l[(eb+3)*65+d];
        s[0][0]+=a0*w0; s[0][1]+=a0*w1v; s[0][2]+=a0*w2v; s[0][3]+=a0*w3;
        s[1][0]+=a1*w0; s[1][1]+=a1*w1v; s[1][2]+=a1*w2v; s[1][3]+=a1*w3;
        s[2][0]+=a2*w0; s[2][1]+=a2*w1v; s[2][2]+=a2*w2v; s[2][3]+=a2*w3;
        s[3][0]+=a3*w0; s[3][1]+=a3*w1v; s[3][2]+=a3*w2v; s[3][3]+=a3*w3;
    }
    #pragma unroll
    for (int j = 0; j < 4; ++j) {
        int e = eb + j;
        ushort4 pk;
        float v0 = fmaxf(s[0][j] * sc[e] + sh[e], 0.f);
        float v1 = fmaxf(s[1][j] * sc[e] + sh[e], 0.f);
        float v2 = fmaxf(s[2][j] * sc[e] + sh[e], 0.f);
        float v3 = fmaxf(s[3][j] * sc[e] + sh[e], 0.f);
        bf16 b0 = f2b(v0), b1b = f2b(v1), b2b = f2b(v2), b3 = f2b(v3);
        pk.x = *(unsigned short*)&b0; pk.y = *(unsigned short*)&b1b;
        pk.z = *(unsigned short*)&b2b; pk.w = *(unsigned short*)&b3;
        *reinterpret_cast<ushort4*>(y + ((size_t)b * 256 + h * 64 + e) * NN + n0 + nb) = pk;
    }
}

// ---------------- final 1x1 conv (f32 out), 2 n per thread ----------------
__global__ __launch_bounds__(256) void k_final(const bf16* __restrict__ y,
    const float* __restrict__ wf, const float* __restrict__ bf_,
    float* __restrict__ out)
{
    int t = blockIdx.x * 256 + threadIdx.x;
    int n = t * 2;
    if (n >= NN) return;
    int o = blockIdx.y;
    int b = blockIdx.z;
    float s0 = bf_[o], s1 = s0;
    const bf16* yp = y + (size_t)b * 256 * NN + n;
    const float* wp = wf + o * 256;
    #pragma unroll 8
    for (int k = 0; k < 256; ++k) {
        unsigned u = *reinterpret_cast<const unsigned*>(yp + (size_t)k * NN);
        float lo = __uint_as_float(u << 16);
        float hi = __uint_as_float(u & 0xffff0000u);
        s0 += wp[k] * lo;
        s1 += wp[k] * hi;
    }
    float* op = out + ((size_t)b * 64 + o) * NN + n;
    op[0] = s0;
    op[1] = s1;
}

extern "C" void kernel_launch(void* const* d_in, const int* in_sizes, int n_in,
                              void* d_out, int out_size, void* d_ws, size_t ws_size,
                              hipStream_t stream)
{
    const float* x   = (const float*)d_in[0];
    const float* wk  = (const float*)d_in[1];
    const float* bk  = (const float*)d_in[2];
    const float* wq  = (const float*)d_in[3];
    const float* bq  = (const float*)d_in[4];
    const float* wv  = (const float*)d_in[5];
    const float* bv  = (const float*)d_in[6];
    const float* w1  = (const float*)d_in[7];
    const float* b1  = (const float*)d_in[8];
    const float* g1  = (const float*)d_in[9];
    const float* be1 = (const float*)d_in[10];
    const float* rm1 = (const float*)d_in[11];
    const float* rv1 = (const float*)d_in[12];
    const float* w2  = (const float*)d_in[13];
    const float* b2  = (const float*)d_in[14];
    const float* g2  = (const float*)d_in[15];
    const float* be2 = (const float*)d_in[16];
    const float* rm2 = (const float*)d_in[17];
    const float* rv2 = (const float*)d_in[18];
    const float* wf  = (const float*)d_in[19];
    const float* bff = (const float*)d_in[20];
    float* out = (float*)d_out;

    char* ws = (char*)d_ws;
    bf16* kt   = (bf16*)ws;
    bf16* qt   = kt + (size_t)NBH * NN * 32;
    bf16* vt   = qt + (size_t)NBH * NN * 32;
    bf16* awts = vt + (size_t)NBH * 32 * NN;
    bf16* y    = awts + (size_t)NBH * 64 * NN;
    float* den     = (float*)(y + (size_t)2 * 256 * NN);
    float* av_acc  = den + (size_t)NBH * NN;
    float* av2_acc = av_acc + (size_t)NBH * NN * 32;

    k_zero  <<<dim3(2377),     256, 0, stream>>>(den, 608384);
    k_proj  <<<dim3(49, 2, 4), 256, 0, stream>>>(x, wk, bk, wq, bq, wv, bv, kt, qt, vt);
    k_stats <<<dim3(25, 7, 8), 256, 0, stream>>>(kt, qt, den);
    k_recip <<<dim3(98),       256, 0, stream>>>(den);
    k_scalev<<<dim3(7, 256),   256, 0, stream>>>(vt, den);
    k_av    <<<dim3(13, 7, 8), 256, 0, stream>>>(kt, qt, vt, av_acc);
    k_red1  <<<dim3(49, 8),    256, 0, stream>>>(av_acc, w1, b1, g1, be1, rm1, rv1, den, awts);
    k_av2   <<<dim3(13, 7, 8), 256, 0, stream>>>(kt, qt, awts, av2_acc);
    k_red2  <<<dim3(49, 8),    256, 0, stream>>>(av2_acc, w2, b2, g2, be2, rm2, rv2, y);
    k_final <<<dim3(7, 64, 2), 256, 0, stream>>>(y, wf, bff, out);
}

// Round 12
// 197.017 us; speedup vs baseline: 1.0178x; 1.0178x over previous
//
#include <hip/hip_runtime.h>
#include <hip/hip_bf16.h>

typedef __hip_bfloat16 bf16;
typedef __attribute__((ext_vector_type(8))) short bfrag;    // 8 x bf16 (16 B)
typedef __attribute__((ext_vector_type(4))) short s16x4;    // 4 x bf16 (8 B)
typedef __attribute__((ext_vector_type(4))) float f32x4;
typedef __attribute__((ext_vector_type(16))) float f32x16;

#define MFMA32(a,b,c) __builtin_amdgcn_mfma_f32_32x32x16_bf16((a),(b),(c),0,0,0)

__device__ __forceinline__ float b2f(bf16 x){ return __bfloat162float(x); }
__device__ __forceinline__ bf16 f2b(float x){ return __float2bfloat16(x); }
__device__ __forceinline__ float fexp2(float x){ return __builtin_amdgcn_exp2f(x); }

#define NN   3136   // 56*56 = 98 tiles of 32
#define NBH  8      // B * NH
#define MCH  448    // m/n chunk = 14 tiles of 32
#define LDP  40     // LDS row stride in elements (80 B; known-good)
#define LOG2E 1.44269504f

// ---------------- zero accumulators ----------------
__global__ __launch_bounds__(256) void k_zero(float* __restrict__ p, int n4)
{
    int i = blockIdx.x * 256 + threadIdx.x;
    if (i < n4) reinterpret_cast<f32x4*>(p)[i] = (f32x4){0.f, 0.f, 0.f, 0.f};
}

// ---------------- QKV 1x1 conv projections, LDS-tiled ----------------
// kt: [bh][N][32] (pre-scaled by log2e), qt: [bh][N][32], vt: [bh][32][N]
__global__ __launch_bounds__(256) void k_proj(
    const float* __restrict__ x,
    const float* __restrict__ wk, const float* __restrict__ bk,
    const float* __restrict__ wq, const float* __restrict__ bq,
    const float* __restrict__ wv, const float* __restrict__ bv,
    bf16* __restrict__ kt, bf16* __restrict__ qt, bf16* __restrict__ vt)
{
    __shared__ float xl[64 * 65];
    __shared__ float wl[96 * 64];
    __shared__ float bl[96];
    int n0 = blockIdx.x * 64;
    int b  = blockIdx.y;
    int z  = blockIdx.z;
    int tid = threadIdx.x;

    for (int i = tid; i < 4096; i += 256) {
        int c = i >> 6, n = i & 63;
        xl[c * 65 + n] = x[((size_t)b * 64 + c) * NN + n0 + n];
    }
    const float* wp_[3] = {wk, wq, wv};
    const float* bp_[3] = {bk, bq, bv};
    for (int i = tid; i < 96 * 64; i += 256) {
        int j = i >> 6, c = i & 63;
        int ch = z * 96 + j, pr = ch >> 7, oc = ch & 127;
        wl[i] = wp_[pr][oc * 64 + c];
    }
    if (tid < 96) { int ch = z * 96 + tid; bl[tid] = bp_[ch >> 7][ch & 127]; }
    __syncthreads();

    int n = tid & 63, jg = tid >> 6;
    for (int j0 = jg * 24; j0 < (jg + 1) * 24; j0 += 4) {
        float s0 = bl[j0+0], s1 = bl[j0+1], s2 = bl[j0+2], s3 = bl[j0+3];
        for (int c = 0; c < 64; ++c) {
            float xv = xl[c * 65 + n];
            s0 += xv * wl[(j0+0) * 64 + c];
            s1 += xv * wl[(j0+1) * 64 + c];
            s2 += xv * wl[(j0+2) * 64 + c];
            s3 += xv * wl[(j0+3) * 64 + c];
        }
        float sv[4] = {s0, s1, s2, s3};
        #pragma unroll
        for (int q = 0; q < 4; ++q) {
            int ch = z * 96 + j0 + q;
            int pr = ch >> 7, oc = ch & 127, h = oc >> 5, d = oc & 31;
            size_t bh = (size_t)b * 4 + h;
            if (pr == 0)      kt[(bh * NN + n0 + n) * 32 + d] = f2b(sv[q] * LOG2E);
            else if (pr == 1) qt[(bh * NN + n0 + n) * 32 + d] = f2b(sv[q]);
            else              vt[(bh * 32 + d) * NN + n0 + n] = f2b(sv[q]);
        }
    }
}

// ---------------- k_stats: den[m] += sum_{n-chunk} exp2(S'[n,m]) ----------------
// 4 waves own 4 m-tiles (Q in regs); block stages K n-tiles in LDS; split-n 7 chunks; 1 barrier/step.
__global__ __launch_bounds__(256) void k_stats(const bf16* __restrict__ kt,
                                               const bf16* __restrict__ qt,
                                               float* __restrict__ den)
{
    __shared__ __align__(16) bf16 Kb[2][32 * LDP];
    int tid = threadIdx.x, w = tid >> 6, lane = tid & 63;
    int l31 = lane & 31, lsel = lane >> 5;
    int bh = blockIdx.z;
    int mt = blockIdx.x * 4 + w;
    bool act = (mt < 98);
    int m0 = (act ? mt : 97) * 32;
    int ns = blockIdx.y * MCH;   // 14 tiles per chunk

    const bf16* qp = qt + ((size_t)bh * NN + m0 + l31) * 32 + lsel * 8;
    bfrag qb0 = *(const bfrag*)qp;
    bfrag qb1 = *(const bfrag*)(qp + 16);
    const bf16* kt_bh = kt + (size_t)bh * NN * 32;

    int sr = (tid & 127) >> 2, sc = (tid & 3) * 8;
    const bf16* sbase = kt_bh + (size_t)(ns + sr) * 32 + sc;
    bool st = (tid < 128);

    if (st) *(bfrag*)(&Kb[0][sr * LDP + sc]) = *(const bfrag*)sbase;
    __syncthreads();

    float dacc = 0.f;
    for (int t = 0; t < 14; ++t) {
        bfrag pre;
        bool hn = st && (t + 1 < 14);
        if (hn) pre = *(const bfrag*)(sbase + (size_t)(t + 1) * 1024);
        const bf16* kl = &Kb[t & 1][0];
        bfrag kb0 = *(const bfrag*)(kl + l31 * LDP + lsel * 8);
        bfrag kb1 = *(const bfrag*)(kl + l31 * LDP + 16 + lsel * 8);
        f32x16 s;
        #pragma unroll
        for (int r = 0; r < 16; ++r) s[r] = 0.f;
        s = MFMA32(kb0, qb0, s);
        s = MFMA32(kb1, qb1, s);
        float ps = 0.f;
        #pragma unroll
        for (int r = 0; r < 16; ++r) ps += fexp2(s[r]);
        dacc += ps;
        // write next tile to the OTHER buffer; parity argument makes the
        // mid-step barrier redundant (end-of-step barrier orders both WAR and RAW)
        if (hn) *(bfrag*)(&Kb[(t + 1) & 1][sr * LDP + sc]) = pre;
        __syncthreads();
    }
    dacc += __shfl_xor(dacc, 32);
    if (act && lane < 32) atomicAdd(&den[(size_t)bh * NN + m0 + l31], dacc);
}

__global__ __launch_bounds__(256) void k_recip(float* __restrict__ den)
{
    int i = blockIdx.x * 256 + threadIdx.x;
    if (i < NBH * NN) den[i] = 1.0f / den[i];
}

__global__ __launch_bounds__(256) void k_scalev(bf16* __restrict__ vt, const float* __restrict__ rden)
{
    int by = blockIdx.y;
    const float* rdp = rden + ((size_t)(by >> 5)) * NN;
    bf16* vp = vt + (size_t)by * NN;
    for (int m = blockIdx.x * MCH + threadIdx.x; m < blockIdx.x * MCH + MCH && m < NN; m += 256)
        vp[m] = f2b(b2f(vp[m]) * rdp[m]);
}

// ---------------- k_av: av[n,0:32] += sum_m exp2(S'[n,m]) * V'[m,e] ----------------
// 4 waves own n-tiles (K in regs); block stages Q-tile + V-tile per m-step; 1 barrier/step.
__global__ __launch_bounds__(256) void k_av(const bf16* __restrict__ kt,
    const bf16* __restrict__ qt, const bf16* __restrict__ vtp,
    float* __restrict__ av_acc)
{
    __shared__ __align__(16) bf16 Qb[2][32 * LDP];
    __shared__ __align__(16) bf16 Vb[2][32 * LDP];
    int tid = threadIdx.x, w = tid >> 6, lane = tid & 63;
    int l31 = lane & 31, lsel = lane >> 5;
    int bh = blockIdx.z;
    int ntile = blockIdx.x * 4 + w;
    bool act = (ntile < 98);
    int n0 = (act ? ntile : 97) * 32;
    int ms = blockIdx.y * MCH;

    const bf16* kp = kt + ((size_t)bh * NN + n0 + l31) * 32 + lsel * 8;
    bfrag kb0 = *(const bfrag*)kp;
    bfrag kb1 = *(const bfrag*)(kp + 16);
    const bf16* qt_bh = qt + (size_t)bh * NN * 32;
    const bf16* vt_bh = vtp + (size_t)bh * 32 * NN;

    int sr = (tid & 127) >> 2, sc = (tid & 3) * 8;
    bool isQ = (tid < 128);   // wave-uniform: waves 0-1 stage Q, waves 2-3 stage V
    const bf16* sbase = isQ ? (qt_bh + (size_t)(ms + sr) * 32 + sc)
                            : (vt_bh + (size_t)sr * NN + ms + sc);
    size_t sstep = isQ ? 1024 : 32;
    bf16* ld0 = isQ ? &Qb[0][sr * LDP + sc] : &Vb[0][sr * LDP + sc];
    bf16* ld1 = isQ ? &Qb[1][sr * LDP + sc] : &Vb[1][sr * LDP + sc];

    *(bfrag*)ld0 = *(const bfrag*)sbase;
    __syncthreads();

    f32x16 acc;
    #pragma unroll
    for (int r = 0; r < 16; ++r) acc[r] = 0.f;

    for (int t = 0; t < 14; ++t) {
        bfrag pre;
        bool hn = (t + 1 < 14);
        if (hn) pre = *(const bfrag*)(sbase + (size_t)(t + 1) * sstep);
        const bf16* ql = &Qb[t & 1][0];
        const bf16* vl = &Vb[t & 1][0];
        bfrag qb0 = *(const bfrag*)(ql + l31 * LDP + lsel * 8);
        bfrag qb1 = *(const bfrag*)(ql + l31 * LDP + 16 + lsel * 8);
        f32x16 s;
        #pragma unroll
        for (int r = 0; r < 16; ++r) s[r] = 0.f;
        s = MFMA32(qb0, kb0, s);   // D[row=m][col=n=l31]  (S^T tile)
        s = MFMA32(qb1, kb1, s);
        union { unsigned short us[8]; bfrag v; } pa0, pa1;
        #pragma unroll
        for (int i = 0; i < 8; ++i) {
            bf16 e0 = f2b(fexp2(s[i]));
            bf16 e1 = f2b(fexp2(s[8 + i]));
            pa0.us[i] = *(unsigned short*)&e0;
            pa1.us[i] = *(unsigned short*)&e1;
        }
        const bf16* vrow = vl + l31 * LDP + lsel * 4;
        union { s16x4 h[2]; bfrag v; } vb0, vb1;
        vb0.h[0] = *(const s16x4*)(vrow);
        vb0.h[1] = *(const s16x4*)(vrow + 8);
        vb1.h[0] = *(const s16x4*)(vrow + 16);
        vb1.h[1] = *(const s16x4*)(vrow + 24);
        acc = MFMA32(pa0.v, vb0.v, acc);    // D[row=n][col=e]
        acc = MFMA32(pa1.v, vb1.v, acc);
        if (hn) *(bfrag*)((t & 1) ? ld0 : ld1) = pre;
        __syncthreads();
    }
    if (act) {
        float* dst = av_acc + ((size_t)bh * NN + n0) * 32 + l31;
        #pragma unroll
        for (int r = 0; r < 16; ++r) {
            int nl = (r & 3) + 8 * (r >> 2) + 4 * lsel;
            atomicAdd(dst + (size_t)nl * 32, acc[r]);
        }
    }
}

// ---------------- k_av2: av2[n,0:64] += sum_m exp2(S'[n,m]) * awts'[m,e] ----------------
__global__ __launch_bounds__(256) void k_av2(const bf16* __restrict__ kt,
    const bf16* __restrict__ qt, const bf16* __restrict__ awts,
    float* __restrict__ av2_acc)
{
    __shared__ __align__(16) bf16 Qb[2][32 * LDP];
    __shared__ __align__(16) bf16 Ab[2][64 * LDP];
    int tid = threadIdx.x, w = tid >> 6, lane = tid & 63;
    int l31 = lane & 31, lsel = lane >> 5;
    int bh = blockIdx.z;
    int ntile = blockIdx.x * 4 + w;
    bool act = (ntile < 98);
    int n0 = (act ? ntile : 97) * 32;
    int ms = blockIdx.y * MCH;

    const bf16* kp = kt + ((size_t)bh * NN + n0 + l31) * 32 + lsel * 8;
    bfrag kb0 = *(const bfrag*)kp;
    bfrag kb1 = *(const bfrag*)(kp + 16);
    const bf16* qt_bh = qt + (size_t)bh * NN * 32;
    const bf16* aw_bh = awts + (size_t)bh * 64 * NN;

    int ar = tid >> 2, acs = (tid & 3) * 8;
    int qr = (tid & 127) >> 2;
    const bf16* abase = aw_bh + (size_t)ar * NN + ms + acs;
    const bf16* qbase = qt_bh + (size_t)(ms + qr) * 32 + acs;
    bool st = (tid < 128);

    *(bfrag*)(&Ab[0][ar * LDP + acs]) = *(const bfrag*)abase;
    if (st) *(bfrag*)(&Qb[0][qr * LDP + acs]) = *(const bfrag*)qbase;
    __syncthreads();

    f32x16 acc0, acc1;
    #pragma unroll
    for (int r = 0; r < 16; ++r) { acc0[r] = 0.f; acc1[r] = 0.f; }

    for (int t = 0; t < 14; ++t) {
        bfrag preA, preQ;
        bool hn = (t + 1 < 14);
        if (hn) {
            preA = *(const bfrag*)(abase + (size_t)(t + 1) * 32);
            if (st) preQ = *(const bfrag*)(qbase + (size_t)(t + 1) * 1024);
        }
        const bf16* ql = &Qb[t & 1][0];
        const bf16* al = &Ab[t & 1][0];
        bfrag qb0 = *(const bfrag*)(ql + l31 * LDP + lsel * 8);
        bfrag qb1 = *(const bfrag*)(ql + l31 * LDP + 16 + lsel * 8);
        f32x16 s;
        #pragma unroll
        for (int r = 0; r < 16; ++r) s[r] = 0.f;
        s = MFMA32(qb0, kb0, s);
        s = MFMA32(qb1, kb1, s);
        union { unsigned short us[8]; bfrag v; } pa0, pa1;
        #pragma unroll
        for (int i = 0; i < 8; ++i) {
            bf16 e0 = f2b(fexp2(s[i]));
            bf16 e1 = f2b(fexp2(s[8 + i]));
            pa0.us[i] = *(unsigned short*)&e0;
            pa1.us[i] = *(unsigned short*)&e1;
        }
        const bf16* a0 = al + l31 * LDP + lsel * 4;
        const bf16* a1 = al + (l31 + 32) * LDP + lsel * 4;
        union { s16x4 h[2]; bfrag v; } e00, e01, e10, e11;
        e00.h[0] = *(const s16x4*)(a0);
        e00.h[1] = *(const s16x4*)(a0 + 8);
        e01.h[0] = *(const s16x4*)(a0 + 16);
        e01.h[1] = *(const s16x4*)(a0 + 24);
        e10.h[0] = *(const s16x4*)(a1);
        e10.h[1] = *(const s16x4*)(a1 + 8);
        e11.h[0] = *(const s16x4*)(a1 + 16);
        e11.h[1] = *(const s16x4*)(a1 + 24);
        acc0 = MFMA32(pa0.v, e00.v, acc0);
        acc0 = MFMA32(pa1.v, e01.v, acc0);
        acc1 = MFMA32(pa0.v, e10.v, acc1);
        acc1 = MFMA32(pa1.v, e11.v, acc1);
        if (hn) {
            *(bfrag*)(&Ab[(t + 1) & 1][ar * LDP + acs]) = preA;
            if (st) *(bfrag*)(&Qb[(t + 1) & 1][qr * LDP + acs]) = preQ;
        }
        __syncthreads();
    }
    if (act) {
        float* dst = av2_acc + ((size_t)bh * NN + n0) * 64 + l31;
        #pragma unroll
        for (int r = 0; r < 16; ++r) {
            int nl = (r & 3) + 8 * (r >> 2) + 4 * lsel;
            atomicAdd(dst + (size_t)nl * 64, acc0[r]);
            atomicAdd(dst + (size_t)nl * 64 + 32, acc1[r]);
        }
    }
}

// ---------------- reduce1: awts' = relu(bn1(av @ w1^T + b1)) * rden -> [bh][64][N] bf16 ----------------
__global__ __launch_bounds__(256) void k_red1(const float* __restrict__ av_acc,
    const float* __restrict__ w1, const float* __restrict__ b1,
    const float* __restrict__ g1, const float* __restrict__ be1,
    const float* __restrict__ rm1, const float* __restrict__ rv1,
    const float* __restrict__ rds,
    bf16* __restrict__ awts)
{
    __shared__ float avl[64 * 33];
    __shared__ float w1l[64 * 33];
    __shared__ float sc[64], sh[64], bb[64];
    int n0 = blockIdx.x * 64, bh = blockIdx.y, h = bh & 3;
    int tid = threadIdx.x;
    const float* ap = av_acc + ((size_t)bh * NN + n0) * 32;
    for (int i = tid; i < 2048; i += 256) {
        avl[(i >> 5) * 33 + (i & 31)] = ap[i];
        w1l[(i >> 5) * 33 + (i & 31)] = w1[i];
    }
    if (tid < 64) {
        int ch = h * 64 + tid;
        float s = g1[ch] * rsqrtf(rv1[ch] + 1e-5f);
        sc[tid] = s; sh[tid] = be1[ch] - rm1[ch] * s; bb[tid] = b1[tid];
    }
    __syncthreads();
    int nb = (tid & 15) * 4, eb = (tid >> 4) * 4;
    float rsc[4];
    {
        const float* rp = rds + (size_t)bh * NN + n0 + nb;
        rsc[0] = rp[0]; rsc[1] = rp[1]; rsc[2] = rp[2]; rsc[3] = rp[3];
    }
    float s[4][4];
    #pragma unroll
    for (int i = 0; i < 4; ++i)
        #pragma unroll
        for (int j = 0; j < 4; ++j) s[i][j] = bb[eb + j];
    for (int d = 0; d < 32; ++d) {
        float a0 = avl[(nb+0)*33+d], a1 = avl[(nb+1)*33+d], a2 = avl[(nb+2)*33+d], a3 = avl[(nb+3)*33+d];
        float w0 = w1l[(eb+0)*33+d], w1v = w1l[(eb+1)*33+d], w2v = w1l[(eb+2)*33+d], w3 = w1l[(eb+3)*33+d];
        s[0][0]+=a0*w0; s[0][1]+=a0*w1v; s[0][2]+=a0*w2v; s[0][3]+=a0*w3;
        s[1][0]+=a1*w0; s[1][1]+=a1*w1v; s[1][2]+=a1*w2v; s[1][3]+=a1*w3;
        s[2][0]+=a2*w0; s[2][1]+=a2*w1v; s[2][2]+=a2*w2v; s[2][3]+=a2*w3;
        s[3][0]+=a3*w0; s[3][1]+=a3*w1v; s[3][2]+=a3*w2v; s[3][3]+=a3*w3;
    }
    #pragma unroll
    for (int j = 0; j < 4; ++j) {
        int e = eb + j;
        ushort4 pk;
        float v0 = fmaxf(s[0][j] * sc[e] + sh[e], 0.f) * rsc[0];
        float v1 = fmaxf(s[1][j] * sc[e] + sh[e], 0.f) * rsc[1];
        float v2 = fmaxf(s[2][j] * sc[e] + sh[e], 0.f) * rsc[2];
        float v3 = fmaxf(s[3][j] * sc[e] + sh[e], 0.f) * rsc[3];
        bf16 b0 = f2b(v0), b1b = f2b(v1), b2b = f2b(v2), b3 = f2b(v3);
        pk.x = *(unsigned short*)&b0; pk.y = *(unsigned short*)&b1b;
        pk.z = *(unsigned short*)&b2b; pk.w = *(unsigned short*)&b3;
        *reinterpret_cast<ushort4*>(awts + ((size_t)bh * 64 + e) * NN + n0 + nb) = pk;
    }
}

// ---------------- reduce2: avw2 = relu(bn2(av2 @ w2^T + b2)) -> y[b][256][N] bf16 ----------------
__global__ __launch_bounds__(256) void k_red2(const float* __restrict__ av2_acc,
    const float* __restrict__ w2, const float* __restrict__ b2,
    const float* __restrict__ g2, const float* __restrict__ be2,
    const float* __restrict__ rm2, const float* __restrict__ rv2,
    bf16* __restrict__ y)
{
    __shared__ float a2l[64 * 65];
    __shared__ float w2l[64 * 65];
    __shared__ float sc[64], sh[64], bb[64];
    int n0 = blockIdx.x * 64, bh = blockIdx.y, h = bh & 3, b = bh >> 2;
    int tid = threadIdx.x;
    const float* ap = av2_acc + ((size_t)bh * NN + n0) * 64;
    for (int i = tid; i < 4096; i += 256) {
        a2l[(i >> 6) * 65 + (i & 63)] = ap[i];
        w2l[(i >> 6) * 65 + (i & 63)] = w2[i];
    }
    if (tid < 64) {
        int ch = h * 64 + tid;
        float s = g2[ch] * rsqrtf(rv2[ch] + 1e-5f);
        sc[tid] = s; sh[tid] = be2[ch] - rm2[ch] * s; bb[tid] = b2[tid];
    }
    __syncthreads();
    int nb = (tid & 15) * 4, eb = (tid >> 4) * 4;
    float s[4][4];
    #pragma unroll
    for (int i = 0; i < 4; ++i)
        #pragma unroll
        for (int j = 0; j < 4; ++j) s[i][j] = bb[eb + j];
    for (int d = 0; d < 64; ++d) {
        float a0 = a2l[(nb+0)*65+d], a1 = a2l[(nb+1)*65+d], a2 = a2l[(nb+2)*65+d], a3 = a2l[(nb+3)*65+d];
        float w0 = w2l[(eb+0)*65+d], w1v = w2l[(eb+1)*65+d], w2v = w2l[(eb+2)*65+d], w3 = w2l[(eb+3)*65+d];
        s[0][0]+=a0*w0; s[0][1]+=a0*w1v; s[0][2]+=a0*w2v; s[0][3]+=a0*w3;
        s[1][0]+=a1*w0; s[1][1]+=a1*w1v; s[1][2]+=a1*w2v; s[1][3]+=a1*w3;
        s[2][0]+=a2*w0; s[2][1]+=a2*w1v; s[2][2]+=a2*w2v; s[2][3]+=a2*w3;
        s[3][0]+=a3*w0; s[3][1]+=a3*w1v; s[3][2]+=a3*w2v; s[3][3]+=a3*w3;
    }
    #pragma unroll
    for (int j = 0; j < 4; ++j) {
        int e = eb + j;
        ushort4 pk;
        float v0 = fmaxf(s[0][j] * sc[e] + sh[e], 0.f);
        float v1 = fmaxf(s[1][j] * sc[e] + sh[e], 0.f);
        float v2 = fmaxf(s[2][j] * sc[e] + sh[e], 0.f);
        float v3 = fmaxf(s[3][j] * sc[e] + sh[e], 0.f);
        bf16 b0 = f2b(v0), b1b = f2b(v1), b2b = f2b(v2), b3 = f2b(v3);
        pk.x = *(unsigned short*)&b0; pk.y = *(unsigned short*)&b1b;
        pk.z = *(unsigned short*)&b2b; pk.w = *(unsigned short*)&b3;
        *reinterpret_cast<ushort4*>(y + ((size_t)b * 256 + h * 64 + e) * NN + n0 + nb) = pk;
    }
}

// ---------------- final 1x1 conv (f32 out), 2 n per thread ----------------
__global__ __launch_bounds__(256) void k_final(const bf16* __restrict__ y,
    const float* __restrict__ wf, const float* __restrict__ bf_,
    float* __restrict__ out)
{
    int t = blockIdx.x * 256 + threadIdx.x;
    int n = t * 2;
    if (n >= NN) return;
    int o = blockIdx.y;
    int b = blockIdx.z;
    float s0 = bf_[o], s1 = s0;
    const bf16* yp = y + (size_t)b * 256 * NN + n;
    const float* wp = wf + o * 256;
    #pragma unroll 8
    for (int k = 0; k < 256; ++k) {
        unsigned u = *reinterpret_cast<const unsigned*>(yp + (size_t)k * NN);
        float lo = __uint_as_float(u << 16);
        float hi = __uint_as_float(u & 0xffff0000u);
        s0 += wp[k] * lo;
        s1 += wp[k] * hi;
    }
    float* op = out + ((size_t)b * 64 + o) * NN + n;
    op[0] = s0;
    op[1] = s1;
}

extern "C" void kernel_launch(void* const* d_in, const int* in_sizes, int n_in,
                              void* d_out, int out_size, void* d_ws, size_t ws_size,
                              hipStream_t stream)
{
    const float* x   = (const float*)d_in[0];
    const float* wk  = (const float*)d_in[1];
    const float* bk  = (const float*)d_in[2];
    const float* wq  = (const float*)d_in[3];
    const float* bq  = (const float*)d_in[4];
    const float* wv  = (const float*)d_in[5];
    const float* bv  = (const float*)d_in[6];
    const float* w1  = (const float*)d_in[7];
    const float* b1  = (const float*)d_in[8];
    const float* g1  = (const float*)d_in[9];
    const float* be1 = (const float*)d_in[10];
    const float* rm1 = (const float*)d_in[11];
    const float* rv1 = (const float*)d_in[12];
    const float* w2  = (const float*)d_in[13];
    const float* b2  = (const float*)d_in[14];
    const float* g2  = (const float*)d_in[15];
    const float* be2 = (const float*)d_in[16];
    const float* rm2 = (const float*)d_in[17];
    const float* rv2 = (const float*)d_in[18];
    const float* wf  = (const float*)d_in[19];
    const float* bff = (const float*)d_in[20];
    float* out = (float*)d_out;

    char* ws = (char*)d_ws;
    bf16* kt   = (bf16*)ws;
    bf16* qt   = kt + (size_t)NBH * NN * 32;
    bf16* vt   = qt + (size_t)NBH * NN * 32;
    bf16* awts = vt + (size_t)NBH * 32 * NN;
    bf16* y    = awts + (size_t)NBH * 64 * NN;
    float* den     = (float*)(y + (size_t)2 * 256 * NN);
    float* av_acc  = den + (size_t)NBH * NN;
    float* av2_acc = av_acc + (size_t)NBH * NN * 32;

    k_zero  <<<dim3(2377),     256, 0, stream>>>(den, 608384);
    k_proj  <<<dim3(49, 2, 4), 256, 0, stream>>>(x, wk, bk, wq, bq, wv, bv, kt, qt, vt);
    k_stats <<<dim3(25, 7, 8), 256, 0, stream>>>(kt, qt, den);
    k_recip <<<dim3(98),       256, 0, stream>>>(den);
    k_scalev<<<dim3(7, 256),   256, 0, stream>>>(vt, den);
    k_av    <<<dim3(25, 7, 8), 256, 0, stream>>>(kt, qt, vt, av_acc);
    k_red1  <<<dim3(49, 8),    256, 0, stream>>>(av_acc, w1, b1, g1, be1, rm1, rv1, den, awts);
    k_av2   <<<dim3(25, 7, 8), 256, 0, stream>>>(kt, qt, awts, av2_acc);
    k_red2  <<<dim3(49, 8),    256, 0, stream>>>(av2_acc, w2, b2, g2, be2, rm2, rv2, y);
    k_final <<<dim3(7, 64, 2), 256, 0, stream>>>(y, wf, bff, out);
}

// Round 13
// 195.812 us; speedup vs baseline: 1.0241x; 1.0062x over previous
//
#include <hip/hip_runtime.h>
#include <hip/hip_bf16.h>

typedef __hip_bfloat16 bf16;
typedef __attribute__((ext_vector_type(8))) short bfrag;    // 8 x bf16 (16 B)
typedef __attribute__((ext_vector_type(4))) short s16x4;    // 4 x bf16 (8 B)
typedef __attribute__((ext_vector_type(4))) float f32x4;
typedef __attribute__((ext_vector_type(16))) float f32x16;

#define MFMA32(a,b,c) __builtin_amdgcn_mfma_f32_32x32x16_bf16((a),(b),(c),0,0,0)

__device__ __forceinline__ float b2f(bf16 x){ return __bfloat162float(x); }
__device__ __forceinline__ bf16 f2b(float x){ return __float2bfloat16(x); }
__device__ __forceinline__ float fexp2(float x){ return __builtin_amdgcn_exp2f(x); }

#define NN   3136   // 56*56 = 98 tiles of 32
#define NBH  8      // B * NH
#define MCH  448    // m/n chunk = 14 tiles of 32
#define LDP  36     // LDS row stride (72 B: bank=(r*18)%32 period 16 -> 2-way = free); 8B LDS ops only
#define LOG2E 1.44269504f

// ---------------- zero accumulators ----------------
__global__ __launch_bounds__(256) void k_zero(float* __restrict__ p, int n4)
{
    int i = blockIdx.x * 256 + threadIdx.x;
    if (i < n4) reinterpret_cast<f32x4*>(p)[i] = (f32x4){0.f, 0.f, 0.f, 0.f};
}

// ---------------- QKV 1x1 conv projections, LDS-tiled ----------------
// kt: [bh][N][32] (pre-scaled by log2e), qt: [bh][N][32], vt: [bh][32][N]
__global__ __launch_bounds__(256) void k_proj(
    const float* __restrict__ x,
    const float* __restrict__ wk, const float* __restrict__ bk,
    const float* __restrict__ wq, const float* __restrict__ bq,
    const float* __restrict__ wv, const float* __restrict__ bv,
    bf16* __restrict__ kt, bf16* __restrict__ qt, bf16* __restrict__ vt)
{
    __shared__ float xl[64 * 65];
    __shared__ float wl[96 * 64];
    __shared__ float bl[96];
    int n0 = blockIdx.x * 64;
    int b  = blockIdx.y;
    int z  = blockIdx.z;
    int tid = threadIdx.x;

    for (int i = tid; i < 4096; i += 256) {
        int c = i >> 6, n = i & 63;
        xl[c * 65 + n] = x[((size_t)b * 64 + c) * NN + n0 + n];
    }
    const float* wp_[3] = {wk, wq, wv};
    const float* bp_[3] = {bk, bq, bv};
    for (int i = tid; i < 96 * 64; i += 256) {
        int j = i >> 6, c = i & 63;
        int ch = z * 96 + j, pr = ch >> 7, oc = ch & 127;
        wl[i] = wp_[pr][oc * 64 + c];
    }
    if (tid < 96) { int ch = z * 96 + tid; bl[tid] = bp_[ch >> 7][ch & 127]; }
    __syncthreads();

    int n = tid & 63, jg = tid >> 6;
    for (int j0 = jg * 24; j0 < (jg + 1) * 24; j0 += 4) {
        float s0 = bl[j0+0], s1 = bl[j0+1], s2 = bl[j0+2], s3 = bl[j0+3];
        for (int c = 0; c < 64; ++c) {
            float xv = xl[c * 65 + n];
            s0 += xv * wl[(j0+0) * 64 + c];
            s1 += xv * wl[(j0+1) * 64 + c];
            s2 += xv * wl[(j0+2) * 64 + c];
            s3 += xv * wl[(j0+3) * 64 + c];
        }
        float sv[4] = {s0, s1, s2, s3};
        #pragma unroll
        for (int q = 0; q < 4; ++q) {
            int ch = z * 96 + j0 + q;
            int pr = ch >> 7, oc = ch & 127, h = oc >> 5, d = oc & 31;
            size_t bh = (size_t)b * 4 + h;
            if (pr == 0)      kt[(bh * NN + n0 + n) * 32 + d] = f2b(sv[q] * LOG2E);
            else if (pr == 1) qt[(bh * NN + n0 + n) * 32 + d] = f2b(sv[q]);
            else              vt[(bh * 32 + d) * NN + n0 + n] = f2b(sv[q]);
        }
    }
}

// ---------------- k_stats: den[m] += sum_{n-chunk} exp2(S'[n,m]) ----------------
// 4 waves own 4 m-tiles (Q in regs); block stages K n-tiles in LDS; split-n 7 chunks; 1 barrier/step.
__global__ __launch_bounds__(256) void k_stats(const bf16* __restrict__ kt,
                                               const bf16* __restrict__ qt,
                                               float* __restrict__ den)
{
    __shared__ __align__(16) bf16 Kb[2][32 * LDP];
    int tid = threadIdx.x, w = tid >> 6, lane = tid & 63;
    int l31 = lane & 31, lsel = lane >> 5;
    int bh = blockIdx.z;
    int mt = blockIdx.x * 4 + w;
    bool act = (mt < 98);
    int m0 = (act ? mt : 97) * 32;
    int ns = blockIdx.y * MCH;   // 14 tiles per chunk

    const bf16* qp = qt + ((size_t)bh * NN + m0 + l31) * 32 + lsel * 8;
    bfrag qb0 = *(const bfrag*)qp;
    bfrag qb1 = *(const bfrag*)(qp + 16);
    const bf16* kt_bh = kt + (size_t)bh * NN * 32;

    int sr = (tid & 127) >> 2, sc = (tid & 3) * 8;
    const bf16* sbase = kt_bh + (size_t)(ns + sr) * 32 + sc;
    bool st = (tid < 128);
    int soff = sr * LDP + sc;

    if (st) {
        union { bfrag v; s16x4 h[2]; } u; u.v = *(const bfrag*)sbase;
        *(s16x4*)(&Kb[0][soff])     = u.h[0];
        *(s16x4*)(&Kb[0][soff + 4]) = u.h[1];
    }
    __syncthreads();

    float dacc = 0.f;
    for (int t = 0; t < 14; ++t) {
        bfrag pre;
        bool hn = st && (t + 1 < 14);
        if (hn) pre = *(const bfrag*)(sbase + (size_t)(t + 1) * 1024);
        const bf16* kl = &Kb[t & 1][0];
        int ko = l31 * LDP + lsel * 8;
        union { s16x4 h[2]; bfrag v; } k0, k1;
        k0.h[0] = *(const s16x4*)(kl + ko);
        k0.h[1] = *(const s16x4*)(kl + ko + 4);
        k1.h[0] = *(const s16x4*)(kl + ko + 16);
        k1.h[1] = *(const s16x4*)(kl + ko + 20);
        f32x16 s;
        #pragma unroll
        for (int r = 0; r < 16; ++r) s[r] = 0.f;
        s = MFMA32(k0.v, qb0, s);
        s = MFMA32(k1.v, qb1, s);
        float ps = 0.f;
        #pragma unroll
        for (int r = 0; r < 16; ++r) ps += fexp2(s[r]);
        dacc += ps;
        if (hn) {
            union { bfrag v; s16x4 h[2]; } u; u.v = pre;
            *(s16x4*)(&Kb[(t + 1) & 1][soff])     = u.h[0];
            *(s16x4*)(&Kb[(t + 1) & 1][soff + 4]) = u.h[1];
        }
        __syncthreads();
    }
    dacc += __shfl_xor(dacc, 32);
    if (act && lane < 32) atomicAdd(&den[(size_t)bh * NN + m0 + l31], dacc);
}

__global__ __launch_bounds__(256) void k_recip(float* __restrict__ den)
{
    int i = blockIdx.x * 256 + threadIdx.x;
    if (i < NBH * NN) den[i] = 1.0f / den[i];
}

__global__ __launch_bounds__(256) void k_scalev(bf16* __restrict__ vt, const float* __restrict__ rden)
{
    int by = blockIdx.y;
    const float* rdp = rden + ((size_t)(by >> 5)) * NN;
    bf16* vp = vt + (size_t)by * NN;
    for (int m = blockIdx.x * MCH + threadIdx.x; m < blockIdx.x * MCH + MCH && m < NN; m += 256)
        vp[m] = f2b(b2f(vp[m]) * rdp[m]);
}

// ---------------- k_av: av[n,0:32] += sum_m exp2(S'[n,m]) * V'[m,e] ----------------
// 4 waves own n-tiles (K in regs); block stages Q-tile + V-tile per m-step; 1 barrier/step.
__global__ __launch_bounds__(256) void k_av(const bf16* __restrict__ kt,
    const bf16* __restrict__ qt, const bf16* __restrict__ vtp,
    float* __restrict__ av_acc)
{
    __shared__ __align__(16) bf16 Qb[2][32 * LDP];
    __shared__ __align__(16) bf16 Vb[2][32 * LDP];
    int tid = threadIdx.x, w = tid >> 6, lane = tid & 63;
    int l31 = lane & 31, lsel = lane >> 5;
    int bh = blockIdx.z;
    int ntile = blockIdx.x * 4 + w;
    bool act = (ntile < 98);
    int n0 = (act ? ntile : 97) * 32;
    int ms = blockIdx.y * MCH;

    const bf16* kp = kt + ((size_t)bh * NN + n0 + l31) * 32 + lsel * 8;
    bfrag kb0 = *(const bfrag*)kp;
    bfrag kb1 = *(const bfrag*)(kp + 16);
    const bf16* qt_bh = qt + (size_t)bh * NN * 32;
    const bf16* vt_bh = vtp + (size_t)bh * 32 * NN;

    int sr = (tid & 127) >> 2, sc = (tid & 3) * 8;
    bool isQ = (tid < 128);   // wave-uniform: waves 0-1 stage Q, waves 2-3 stage V
    const bf16* sbase = isQ ? (qt_bh + (size_t)(ms + sr) * 32 + sc)
                            : (vt_bh + (size_t)sr * NN + ms + sc);
    size_t sstep = isQ ? 1024 : 32;
    int soff = sr * LDP + sc;
    bf16* ld0 = isQ ? &Qb[0][soff] : &Vb[0][soff];
    bf16* ld1 = isQ ? &Qb[1][soff] : &Vb[1][soff];

    {
        union { bfrag v; s16x4 h[2]; } u; u.v = *(const bfrag*)sbase;
        *(s16x4*)(ld0)     = u.h[0];
        *(s16x4*)(ld0 + 4) = u.h[1];
    }
    __syncthreads();

    f32x16 acc;
    #pragma unroll
    for (int r = 0; r < 16; ++r) acc[r] = 0.f;

    for (int t = 0; t < 14; ++t) {
        bfrag pre;
        bool hn = (t + 1 < 14);
        if (hn) pre = *(const bfrag*)(sbase + (size_t)(t + 1) * sstep);
        const bf16* ql = &Qb[t & 1][0];
        const bf16* vl = &Vb[t & 1][0];
        int qo = l31 * LDP + lsel * 8;
        union { s16x4 h[2]; bfrag v; } q0, q1;
        q0.h[0] = *(const s16x4*)(ql + qo);
        q0.h[1] = *(const s16x4*)(ql + qo + 4);
        q1.h[0] = *(const s16x4*)(ql + qo + 16);
        q1.h[1] = *(const s16x4*)(ql + qo + 20);
        f32x16 s;
        #pragma unroll
        for (int r = 0; r < 16; ++r) s[r] = 0.f;
        s = MFMA32(q0.v, kb0, s);   // D[row=m][col=n=l31]  (S^T tile)
        s = MFMA32(q1.v, kb1, s);
        union { unsigned short us[8]; bfrag v; } pa0, pa1;
        #pragma unroll
        for (int i = 0; i < 8; ++i) {
            bf16 e0 = f2b(fexp2(s[i]));
            bf16 e1 = f2b(fexp2(s[8 + i]));
            pa0.us[i] = *(unsigned short*)&e0;
            pa1.us[i] = *(unsigned short*)&e1;
        }
        const bf16* vrow = vl + l31 * LDP + lsel * 4;
        union { s16x4 h[2]; bfrag v; } vb0, vb1;
        vb0.h[0] = *(const s16x4*)(vrow);
        vb0.h[1] = *(const s16x4*)(vrow + 8);
        vb1.h[0] = *(const s16x4*)(vrow + 16);
        vb1.h[1] = *(const s16x4*)(vrow + 24);
        acc = MFMA32(pa0.v, vb0.v, acc);    // D[row=n][col=e]
        acc = MFMA32(pa1.v, vb1.v, acc);
        if (hn) {
            union { bfrag v; s16x4 h[2]; } u; u.v = pre;
            bf16* d = (t & 1) ? ld0 : ld1;
            *(s16x4*)(d)     = u.h[0];
            *(s16x4*)(d + 4) = u.h[1];
        }
        __syncthreads();
    }
    if (act) {
        float* dst = av_acc + ((size_t)bh * NN + n0) * 32 + l31;
        #pragma unroll
        for (int r = 0; r < 16; ++r) {
            int nl = (r & 3) + 8 * (r >> 2) + 4 * lsel;
            atomicAdd(dst + (size_t)nl * 32, acc[r]);
        }
    }
}

// ---------------- k_av2: av2[n,0:64] += sum_m exp2(S'[n,m]) * awts'[m,e] ----------------
__global__ __launch_bounds__(256) void k_av2(const bf16* __restrict__ kt,
    const bf16* __restrict__ qt, const bf16* __restrict__ awts,
    float* __restrict__ av2_acc)
{
    __shared__ __align__(16) bf16 Qb[2][32 * LDP];
    __shared__ __align__(16) bf16 Ab[2][64 * LDP];
    int tid = threadIdx.x, w = tid >> 6, lane = tid & 63;
    int l31 = lane & 31, lsel = lane >> 5;
    int bh = blockIdx.z;
    int ntile = blockIdx.x * 4 + w;
    bool act = (ntile < 98);
    int n0 = (act ? ntile : 97) * 32;
    int ms = blockIdx.y * MCH;

    const bf16* kp = kt + ((size_t)bh * NN + n0 + l31) * 32 + lsel * 8;
    bfrag kb0 = *(const bfrag*)kp;
    bfrag kb1 = *(const bfrag*)(kp + 16);
    const bf16* qt_bh = qt + (size_t)bh * NN * 32;
    const bf16* aw_bh = awts + (size_t)bh * 64 * NN;

    int ar = tid >> 2, acs = (tid & 3) * 8;
    int qr = (tid & 127) >> 2;
    const bf16* abase = aw_bh + (size_t)ar * NN + ms + acs;
    const bf16* qbase = qt_bh + (size_t)(ms + qr) * 32 + acs;
    bool st = (tid < 128);
    int aoff = ar * LDP + acs, qoff = qr * LDP + acs;

    {
        union { bfrag v; s16x4 h[2]; } u; u.v = *(const bfrag*)abase;
        *(s16x4*)(&Ab[0][aoff])     = u.h[0];
        *(s16x4*)(&Ab[0][aoff + 4]) = u.h[1];
        if (st) {
            union { bfrag v; s16x4 h[2]; } uq; uq.v = *(const bfrag*)qbase;
            *(s16x4*)(&Qb[0][qoff])     = uq.h[0];
            *(s16x4*)(&Qb[0][qoff + 4]) = uq.h[1];
        }
    }
    __syncthreads();

    f32x16 acc0, acc1;
    #pragma unroll
    for (int r = 0; r < 16; ++r) { acc0[r] = 0.f; acc1[r] = 0.f; }

    for (int t = 0; t < 14; ++t) {
        bfrag preA, preQ;
        bool hn = (t + 1 < 14);
        if (hn) {
            preA = *(const bfrag*)(abase + (size_t)(t + 1) * 32);
            if (st) preQ = *(const bfrag*)(qbase + (size_t)(t + 1) * 1024);
        }
        const bf16* ql = &Qb[t & 1][0];
        const bf16* al = &Ab[t & 1][0];
        int qo = l31 * LDP + lsel * 8;
        union { s16x4 h[2]; bfrag v; } q0, q1;
        q0.h[0] = *(const s16x4*)(ql + qo);
        q0.h[1] = *(const s16x4*)(ql + qo + 4);
        q1.h[0] = *(const s16x4*)(ql + qo + 16);
        q1.h[1] = *(const s16x4*)(ql + qo + 20);
        f32x16 s;
        #pragma unroll
        for (int r = 0; r < 16; ++r) s[r] = 0.f;
        s = MFMA32(q0.v, kb0, s);
        s = MFMA32(q1.v, kb1, s);
        union { unsigned short us[8]; bfrag v; } pa0, pa1;
        #pragma unroll
        for (int i = 0; i < 8; ++i) {
            bf16 e0 = f2b(fexp2(s[i]));
            bf16 e1 = f2b(fexp2(s[8 + i]));
            pa0.us[i] = *(unsigned short*)&e0;
            pa1.us[i] = *(unsigned short*)&e1;
        }
        const bf16* a0 = al + l31 * LDP + lsel * 4;
        const bf16* a1 = al + (l31 + 32) * LDP + lsel * 4;
        union { s16x4 h[2]; bfrag v; } e00, e01, e10, e11;
        e00.h[0] = *(const s16x4*)(a0);
        e00.h[1] = *(const s16x4*)(a0 + 8);
        e01.h[0] = *(const s16x4*)(a0 + 16);
        e01.h[1] = *(const s16x4*)(a0 + 24);
        e10.h[0] = *(const s16x4*)(a1);
        e10.h[1] = *(const s16x4*)(a1 + 8);
        e11.h[0] = *(const s16x4*)(a1 + 16);
        e11.h[1] = *(const s16x4*)(a1 + 24);
        acc0 = MFMA32(pa0.v, e00.v, acc0);
        acc0 = MFMA32(pa1.v, e01.v, acc0);
        acc1 = MFMA32(pa0.v, e10.v, acc1);
        acc1 = MFMA32(pa1.v, e11.v, acc1);
        if (hn) {
            union { bfrag v; s16x4 h[2]; } u; u.v = preA;
            *(s16x4*)(&Ab[(t + 1) & 1][aoff])     = u.h[0];
            *(s16x4*)(&Ab[(t + 1) & 1][aoff + 4]) = u.h[1];
            if (st) {
                union { bfrag v; s16x4 h[2]; } uq; uq.v = preQ;
                *(s16x4*)(&Qb[(t + 1) & 1][qoff])     = uq.h[0];
                *(s16x4*)(&Qb[(t + 1) & 1][qoff + 4]) = uq.h[1];
            }
        }
        __syncthreads();
    }
    if (act) {
        float* dst = av2_acc + ((size_t)bh * NN + n0) * 64 + l31;
        #pragma unroll
        for (int r = 0; r < 16; ++r) {
            int nl = (r & 3) + 8 * (r >> 2) + 4 * lsel;
            atomicAdd(dst + (size_t)nl * 64, acc0[r]);
            atomicAdd(dst + (size_t)nl * 64 + 32, acc1[r]);
        }
    }
}

// ---------------- reduce1: awts' = relu(bn1(av @ w1^T + b1)) * rden -> [bh][64][N] bf16 ----------------
__global__ __launch_bounds__(256) void k_red1(const float* __restrict__ av_acc,
    const float* __restrict__ w1, const float* __restrict__ b1,
    const float* __restrict__ g1, const float* __restrict__ be1,
    const float* __restrict__ rm1, const float* __restrict__ rv1,
    const float* __restrict__ rds,
    bf16* __restrict__ awts)
{
    __shared__ float avl[64 * 33];
    __shared__ float w1l[64 * 33];
    __shared__ float sc[64], sh[64], bb[64];
    int n0 = blockIdx.x * 64, bh = blockIdx.y, h = bh & 3;
    int tid = threadIdx.x;
    const float* ap = av_acc + ((size_t)bh * NN + n0) * 32;
    for (int i = tid; i < 2048; i += 256) {
        avl[(i >> 5) * 33 + (i & 31)] = ap[i];
        w1l[(i >> 5) * 33 + (i & 31)] = w1[i];
    }
    if (tid < 64) {
        int ch = h * 64 + tid;
        float s = g1[ch] * rsqrtf(rv1[ch] + 1e-5f);
        sc[tid] = s; sh[tid] = be1[ch] - rm1[ch] * s; bb[tid] = b1[tid];
    }
    __syncthreads();
    int nb = (tid & 15) * 4, eb = (tid >> 4) * 4;
    float rsc[4];
    {
        const float* rp = rds + (size_t)bh * NN + n0 + nb;
        rsc[0] = rp[0]; rsc[1] = rp[1]; rsc[2] = rp[2]; rsc[3] = rp[3];
    }
    float s[4][4];
    #pragma unroll
    for (int i = 0; i < 4; ++i)
        #pragma unroll
        for (int j = 0; j < 4; ++j) s[i][j] = bb[eb + j];
    for (int d = 0; d < 32; ++d) {
        float a0 = avl[(nb+0)*33+d], a1 = avl[(nb+1)*33+d], a2 = avl[(nb+2)*33+d], a3 = avl[(nb+3)*33+d];
        float w0 = w1l[(eb+0)*33+d], w1v = w1l[(eb+1)*33+d], w2v = w1l[(eb+2)*33+d], w3 = w1l[(eb+3)*33+d];
        s[0][0]+=a0*w0; s[0][1]+=a0*w1v; s[0][2]+=a0*w2v; s[0][3]+=a0*w3;
        s[1][0]+=a1*w0; s[1][1]+=a1*w1v; s[1][2]+=a1*w2v; s[1][3]+=a1*w3;
        s[2][0]+=a2*w0; s[2][1]+=a2*w1v; s[2][2]+=a2*w2v; s[2][3]+=a2*w3;
        s[3][0]+=a3*w0; s[3][1]+=a3*w1v; s[3][2]+=a3*w2v; s[3][3]+=a3*w3;
    }
    #pragma unroll
    for (int j = 0; j < 4; ++j) {
        int e = eb + j;
        ushort4 pk;
        float v0 = fmaxf(s[0][j] * sc[e] + sh[e], 0.f) * rsc[0];
        float v1 = fmaxf(s[1][j] * sc[e] + sh[e], 0.f) * rsc[1];
        float v2 = fmaxf(s[2][j] * sc[e] + sh[e], 0.f) * rsc[2];
        float v3 = fmaxf(s[3][j] * sc[e] + sh[e], 0.f) * rsc[3];
        bf16 b0 = f2b(v0), b1b = f2b(v1), b2b = f2b(v2), b3 = f2b(v3);
        pk.x = *(unsigned short*)&b0; pk.y = *(unsigned short*)&b1b;
        pk.z = *(unsigned short*)&b2b; pk.w = *(unsigned short*)&b3;
        *reinterpret_cast<ushort4*>(awts + ((size_t)bh * 64 + e) * NN + n0 + nb) = pk;
    }
}

// ---------------- reduce2: avw2 = relu(bn2(av2 @ w2^T + b2)) -> y[b][256][N] bf16 ----------------
__global__ __launch_bounds__(256) void k_red2(const float* __restrict__ av2_acc,
    const float* __restrict__ w2, const float* __restrict__ b2,
    const float* __restrict__ g2, const float* __restrict__ be2,
    const float* __restrict__ rm2, const float* __restrict__ rv2,
    bf16* __restrict__ y)
{
    __shared__ float a2l[64 * 65];
    __shared__ float w2l[64 * 65];
    __shared__ float sc[64], sh[64], bb[64];
    int n0 = blockIdx.x * 64, bh = blockIdx.y, h = bh & 3, b = bh >> 2;
    int tid = threadIdx.x;
    const float* ap = av2_acc + ((size_t)bh * NN + n0) * 64;
    for (int i = tid; i < 4096; i += 256) {
        a2l[(i >> 6) * 65 + (i & 63)] = ap[i];
        w2l[(i >> 6) * 65 + (i & 63)] = w2[i];
    }
    if (tid < 64) {
        int ch = h * 64 + tid;
        float s = g2[ch] * rsqrtf(rv2[ch] + 1e-5f);
        sc[tid] = s; sh[tid] = be2[ch] - rm2[ch] * s; bb[tid] = b2[tid];
    }
    __syncthreads();
    int nb = (tid & 15) * 4, eb = (tid >> 4) * 4;
    float s[4][4];
    #pragma unroll
    for (int i = 0; i < 4; ++i)
        #pragma unroll
        for (int j = 0; j < 4; ++j) s[i][j] = bb[eb + j];
    for (int d = 0; d < 64; ++d) {
        float a0 = a2l[(nb+0)*65+d], a1 = a2l[(nb+1)*65+d], a2 = a2l[(nb+2)*65+d], a3 = a2l[(nb+3)*65+d];
        float w0 = w2l[(eb+0)*65+d], w1v = w2l[(eb+1)*65+d], w2v = w2l[(eb+2)*65+d], w3 = w2l[(eb+3)*65+d];
        s[0][0]+=a0*w0; s[0][1]+=a0*w1v; s[0][2]+=a0*w2v; s[0][3]+=a0*w3;
        s[1][0]+=a1*w0; s[1][1]+=a1*w1v; s[1][2]+=a1*w2v; s[1][3]+=a1*w3;
        s[2][0]+=a2*w0; s[2][1]+=a2*w1v; s[2][2]+=a2*w2v; s[2][3]+=a2*w3;
        s[3][0]+=a3*w0; s[3][1]+=a3*w1v; s[3][2]+=a3*w2v; s[3][3]+=a3*w3;
    }
    #pragma unroll
    for (int j = 0; j < 4; ++j) {
        int e = eb + j;
        ushort4 pk;
        float v0 = fmaxf(s[0][j] * sc[e] + sh[e], 0.f);
        float v1 = fmaxf(s[1][j] * sc[e] + sh[e], 0.f);
        float v2 = fmaxf(s[2][j] * sc[e] + sh[e], 0.f);
        float v3 = fmaxf(s[3][j] * sc[e] + sh[e], 0.f);
        bf16 b0 = f2b(v0), b1b = f2b(v1), b2b = f2b(v2), b3 = f2b(v3);
        pk.x = *(unsigned short*)&b0; pk.y = *(unsigned short*)&b1b;
        pk.z = *(unsigned short*)&b2b; pk.w = *(unsigned short*)&b3;
        *reinterpret_cast<ushort4*>(y + ((size_t)b * 256 + h * 64 + e) * NN + n0 + nb) = pk;
    }
}

// ---------------- final 1x1 conv (f32 out), 2 n per thread ----------------
__global__ __launch_bounds__(256) void k_final(const bf16* __restrict__ y,
    const float* __restrict__ wf, const float* __restrict__ bf_,
    float* __restrict__ out)
{
    int t = blockIdx.x * 256 + threadIdx.x;
    int n = t * 2;
    if (n >= NN) return;
    int o = blockIdx.y;
    int b = blockIdx.z;
    float s0 = bf_[o], s1 = s0;
    const bf16* yp = y + (size_t)b * 256 * NN + n;
    const float* wp = wf + o * 256;
    #pragma unroll 8
    for (int k = 0; k < 256; ++k) {
        unsigned u = *reinterpret_cast<const unsigned*>(yp + (size_t)k * NN);
        float lo = __uint_as_float(u << 16);
        float hi = __uint_as_float(u & 0xffff0000u);
        s0 += wp[k] * lo;
        s1 += wp[k] * hi;
    }
    float* op = out + ((size_t)b * 64 + o) * NN + n;
    op[0] = s0;
    op[1] = s1;
}

extern "C" void kernel_launch(void* const* d_in, const int* in_sizes, int n_in,
                              void* d_out, int out_size, void* d_ws, size_t ws_size,
                              hipStream_t stream)
{
    const float* x   = (const float*)d_in[0];
    const float* wk  = (const float*)d_in[1];
    const float* bk  = (const float*)d_in[2];
    const float* wq  = (const float*)d_in[3];
    const float* bq  = (const float*)d_in[4];
    const float* wv  = (const float*)d_in[5];
    const float* bv  = (const float*)d_in[6];
    const float* w1  = (const float*)d_in[7];
    const float* b1  = (const float*)d_in[8];
    const float* g1  = (const float*)d_in[9];
    const float* be1 = (const float*)d_in[10];
    const float* rm1 = (const float*)d_in[11];
    const float* rv1 = (const float*)d_in[12];
    const float* w2  = (const float*)d_in[13];
    const float* b2  = (const float*)d_in[14];
    const float* g2  = (const float*)d_in[15];
    const float* be2 = (const float*)d_in[16];
    const float* rm2 = (const float*)d_in[17];
    const float* rv2 = (const float*)d_in[18];
    const float* wf  = (const float*)d_in[19];
    const float* bff = (const float*)d_in[20];
    float* out = (float*)d_out;

    char* ws = (char*)d_ws;
    bf16* kt   = (bf16*)ws;
    bf16* qt   = kt + (size_t)NBH * NN * 32;
    bf16* vt   = qt + (size_t)NBH * NN * 32;
    bf16* awts = vt + (size_t)NBH * 32 * NN;
    bf16* y    = awts + (size_t)NBH * 64 * NN;
    float* den     = (float*)(y + (size_t)2 * 256 * NN);
    float* av_acc  = den + (size_t)NBH * NN;
    float* av2_acc = av_acc + (size_t)NBH * NN * 32;

    k_zero  <<<dim3(2377),     256, 0, stream>>>(den, 608384);
    k_proj  <<<dim3(49, 2, 4), 256, 0, stream>>>(x, wk, bk, wq, bq, wv, bv, kt, qt, vt);
    k_stats <<<dim3(25, 7, 8), 256, 0, stream>>>(kt, qt, den);
    k_recip <<<dim3(98),       256, 0, stream>>>(den);
    k_scalev<<<dim3(7, 256),   256, 0, stream>>>(vt, den);
    k_av    <<<dim3(25, 7, 8), 256, 0, stream>>>(kt, qt, vt, av_acc);
    k_red1  <<<dim3(49, 8),    256, 0, stream>>>(av_acc, w1, b1, g1, be1, rm1, rv1, den, awts);
    k_av2   <<<dim3(25, 7, 8), 256, 0, stream>>>(kt, qt, awts, av2_acc);
    k_red2  <<<dim3(49, 8),    256, 0, stream>>>(av2_acc, w2, b2, g2, be2, rm2, rv2, y);
    k_final <<<dim3(7, 64, 2), 256, 0, stream>>>(y, wf, bff, out);
}

// Round 14
// 172.201 us; speedup vs baseline: 1.1645x; 1.1371x over previous
//
#include <hip/hip_runtime.h>
#include <hip/hip_bf16.h>

typedef __hip_bfloat16 bf16;
typedef __attribute__((ext_vector_type(8))) short bfrag;    // 8 x bf16 (16 B)
typedef __attribute__((ext_vector_type(4))) short s16x4;    // 4 x bf16 (8 B)
typedef __attribute__((ext_vector_type(4))) float f32x4;
typedef __attribute__((ext_vector_type(16))) float f32x16;

#define MFMA32(a,b,c) __builtin_amdgcn_mfma_f32_32x32x16_bf16((a),(b),(c),0,0,0)

__device__ __forceinline__ float b2f(bf16 x){ return __bfloat162float(x); }
__device__ __forceinline__ bf16 f2b(float x){ return __float2bfloat16(x); }
__device__ __forceinline__ float fexp2(float x){ return __builtin_amdgcn_exp2f(x); }

#define NN   3136   // 56*56 = 98 tiles of 32
#define NBH  8      // B * NH
#define MCH  448    // m/n chunk = 14 tiles of 32 = 7 double-steps of 64
#define LDP  40     // LDS row stride for 32-col tiles (80 B; known-good K12)
#define LDPA 72     // LDS row stride for 64-col tiles (144 B)
#define LOG2E 1.44269504f

// ---------------- zero accumulators ----------------
__global__ __launch_bounds__(256) void k_zero(float* __restrict__ p, int n4)
{
    int i = blockIdx.x * 256 + threadIdx.x;
    if (i < n4) reinterpret_cast<f32x4*>(p)[i] = (f32x4){0.f, 0.f, 0.f, 0.f};
}

// ---------------- QKV 1x1 conv projections, LDS-tiled ----------------
// kt: [bh][N][32] (pre-scaled by log2e), qt: [bh][N][32], vt: [bh][32][N]
__global__ __launch_bounds__(256) void k_proj(
    const float* __restrict__ x,
    const float* __restrict__ wk, const float* __restrict__ bk,
    const float* __restrict__ wq, const float* __restrict__ bq,
    const float* __restrict__ wv, const float* __restrict__ bv,
    bf16* __restrict__ kt, bf16* __restrict__ qt, bf16* __restrict__ vt)
{
    __shared__ float xl[64 * 65];
    __shared__ float wl[96 * 64];
    __shared__ float bl[96];
    int n0 = blockIdx.x * 64;
    int b  = blockIdx.y;
    int z  = blockIdx.z;
    int tid = threadIdx.x;

    for (int i = tid; i < 4096; i += 256) {
        int c = i >> 6, n = i & 63;
        xl[c * 65 + n] = x[((size_t)b * 64 + c) * NN + n0 + n];
    }
    const float* wp_[3] = {wk, wq, wv};
    const float* bp_[3] = {bk, bq, bv};
    for (int i = tid; i < 96 * 64; i += 256) {
        int j = i >> 6, c = i & 63;
        int ch = z * 96 + j, pr = ch >> 7, oc = ch & 127;
        wl[i] = wp_[pr][oc * 64 + c];
    }
    if (tid < 96) { int ch = z * 96 + tid; bl[tid] = bp_[ch >> 7][ch & 127]; }
    __syncthreads();

    int n = tid & 63, jg = tid >> 6;
    for (int j0 = jg * 24; j0 < (jg + 1) * 24; j0 += 4) {
        float s0 = bl[j0+0], s1 = bl[j0+1], s2 = bl[j0+2], s3 = bl[j0+3];
        for (int c = 0; c < 64; ++c) {
            float xv = xl[c * 65 + n];
            s0 += xv * wl[(j0+0) * 64 + c];
            s1 += xv * wl[(j0+1) * 64 + c];
            s2 += xv * wl[(j0+2) * 64 + c];
            s3 += xv * wl[(j0+3) * 64 + c];
        }
        float sv[4] = {s0, s1, s2, s3};
        #pragma unroll
        for (int q = 0; q < 4; ++q) {
            int ch = z * 96 + j0 + q;
            int pr = ch >> 7, oc = ch & 127, h = oc >> 5, d = oc & 31;
            size_t bh = (size_t)b * 4 + h;
            if (pr == 0)      kt[(bh * NN + n0 + n) * 32 + d] = f2b(sv[q] * LOG2E);
            else if (pr == 1) qt[(bh * NN + n0 + n) * 32 + d] = f2b(sv[q]);
            else              vt[(bh * 32 + d) * NN + n0 + n] = f2b(sv[q]);
        }
    }
}

// ---------------- k_stats: den[m] += sum_{n-chunk} exp2(S'[n,m]) ----------------
// 4 waves own 4 m-tiles (Q in regs); block stages 2 K n-tiles (64 rows) per barrier step.
__global__ __launch_bounds__(256) void k_stats(const bf16* __restrict__ kt,
                                               const bf16* __restrict__ qt,
                                               float* __restrict__ den)
{
    __shared__ __align__(16) bf16 Kb[2][64 * LDP];
    int tid = threadIdx.x, w = tid >> 6, lane = tid & 63;
    int l31 = lane & 31, lsel = lane >> 5;
    int bh = blockIdx.z;
    int mt = blockIdx.x * 4 + w;
    bool act = (mt < 98);
    int m0 = (act ? mt : 97) * 32;
    int ns = blockIdx.y * MCH;

    const bf16* qp = qt + ((size_t)bh * NN + m0 + l31) * 32 + lsel * 8;
    bfrag qb0 = *(const bfrag*)qp;
    bfrag qb1 = *(const bfrag*)(qp + 16);
    const bf16* kt_bh = kt + (size_t)bh * NN * 32;

    int sr = tid >> 2, sc = (tid & 3) * 8;            // 64 rows x 4 chunks
    const bf16* sbase = kt_bh + (size_t)(ns + sr) * 32 + sc;
    int soff = sr * LDP + sc;

    *(bfrag*)(&Kb[0][soff]) = *(const bfrag*)sbase;
    __syncthreads();

    float dacc = 0.f;
    for (int t = 0; t < 7; ++t) {
        bfrag pre;
        bool hn = (t + 1 < 7);
        if (hn) pre = *(const bfrag*)(sbase + (size_t)(t + 1) * 2048);
        const bf16* kl = &Kb[t & 1][0];
        #pragma unroll
        for (int nt = 0; nt < 2; ++nt) {
            int ko = (l31 + 32 * nt) * LDP + lsel * 8;
            bfrag kb0 = *(const bfrag*)(kl + ko);
            bfrag kb1 = *(const bfrag*)(kl + ko + 16);
            f32x16 s;
            #pragma unroll
            for (int r = 0; r < 16; ++r) s[r] = 0.f;
            s = MFMA32(kb0, qb0, s);
            s = MFMA32(kb1, qb1, s);
            float ps = 0.f;
            #pragma unroll
            for (int r = 0; r < 16; ++r) ps += fexp2(s[r]);
            dacc += ps;
        }
        if (hn) *(bfrag*)(&Kb[(t + 1) & 1][soff]) = pre;
        __syncthreads();
    }
    dacc += __shfl_xor(dacc, 32);
    if (act && lane < 32) atomicAdd(&den[(size_t)bh * NN + m0 + l31], dacc);
}

__global__ __launch_bounds__(256) void k_recip(float* __restrict__ den)
{
    int i = blockIdx.x * 256 + threadIdx.x;
    if (i < NBH * NN) den[i] = 1.0f / den[i];
}

__global__ __launch_bounds__(256) void k_scalev(bf16* __restrict__ vt, const float* __restrict__ rden)
{
    int by = blockIdx.y;
    const float* rdp = rden + ((size_t)(by >> 5)) * NN;
    bf16* vp = vt + (size_t)by * NN;
    for (int m = blockIdx.x * MCH + threadIdx.x; m < blockIdx.x * MCH + MCH && m < NN; m += 256)
        vp[m] = f2b(b2f(vp[m]) * rdp[m]);
}

// ---------------- k_av: av[n,0:32] += sum_m exp2(S'[n,m]) * V'[m,e]; 2 m-tiles/step ----------------
__global__ __launch_bounds__(256) void k_av(const bf16* __restrict__ kt,
    const bf16* __restrict__ qt, const bf16* __restrict__ vtp,
    float* __restrict__ av_acc)
{
    __shared__ __align__(16) bf16 Qb[2][64 * LDP];   // 64 m-rows x 32 cols
    __shared__ __align__(16) bf16 Vb[2][32 * LDPA];  // 32 e-rows x 64 m-cols
    int tid = threadIdx.x, w = tid >> 6, lane = tid & 63;
    int l31 = lane & 31, lsel = lane >> 5;
    int bh = blockIdx.z;
    int ntile = blockIdx.x * 4 + w;
    bool act = (ntile < 98);
    int n0 = (act ? ntile : 97) * 32;
    int ms = blockIdx.y * MCH;

    const bf16* kp = kt + ((size_t)bh * NN + n0 + l31) * 32 + lsel * 8;
    bfrag kb0 = *(const bfrag*)kp;
    bfrag kb1 = *(const bfrag*)(kp + 16);
    const bf16* qt_bh = qt + (size_t)bh * NN * 32;
    const bf16* vt_bh = vtp + (size_t)bh * 32 * NN;

    // staging: every thread stages one 16B of Q and one 16B of V per step
    int qr = tid >> 2, qc = (tid & 3) * 8;                 // Q: 64 rows x 4 chunks
    const bf16* qsb = qt_bh + (size_t)(ms + qr) * 32 + qc;
    int qoff = qr * LDP + qc;
    int vr = tid >> 3, vc = (tid & 7) * 8;                 // V: 32 rows x 8 chunks
    const bf16* vsb = vt_bh + (size_t)vr * NN + ms + vc;
    int voff = vr * LDPA + vc;

    *(bfrag*)(&Qb[0][qoff]) = *(const bfrag*)qsb;
    *(bfrag*)(&Vb[0][voff]) = *(const bfrag*)vsb;
    __syncthreads();

    f32x16 acc;
    #pragma unroll
    for (int r = 0; r < 16; ++r) acc[r] = 0.f;

    for (int t = 0; t < 7; ++t) {
        bfrag preQ, preV;
        bool hn = (t + 1 < 7);
        if (hn) {
            preQ = *(const bfrag*)(qsb + (size_t)(t + 1) * 2048);
            preV = *(const bfrag*)(vsb + (size_t)(t + 1) * 64);
        }
        const bf16* ql = &Qb[t & 1][0];
        const bf16* vl = &Vb[t & 1][0];
        #pragma unroll
        for (int mt2 = 0; mt2 < 2; ++mt2) {
            int qo = (l31 + 32 * mt2) * LDP + lsel * 8;
            bfrag q0 = *(const bfrag*)(ql + qo);
            bfrag q1 = *(const bfrag*)(ql + qo + 16);
            f32x16 s;
            #pragma unroll
            for (int r = 0; r < 16; ++r) s[r] = 0.f;
            s = MFMA32(q0, kb0, s);   // D[row=m][col=n=l31]
            s = MFMA32(q1, kb1, s);
            union { unsigned short us[8]; bfrag v; } pa0, pa1;
            #pragma unroll
            for (int i = 0; i < 8; ++i) {
                bf16 e0 = f2b(fexp2(s[i]));
                bf16 e1 = f2b(fexp2(s[8 + i]));
                pa0.us[i] = *(unsigned short*)&e0;
                pa1.us[i] = *(unsigned short*)&e1;
            }
            const bf16* vrow = vl + l31 * LDPA + 32 * mt2 + lsel * 4;
            union { s16x4 h[2]; bfrag v; } vb0, vb1;
            vb0.h[0] = *(const s16x4*)(vrow);
            vb0.h[1] = *(const s16x4*)(vrow + 8);
            vb1.h[0] = *(const s16x4*)(vrow + 16);
            vb1.h[1] = *(const s16x4*)(vrow + 24);
            acc = MFMA32(pa0.v, vb0.v, acc);    // D[row=n][col=e]
            acc = MFMA32(pa1.v, vb1.v, acc);
        }
        if (hn) {
            *(bfrag*)(&Qb[(t + 1) & 1][qoff]) = preQ;
            *(bfrag*)(&Vb[(t + 1) & 1][voff]) = preV;
        }
        __syncthreads();
    }
    if (act) {
        float* dst = av_acc + ((size_t)bh * NN + n0) * 32 + l31;
        #pragma unroll
        for (int r = 0; r < 16; ++r) {
            int nl = (r & 3) + 8 * (r >> 2) + 4 * lsel;
            atomicAdd(dst + (size_t)nl * 32, acc[r]);
        }
    }
}

// ---------------- k_av2: av2[n,0:64] += sum_m exp2(S'[n,m]) * awts'[m,e]; 2 m-tiles/step ----------------
__global__ __launch_bounds__(256) void k_av2(const bf16* __restrict__ kt,
    const bf16* __restrict__ qt, const bf16* __restrict__ awts,
    float* __restrict__ av2_acc)
{
    __shared__ __align__(16) bf16 Qb[2][64 * LDP];   // 64 m-rows x 32 cols
    __shared__ __align__(16) bf16 Ab[2][64 * LDPA];  // 64 e-rows x 64 m-cols
    int tid = threadIdx.x, w = tid >> 6, lane = tid & 63;
    int l31 = lane & 31, lsel = lane >> 5;
    int bh = blockIdx.z;
    int ntile = blockIdx.x * 4 + w;
    bool act = (ntile < 98);
    int n0 = (act ? ntile : 97) * 32;
    int ms = blockIdx.y * MCH;

    const bf16* kp = kt + ((size_t)bh * NN + n0 + l31) * 32 + lsel * 8;
    bfrag kb0 = *(const bfrag*)kp;
    bfrag kb1 = *(const bfrag*)(kp + 16);
    const bf16* qt_bh = qt + (size_t)bh * NN * 32;
    const bf16* aw_bh = awts + (size_t)bh * 64 * NN;

    // staging: Q one 16B/thread; A two 16B/thread (rows 0-31 and 32-63)
    int qr = tid >> 2, qc = (tid & 3) * 8;
    const bf16* qsb = qt_bh + (size_t)(ms + qr) * 32 + qc;
    int qoff = qr * LDP + qc;
    int ar0 = tid >> 3, acv = (tid & 7) * 8;
    const bf16* asb0 = aw_bh + (size_t)ar0 * NN + ms + acv;
    const bf16* asb1 = aw_bh + (size_t)(ar0 + 32) * NN + ms + acv;
    int aoff0 = ar0 * LDPA + acv;
    int aoff1 = (ar0 + 32) * LDPA + acv;

    *(bfrag*)(&Qb[0][qoff])  = *(const bfrag*)qsb;
    *(bfrag*)(&Ab[0][aoff0]) = *(const bfrag*)asb0;
    *(bfrag*)(&Ab[0][aoff1]) = *(const bfrag*)asb1;
    __syncthreads();

    f32x16 acc0, acc1;
    #pragma unroll
    for (int r = 0; r < 16; ++r) { acc0[r] = 0.f; acc1[r] = 0.f; }

    for (int t = 0; t < 7; ++t) {
        bfrag preQ, preA0, preA1;
        bool hn = (t + 1 < 7);
        if (hn) {
            preQ  = *(const bfrag*)(qsb  + (size_t)(t + 1) * 2048);
            preA0 = *(const bfrag*)(asb0 + (size_t)(t + 1) * 64);
            preA1 = *(const bfrag*)(asb1 + (size_t)(t + 1) * 64);
        }
        const bf16* ql = &Qb[t & 1][0];
        const bf16* al = &Ab[t & 1][0];
        #pragma unroll
        for (int mt2 = 0; mt2 < 2; ++mt2) {
            int qo = (l31 + 32 * mt2) * LDP + lsel * 8;
            bfrag q0 = *(const bfrag*)(ql + qo);
            bfrag q1 = *(const bfrag*)(ql + qo + 16);
            f32x16 s;
            #pragma unroll
            for (int r = 0; r < 16; ++r) s[r] = 0.f;
            s = MFMA32(q0, kb0, s);
            s = MFMA32(q1, kb1, s);
            union { unsigned short us[8]; bfrag v; } pa0, pa1;
            #pragma unroll
            for (int i = 0; i < 8; ++i) {
                bf16 e0 = f2b(fexp2(s[i]));
                bf16 e1 = f2b(fexp2(s[8 + i]));
                pa0.us[i] = *(unsigned short*)&e0;
                pa1.us[i] = *(unsigned short*)&e1;
            }
            const bf16* a0 = al + l31 * LDPA + 32 * mt2 + lsel * 4;
            const bf16* a1 = al + (l31 + 32) * LDPA + 32 * mt2 + lsel * 4;
            union { s16x4 h[2]; bfrag v; } e00, e01, e10, e11;
            e00.h[0] = *(const s16x4*)(a0);
            e00.h[1] = *(const s16x4*)(a0 + 8);
            e01.h[0] = *(const s16x4*)(a0 + 16);
            e01.h[1] = *(const s16x4*)(a0 + 24);
            e10.h[0] = *(const s16x4*)(a1);
            e10.h[1] = *(const s16x4*)(a1 + 8);
            e11.h[0] = *(const s16x4*)(a1 + 16);
            e11.h[1] = *(const s16x4*)(a1 + 24);
            acc0 = MFMA32(pa0.v, e00.v, acc0);
            acc0 = MFMA32(pa1.v, e01.v, acc0);
            acc1 = MFMA32(pa0.v, e10.v, acc1);
            acc1 = MFMA32(pa1.v, e11.v, acc1);
        }
        if (hn) {
            *(bfrag*)(&Qb[(t + 1) & 1][qoff])  = preQ;
            *(bfrag*)(&Ab[(t + 1) & 1][aoff0]) = preA0;
            *(bfrag*)(&Ab[(t + 1) & 1][aoff1]) = preA1;
        }
        __syncthreads();
    }
    if (act) {
        float* dst = av2_acc + ((size_t)bh * NN + n0) * 64 + l31;
        #pragma unroll
        for (int r = 0; r < 16; ++r) {
            int nl = (r & 3) + 8 * (r >> 2) + 4 * lsel;
            atomicAdd(dst + (size_t)nl * 64, acc0[r]);
            atomicAdd(dst + (size_t)nl * 64 + 32, acc1[r]);
        }
    }
}

// ---------------- reduce1: awts' = relu(bn1(av @ w1^T + b1)) * rden -> [bh][64][N] bf16 ----------------
__global__ __launch_bounds__(256) void k_red1(const float* __restrict__ av_acc,
    const float* __restrict__ w1, const float* __restrict__ b1,
    const float* __restrict__ g1, const float* __restrict__ be1,
    const float* __restrict__ rm1, const float* __restrict__ rv1,
    const float* __restrict__ rds,
    bf16* __restrict__ awts)
{
    __shared__ float avl[64 * 33];
    __shared__ float w1l[64 * 33];
    __shared__ float sc[64], sh[64], bb[64];
    int n0 = blockIdx.x * 64, bh = blockIdx.y, h = bh & 3;
    int tid = threadIdx.x;
    const float* ap = av_acc + ((size_t)bh * NN + n0) * 32;
    for (int i = tid; i < 2048; i += 256) {
        avl[(i >> 5) * 33 + (i & 31)] = ap[i];
        w1l[(i >> 5) * 33 + (i & 31)] = w1[i];
    }
    if (tid < 64) {
        int ch = h * 64 + tid;
        float s = g1[ch] * rsqrtf(rv1[ch] + 1e-5f);
        sc[tid] = s; sh[tid] = be1[ch] - rm1[ch] * s; bb[tid] = b1[tid];
    }
    __syncthreads();
    int nb = (tid & 15) * 4, eb = (tid >> 4) * 4;
    float rsc[4];
    {
        const float* rp = rds + (size_t)bh * NN + n0 + nb;
        rsc[0] = rp[0]; rsc[1] = rp[1]; rsc[2] = rp[2]; rsc[3] = rp[3];
    }
    float s[4][4];
    #pragma unroll
    for (int i = 0; i < 4; ++i)
        #pragma unroll
        for (int j = 0; j < 4; ++j) s[i][j] = bb[eb + j];
    for (int d = 0; d < 32; ++d) {
        float a0 = avl[(nb+0)*33+d], a1 = avl[(nb+1)*33+d], a2 = avl[(nb+2)*33+d], a3 = avl[(nb+3)*33+d];
        float w0 = w1l[(eb+0)*33+d], w1v = w1l[(eb+1)*33+d], w2v = w1l[(eb+2)*33+d], w3 = w1l[(eb+3)*33+d];
        s[0][0]+=a0*w0; s[0][1]+=a0*w1v; s[0][2]+=a0*w2v; s[0][3]+=a0*w3;
        s[1][0]+=a1*w0; s[1][1]+=a1*w1v; s[1][2]+=a1*w2v; s[1][3]+=a1*w3;
        s[2][0]+=a2*w0; s[2][1]+=a2*w1v; s[2][2]+=a2*w2v; s[2][3]+=a2*w3;
        s[3][0]+=a3*w0; s[3][1]+=a3*w1v; s[3][2]+=a3*w2v; s[3][3]+=a3*w3;
    }
    #pragma unroll
    for (int j = 0; j < 4; ++j) {
        int e = eb + j;
        ushort4 pk;
        float v0 = fmaxf(s[0][j] * sc[e] + sh[e], 0.f) * rsc[0];
        float v1 = fmaxf(s[1][j] * sc[e] + sh[e], 0.f) * rsc[1];
        float v2 = fmaxf(s[2][j] * sc[e] + sh[e], 0.f) * rsc[2];
        float v3 = fmaxf(s[3][j] * sc[e] + sh[e], 0.f) * rsc[3];
        bf16 b0 = f2b(v0), b1b = f2b(v1), b2b = f2b(v2), b3 = f2b(v3);
        pk.x = *(unsigned short*)&b0; pk.y = *(unsigned short*)&b1b;
        pk.z = *(unsigned short*)&b2b; pk.w = *(unsigned short*)&b3;
        *reinterpret_cast<ushort4*>(awts + ((size_t)bh * 64 + e) * NN + n0 + nb) = pk;
    }
}

// ---------------- reduce2: avw2 = relu(bn2(av2 @ w2^T + b2)) -> y[b][256][N] bf16 ----------------
__global__ __launch_bounds__(256) void k_red2(const float* __restrict__ av2_acc,
    const float* __restrict__ w2, const float* __restrict__ b2,
    const float* __restrict__ g2, const float* __restrict__ be2,
    const float* __restrict__ rm2, const float* __restrict__ rv2,
    bf16* __restrict__ y)
{
    __shared__ float a2l[64 * 65];
    __shared__ float w2l[64 * 65];
    __shared__ float sc[64], sh[64], bb[64];
    int n0 = blockIdx.x * 64, bh = blockIdx.y, h = bh & 3, b = bh >> 2;
    int tid = threadIdx.x;
    const float* ap = av2_acc + ((size_t)bh * NN + n0) * 64;
    for (int i = tid; i < 4096; i += 256) {
        a2l[(i >> 6) * 65 + (i & 63)] = ap[i];
        w2l[(i >> 6) * 65 + (i & 63)] = w2[i];
    }
    if (tid < 64) {
        int ch = h * 64 + tid;
        float s = g2[ch] * rsqrtf(rv2[ch] + 1e-5f);
        sc[tid] = s; sh[tid] = be2[ch] - rm2[ch] * s; bb[tid] = b2[tid];
    }
    __syncthreads();
    int nb = (tid & 15) * 4, eb = (tid >> 4) * 4;
    float s[4][4];
    #pragma unroll
    for (int i = 0; i < 4; ++i)
        #pragma unroll
        for (int j = 0; j < 4; ++j) s[i][j] = bb[eb + j];
    for (int d = 0; d < 64; ++d) {
        float a0 = a2l[(nb+0)*65+d], a1 = a2l[(nb+1)*65+d], a2 = a2l[(nb+2)*65+d], a3 = a2l[(nb+3)*65+d];
        float w0 = w2l[(eb+0)*65+d], w1v = w2l[(eb+1)*65+d], w2v = w2l[(eb+2)*65+d], w3 = w2l[(eb+3)*65+d];
        s[0][0]+=a0*w0; s[0][1]+=a0*w1v; s[0][2]+=a0*w2v; s[0][3]+=a0*w3;
        s[1][0]+=a1*w0; s[1][1]+=a1*w1v; s[1][2]+=a1*w2v; s[1][3]+=a1*w3;
        s[2][0]+=a2*w0; s[2][1]+=a2*w1v; s[2][2]+=a2*w2v; s[2][3]+=a2*w3;
        s[3][0]+=a3*w0; s[3][1]+=a3*w1v; s[3][2]+=a3*w2v; s[3][3]+=a3*w3;
    }
    #pragma unroll
    for (int j = 0; j < 4; ++j) {
        int e = eb + j;
        ushort4 pk;
        float v0 = fmaxf(s[0][j] * sc[e] + sh[e], 0.f);
        float v1 = fmaxf(s[1][j] * sc[e] + sh[e], 0.f);
        float v2 = fmaxf(s[2][j] * sc[e] + sh[e], 0.f);
        float v3 = fmaxf(s[3][j] * sc[e] + sh[e], 0.f);
        bf16 b0 = f2b(v0), b1b = f2b(v1), b2b = f2b(v2), b3 = f2b(v3);
        pk.x = *(unsigned short*)&b0; pk.y = *(unsigned short*)&b1b;
        pk.z = *(unsigned short*)&b2b; pk.w = *(unsigned short*)&b3;
        *reinterpret_cast<ushort4*>(y + ((size_t)b * 256 + h * 64 + e) * NN + n0 + nb) = pk;
    }
}

// ---------------- final 1x1 conv (f32 out), 2 n per thread ----------------
__global__ __launch_bounds__(256) void k_final(const bf16* __restrict__ y,
    const float* __restrict__ wf, const float* __restrict__ bf_,
    float* __restrict__ out)
{
    int t = blockIdx.x * 256 + threadIdx.x;
    int n = t * 2;
    if (n >= NN) return;
    int o = blockIdx.y;
    int b = blockIdx.z;
    float s0 = bf_[o], s1 = s0;
    const bf16* yp = y + (size_t)b * 256 * NN + n;
    const float* wp = wf + o * 256;
    #pragma unroll 8
    for (int k = 0; k < 256; ++k) {
        unsigned u = *reinterpret_cast<const unsigned*>(yp + (size_t)k * NN);
        float lo = __uint_as_float(u << 16);
        float hi = __uint_as_float(u & 0xffff0000u);
        s0 += wp[k] * lo;
        s1 += wp[k] * hi;
    }
    float* op = out + ((size_t)b * 64 + o) * NN + n;
    op[0] = s0;
    op[1] = s1;
}

extern "C" void kernel_launch(void* const* d_in, const int* in_sizes, int n_in,
                              void* d_out, int out_size, void* d_ws, size_t ws_size,
                              hipStream_t stream)
{
    const float* x   = (const float*)d_in[0];
    const float* wk  = (const float*)d_in[1];
    const float* bk  = (const float*)d_in[2];
    const float* wq  = (const float*)d_in[3];
    const float* bq  = (const float*)d_in[4];
    const float* wv  = (const float*)d_in[5];
    const float* bv  = (const float*)d_in[6];
    const float* w1  = (const float*)d_in[7];
    const float* b1  = (const float*)d_in[8];
    const float* g1  = (const float*)d_in[9];
    const float* be1 = (const float*)d_in[10];
    const float* rm1 = (const float*)d_in[11];
    const float* rv1 = (const float*)d_in[12];
    const float* w2  = (const float*)d_in[13];
    const float* b2  = (const float*)d_in[14];
    const float* g2  = (const float*)d_in[15];
    const float* be2 = (const float*)d_in[16];
    const float* rm2 = (const float*)d_in[17];
    const float* rv2 = (const float*)d_in[18];
    const float* wf  = (const float*)d_in[19];
    const float* bff = (const float*)d_in[20];
    float* out = (float*)d_out;

    char* ws = (char*)d_ws;
    bf16* kt   = (bf16*)ws;
    bf16* qt   = kt + (size_t)NBH * NN * 32;
    bf16* vt   = qt + (size_t)NBH * NN * 32;
    bf16* awts = vt + (size_t)NBH * 32 * NN;
    bf16* y    = awts + (size_t)NBH * 64 * NN;
    float* den     = (float*)(y + (size_t)2 * 256 * NN);
    float* av_acc  = den + (size_t)NBH * NN;
    float* av2_acc = av_acc + (size_t)NBH * NN * 32;

    k_zero  <<<dim3(2377),     256, 0, stream>>>(den, 608384);
    k_proj  <<<dim3(49, 2, 4), 256, 0, stream>>>(x, wk, bk, wq, bq, wv, bv, kt, qt, vt);
    k_stats <<<dim3(25, 7, 8), 256, 0, stream>>>(kt, qt, den);
    k_recip <<<dim3(98),       256, 0, stream>>>(den);
    k_scalev<<<dim3(7, 256),   256, 0, stream>>>(vt, den);
    k_av    <<<dim3(25, 7, 8), 256, 0, stream>>>(kt, qt, vt, av_acc);
    k_red1  <<<dim3(49, 8),    256, 0, stream>>>(av_acc, w1, b1, g1, be1, rm1, rv1, den, awts);
    k_av2   <<<dim3(25, 7, 8), 256, 0, stream>>>(kt, qt, awts, av2_acc);
    k_red2  <<<dim3(49, 8),    256, 0, stream>>>(av2_acc, w2, b2, g2, be2, rm2, rv2, y);
    k_final <<<dim3(7, 64, 2), 256, 0, stream>>>(y, wf, bff, out);
}

// Round 15
// 141.973 us; speedup vs baseline: 1.4124x; 1.2129x over previous
//
#include <hip/hip_runtime.h>
#include <hip/hip_bf16.h>

typedef __hip_bfloat16 bf16;
typedef __attribute__((ext_vector_type(8))) short bfrag;    // 8 x bf16 (16 B)
typedef __attribute__((ext_vector_type(4))) short s16x4;    // 4 x bf16 (8 B)
typedef __attribute__((ext_vector_type(4))) float f32x4;
typedef __attribute__((ext_vector_type(16))) float f32x16;

#define MFMA32(a,b,c) __builtin_amdgcn_mfma_f32_32x32x16_bf16((a),(b),(c),0,0,0)

__device__ __forceinline__ float b2f(bf16 x){ return __bfloat162float(x); }
__device__ __forceinline__ bf16 f2b(float x){ return __float2bfloat16(x); }
__device__ __forceinline__ float fexp2(float x){ return __builtin_amdgcn_exp2f(x); }

#define NN   3136   // 56*56 = 98 tiles of 32
#define NBH  8      // B * NH
#define MCH  448    // m/n chunk = 14 tiles of 32 = 7 double-steps of 64
#define LDP  40     // LDS row stride for 32-col tiles (80 B; known-good)
#define LDPA 72     // LDS row stride for 64-col tiles (144 B)
#define LOG2E 1.44269504f

// ---------------- zero accumulators ----------------
__global__ __launch_bounds__(256) void k_zero(float* __restrict__ p, int n4)
{
    int i = blockIdx.x * 256 + threadIdx.x;
    if (i < n4) reinterpret_cast<f32x4*>(p)[i] = (f32x4){0.f, 0.f, 0.f, 0.f};
}

// ---------------- QKV projections via MFMA ----------------
// out[n, oc] = sum_c xT[n,c] * w[oc,c] + bias[oc]; A=xT rows n, B=w rows oc (verified D-layout).
// kt: [bh][N][32] (pre-scaled by log2e), qt: [bh][N][32], vt: [bh][32][N]
__global__ __launch_bounds__(256) void k_proj(
    const float* __restrict__ x,
    const float* __restrict__ wk, const float* __restrict__ bk,
    const float* __restrict__ wq, const float* __restrict__ bq,
    const float* __restrict__ wv, const float* __restrict__ bv,
    bf16* __restrict__ kt, bf16* __restrict__ qt, bf16* __restrict__ vt)
{
    __shared__ __align__(16) bf16 xT[32 * 72];    // [n][c], stride 144 B (16B-aligned)
    __shared__ __align__(16) bf16 wT[128 * 72];   // [oc][c]
    int tid = threadIdx.x, w = tid >> 6, lane = tid & 63;
    int l31 = lane & 31, lsel = lane >> 5;
    int n0 = blockIdx.x * 32;
    int p  = blockIdx.y;     // 0=K 1=Q 2=V
    int b  = blockIdx.z;
    const float* wp = (p == 0) ? wk : ((p == 1) ? wq : wv);
    const float* bp = (p == 0) ? bk : ((p == 1) ? bq : bv);

    for (int i = tid; i < 2048; i += 256) {
        int c = i >> 5, j = i & 31;
        xT[j * 72 + c] = f2b(x[((size_t)b * 64 + c) * NN + n0 + j]);
    }
    for (int i = tid; i < 8192; i += 256) {
        int oc = i >> 6, c = i & 63;
        wT[oc * 72 + c] = f2b(wp[oc * 64 + c]);
    }
    __syncthreads();

    f32x16 s;
    #pragma unroll
    for (int r = 0; r < 16; ++r) s[r] = 0.f;
    #pragma unroll
    for (int k = 0; k < 4; ++k) {
        bfrag a  = *(const bfrag*)(&xT[l31 * 72 + k * 16 + lsel * 8]);
        bfrag bw = *(const bfrag*)(&wT[(w * 32 + l31) * 72 + k * 16 + lsel * 8]);
        s = MFMA32(a, bw, s);   // D[row=n][col=oc=l31]
    }
    float bias = bp[w * 32 + l31];
    size_t bh = (size_t)b * 4 + w;     // head = oc-tile = wave
    if (p == 2) {
        #pragma unroll
        for (int q = 0; q < 4; ++q) {
            s16x4 pk;
            #pragma unroll
            for (int i = 0; i < 4; ++i) {
                bf16 e = f2b(s[4 * q + i] + bias);
                pk[i] = *(short*)&e;
            }
            *(s16x4*)(vt + (bh * 32 + l31) * NN + n0 + 8 * q + 4 * lsel) = pk;
        }
    } else {
        bf16* dst = (p == 0) ? kt : qt;
        float sc = (p == 0) ? LOG2E : 1.0f;
        #pragma unroll
        for (int r = 0; r < 16; ++r) {
            int nl = (r & 3) + 8 * (r >> 2) + 4 * lsel;
            dst[(bh * NN + n0 + nl) * 32 + l31] = f2b((s[r] + bias) * sc);
        }
    }
}

// ---------------- k_stats: den[m] += sum_{n-chunk} exp2(S'[n,m]) ----------------
// 4 waves own 4 m-tiles (Q in regs); block stages 2 K n-tiles (64 rows) per barrier step.
__global__ __launch_bounds__(256) void k_stats(const bf16* __restrict__ kt,
                                               const bf16* __restrict__ qt,
                                               float* __restrict__ den)
{
    __shared__ __align__(16) bf16 Kb[2][64 * LDP];
    int tid = threadIdx.x, w = tid >> 6, lane = tid & 63;
    int l31 = lane & 31, lsel = lane >> 5;
    int bh = blockIdx.z;
    int mt = blockIdx.x * 4 + w;
    bool act = (mt < 98);
    int m0 = (act ? mt : 97) * 32;
    int ns = blockIdx.y * MCH;

    const bf16* qp = qt + ((size_t)bh * NN + m0 + l31) * 32 + lsel * 8;
    bfrag qb0 = *(const bfrag*)qp;
    bfrag qb1 = *(const bfrag*)(qp + 16);
    const bf16* kt_bh = kt + (size_t)bh * NN * 32;

    int sr = tid >> 2, sc = (tid & 3) * 8;            // 64 rows x 4 chunks
    const bf16* sbase = kt_bh + (size_t)(ns + sr) * 32 + sc;
    int soff = sr * LDP + sc;

    *(bfrag*)(&Kb[0][soff]) = *(const bfrag*)sbase;
    __syncthreads();

    float dacc = 0.f;
    for (int t = 0; t < 7; ++t) {
        bfrag pre;
        bool hn = (t + 1 < 7);
        if (hn) pre = *(const bfrag*)(sbase + (size_t)(t + 1) * 2048);
        const bf16* kl = &Kb[t & 1][0];
        #pragma unroll
        for (int nt = 0; nt < 2; ++nt) {
            int ko = (l31 + 32 * nt) * LDP + lsel * 8;
            bfrag kb0 = *(const bfrag*)(kl + ko);
            bfrag kb1 = *(const bfrag*)(kl + ko + 16);
            f32x16 s;
            #pragma unroll
            for (int r = 0; r < 16; ++r) s[r] = 0.f;
            s = MFMA32(kb0, qb0, s);
            s = MFMA32(kb1, qb1, s);
            float ps = 0.f;
            #pragma unroll
            for (int r = 0; r < 16; ++r) ps += fexp2(s[r]);
            dacc += ps;
        }
        if (hn) *(bfrag*)(&Kb[(t + 1) & 1][soff]) = pre;
        __syncthreads();
    }
    dacc += __shfl_xor(dacc, 32);
    if (act && lane < 32) atomicAdd(&den[(size_t)bh * NN + m0 + l31], dacc);
}

__global__ __launch_bounds__(256) void k_recip(float* __restrict__ den)
{
    int i = blockIdx.x * 256 + threadIdx.x;
    if (i < NBH * NN) den[i] = 1.0f / den[i];
}

__global__ __launch_bounds__(256) void k_scalev(bf16* __restrict__ vt, const float* __restrict__ rden)
{
    int by = blockIdx.y;
    const float* rdp = rden + ((size_t)(by >> 5)) * NN;
    bf16* vp = vt + (size_t)by * NN;
    for (int m = blockIdx.x * MCH + threadIdx.x; m < blockIdx.x * MCH + MCH && m < NN; m += 256)
        vp[m] = f2b(b2f(vp[m]) * rdp[m]);
}

// ---------------- k_av: av[n,0:32] += sum_m exp2(S'[n,m]) * V'[m,e]; 2 m-tiles/step ----------------
__global__ __launch_bounds__(256) void k_av(const bf16* __restrict__ kt,
    const bf16* __restrict__ qt, const bf16* __restrict__ vtp,
    float* __restrict__ av_acc)
{
    __shared__ __align__(16) bf16 Qb[2][64 * LDP];   // 64 m-rows x 32 cols
    __shared__ __align__(16) bf16 Vb[2][32 * LDPA];  // 32 e-rows x 64 m-cols
    int tid = threadIdx.x, w = tid >> 6, lane = tid & 63;
    int l31 = lane & 31, lsel = lane >> 5;
    int bh = blockIdx.z;
    int ntile = blockIdx.x * 4 + w;
    bool act = (ntile < 98);
    int n0 = (act ? ntile : 97) * 32;
    int ms = blockIdx.y * MCH;

    const bf16* kp = kt + ((size_t)bh * NN + n0 + l31) * 32 + lsel * 8;
    bfrag kb0 = *(const bfrag*)kp;
    bfrag kb1 = *(const bfrag*)(kp + 16);
    const bf16* qt_bh = qt + (size_t)bh * NN * 32;
    const bf16* vt_bh = vtp + (size_t)bh * 32 * NN;

    int qr = tid >> 2, qc = (tid & 3) * 8;
    const bf16* qsb = qt_bh + (size_t)(ms + qr) * 32 + qc;
    int qoff = qr * LDP + qc;
    int vr = tid >> 3, vc = (tid & 7) * 8;
    const bf16* vsb = vt_bh + (size_t)vr * NN + ms + vc;
    int voff = vr * LDPA + vc;

    *(bfrag*)(&Qb[0][qoff]) = *(const bfrag*)qsb;
    *(bfrag*)(&Vb[0][voff]) = *(const bfrag*)vsb;
    __syncthreads();

    f32x16 acc;
    #pragma unroll
    for (int r = 0; r < 16; ++r) acc[r] = 0.f;

    for (int t = 0; t < 7; ++t) {
        bfrag preQ, preV;
        bool hn = (t + 1 < 7);
        if (hn) {
            preQ = *(const bfrag*)(qsb + (size_t)(t + 1) * 2048);
            preV = *(const bfrag*)(vsb + (size_t)(t + 1) * 64);
        }
        const bf16* ql = &Qb[t & 1][0];
        const bf16* vl = &Vb[t & 1][0];
        #pragma unroll
        for (int mt2 = 0; mt2 < 2; ++mt2) {
            int qo = (l31 + 32 * mt2) * LDP + lsel * 8;
            bfrag q0 = *(const bfrag*)(ql + qo);
            bfrag q1 = *(const bfrag*)(ql + qo + 16);
            f32x16 s;
            #pragma unroll
            for (int r = 0; r < 16; ++r) s[r] = 0.f;
            s = MFMA32(q0, kb0, s);
            s = MFMA32(q1, kb1, s);
            union { unsigned short us[8]; bfrag v; } pa0, pa1;
            #pragma unroll
            for (int i = 0; i < 8; ++i) {
                bf16 e0 = f2b(fexp2(s[i]));
                bf16 e1 = f2b(fexp2(s[8 + i]));
                pa0.us[i] = *(unsigned short*)&e0;
                pa1.us[i] = *(unsigned short*)&e1;
            }
            const bf16* vrow = vl + l31 * LDPA + 32 * mt2 + lsel * 4;
            union { s16x4 h[2]; bfrag v; } vb0, vb1;
            vb0.h[0] = *(const s16x4*)(vrow);
            vb0.h[1] = *(const s16x4*)(vrow + 8);
            vb1.h[0] = *(const s16x4*)(vrow + 16);
            vb1.h[1] = *(const s16x4*)(vrow + 24);
            acc = MFMA32(pa0.v, vb0.v, acc);
            acc = MFMA32(pa1.v, vb1.v, acc);
        }
        if (hn) {
            *(bfrag*)(&Qb[(t + 1) & 1][qoff]) = preQ;
            *(bfrag*)(&Vb[(t + 1) & 1][voff]) = preV;
        }
        __syncthreads();
    }
    if (act) {
        float* dst = av_acc + ((size_t)bh * NN + n0) * 32 + l31;
        #pragma unroll
        for (int r = 0; r < 16; ++r) {
            int nl = (r & 3) + 8 * (r >> 2) + 4 * lsel;
            atomicAdd(dst + (size_t)nl * 32, acc[r]);
        }
    }
}

// ---------------- k_av2: av2[n,0:64] += sum_m exp2(S'[n,m]) * awts'[m,e]; 2 m-tiles/step ----------------
__global__ __launch_bounds__(256) void k_av2(const bf16* __restrict__ kt,
    const bf16* __restrict__ qt, const bf16* __restrict__ awts,
    float* __restrict__ av2_acc)
{
    __shared__ __align__(16) bf16 Qb[2][64 * LDP];
    __shared__ __align__(16) bf16 Ab[2][64 * LDPA];
    int tid = threadIdx.x, w = tid >> 6, lane = tid & 63;
    int l31 = lane & 31, lsel = lane >> 5;
    int bh = blockIdx.z;
    int ntile = blockIdx.x * 4 + w;
    bool act = (ntile < 98);
    int n0 = (act ? ntile : 97) * 32;
    int ms = blockIdx.y * MCH;

    const bf16* kp = kt + ((size_t)bh * NN + n0 + l31) * 32 + lsel * 8;
    bfrag kb0 = *(const bfrag*)kp;
    bfrag kb1 = *(const bfrag*)(kp + 16);
    const bf16* qt_bh = qt + (size_t)bh * NN * 32;
    const bf16* aw_bh = awts + (size_t)bh * 64 * NN;

    int qr = tid >> 2, qc = (tid & 3) * 8;
    const bf16* qsb = qt_bh + (size_t)(ms + qr) * 32 + qc;
    int qoff = qr * LDP + qc;
    int ar0 = tid >> 3, acv = (tid & 7) * 8;
    const bf16* asb0 = aw_bh + (size_t)ar0 * NN + ms + acv;
    const bf16* asb1 = aw_bh + (size_t)(ar0 + 32) * NN + ms + acv;
    int aoff0 = ar0 * LDPA + acv;
    int aoff1 = (ar0 + 32) * LDPA + acv;

    *(bfrag*)(&Qb[0][qoff])  = *(const bfrag*)qsb;
    *(bfrag*)(&Ab[0][aoff0]) = *(const bfrag*)asb0;
    *(bfrag*)(&Ab[0][aoff1]) = *(const bfrag*)asb1;
    __syncthreads();

    f32x16 acc0, acc1;
    #pragma unroll
    for (int r = 0; r < 16; ++r) { acc0[r] = 0.f; acc1[r] = 0.f; }

    for (int t = 0; t < 7; ++t) {
        bfrag preQ, preA0, preA1;
        bool hn = (t + 1 < 7);
        if (hn) {
            preQ  = *(const bfrag*)(qsb  + (size_t)(t + 1) * 2048);
            preA0 = *(const bfrag*)(asb0 + (size_t)(t + 1) * 64);
            preA1 = *(const bfrag*)(asb1 + (size_t)(t + 1) * 64);
        }
        const bf16* ql = &Qb[t & 1][0];
        const bf16* al = &Ab[t & 1][0];
        #pragma unroll
        for (int mt2 = 0; mt2 < 2; ++mt2) {
            int qo = (l31 + 32 * mt2) * LDP + lsel * 8;
            bfrag q0 = *(const bfrag*)(ql + qo);
            bfrag q1 = *(const bfrag*)(ql + qo + 16);
            f32x16 s;
            #pragma unroll
            for (int r = 0; r < 16; ++r) s[r] = 0.f;
            s = MFMA32(q0, kb0, s);
            s = MFMA32(q1, kb1, s);
            union { unsigned short us[8]; bfrag v; } pa0, pa1;
            #pragma unroll
            for (int i = 0; i < 8; ++i) {
                bf16 e0 = f2b(fexp2(s[i]));
                bf16 e1 = f2b(fexp2(s[8 + i]));
                pa0.us[i] = *(unsigned short*)&e0;
                pa1.us[i] = *(unsigned short*)&e1;
            }
            const bf16* a0 = al + l31 * LDPA + 32 * mt2 + lsel * 4;
            const bf16* a1 = al + (l31 + 32) * LDPA + 32 * mt2 + lsel * 4;
            union { s16x4 h[2]; bfrag v; } e00, e01, e10, e11;
            e00.h[0] = *(const s16x4*)(a0);
            e00.h[1] = *(const s16x4*)(a0 + 8);
            e01.h[0] = *(const s16x4*)(a0 + 16);
            e01.h[1] = *(const s16x4*)(a0 + 24);
            e10.h[0] = *(const s16x4*)(a1);
            e10.h[1] = *(const s16x4*)(a1 + 8);
            e11.h[0] = *(const s16x4*)(a1 + 16);
            e11.h[1] = *(const s16x4*)(a1 + 24);
            acc0 = MFMA32(pa0.v, e00.v, acc0);
            acc0 = MFMA32(pa1.v, e01.v, acc0);
            acc1 = MFMA32(pa0.v, e10.v, acc1);
            acc1 = MFMA32(pa1.v, e11.v, acc1);
        }
        if (hn) {
            *(bfrag*)(&Qb[(t + 1) & 1][qoff])  = preQ;
            *(bfrag*)(&Ab[(t + 1) & 1][aoff0]) = preA0;
            *(bfrag*)(&Ab[(t + 1) & 1][aoff1]) = preA1;
        }
        __syncthreads();
    }
    if (act) {
        float* dst = av2_acc + ((size_t)bh * NN + n0) * 64 + l31;
        #pragma unroll
        for (int r = 0; r < 16; ++r) {
            int nl = (r & 3) + 8 * (r >> 2) + 4 * lsel;
            atomicAdd(dst + (size_t)nl * 64, acc0[r]);
            atomicAdd(dst + (size_t)nl * 64 + 32, acc1[r]);
        }
    }
}

// ---------------- reduce1: awts' = relu(bn1(av @ w1^T + b1)) * rden -> [bh][64][N] bf16 ----------------
__global__ __launch_bounds__(256) void k_red1(const float* __restrict__ av_acc,
    const float* __restrict__ w1, const float* __restrict__ b1,
    const float* __restrict__ g1, const float* __restrict__ be1,
    const float* __restrict__ rm1, const float* __restrict__ rv1,
    const float* __restrict__ rds,
    bf16* __restrict__ awts)
{
    __shared__ float avl[64 * 33];
    __shared__ float w1l[64 * 33];
    __shared__ float sc[64], sh[64], bb[64];
    int n0 = blockIdx.x * 64, bh = blockIdx.y, h = bh & 3;
    int tid = threadIdx.x;
    const float* ap = av_acc + ((size_t)bh * NN + n0) * 32;
    for (int i = tid; i < 2048; i += 256) {
        avl[(i >> 5) * 33 + (i & 31)] = ap[i];
        w1l[(i >> 5) * 33 + (i & 31)] = w1[i];
    }
    if (tid < 64) {
        int ch = h * 64 + tid;
        float s = g1[ch] * rsqrtf(rv1[ch] + 1e-5f);
        sc[tid] = s; sh[tid] = be1[ch] - rm1[ch] * s; bb[tid] = b1[tid];
    }
    __syncthreads();
    int nb = (tid & 15) * 4, eb = (tid >> 4) * 4;
    float rsc[4];
    {
        const float* rp = rds + (size_t)bh * NN + n0 + nb;
        rsc[0] = rp[0]; rsc[1] = rp[1]; rsc[2] = rp[2]; rsc[3] = rp[3];
    }
    float s[4][4];
    #pragma unroll
    for (int i = 0; i < 4; ++i)
        #pragma unroll
        for (int j = 0; j < 4; ++j) s[i][j] = bb[eb + j];
    for (int d = 0; d < 32; ++d) {
        float a0 = avl[(nb+0)*33+d], a1 = avl[(nb+1)*33+d], a2 = avl[(nb+2)*33+d], a3 = avl[(nb+3)*33+d];
        float w0 = w1l[(eb+0)*33+d], w1v = w1l[(eb+1)*33+d], w2v = w1l[(eb+2)*33+d], w3 = w1l[(eb+3)*33+d];
        s[0][0]+=a0*w0; s[0][1]+=a0*w1v; s[0][2]+=a0*w2v; s[0][3]+=a0*w3;
        s[1][0]+=a1*w0; s[1][1]+=a1*w1v; s[1][2]+=a1*w2v; s[1][3]+=a1*w3;
        s[2][0]+=a2*w0; s[2][1]+=a2*w1v; s[2][2]+=a2*w2v; s[2][3]+=a2*w3;
        s[3][0]+=a3*w0; s[3][1]+=a3*w1v; s[3][2]+=a3*w2v; s[3][3]+=a3*w3;
    }
    #pragma unroll
    for (int j = 0; j < 4; ++j) {
        int e = eb + j;
        ushort4 pk;
        float v0 = fmaxf(s[0][j] * sc[e] + sh[e], 0.f) * rsc[0];
        float v1 = fmaxf(s[1][j] * sc[e] + sh[e], 0.f) * rsc[1];
        float v2 = fmaxf(s[2][j] * sc[e] + sh[e], 0.f) * rsc[2];
        float v3 = fmaxf(s[3][j] * sc[e] + sh[e], 0.f) * rsc[3];
        bf16 b0 = f2b(v0), b1b = f2b(v1), b2b = f2b(v2), b3 = f2b(v3);
        pk.x = *(unsigned short*)&b0; pk.y = *(unsigned short*)&b1b;
        pk.z = *(unsigned short*)&b2b; pk.w = *(unsigned short*)&b3;
        *reinterpret_cast<ushort4*>(awts + ((size_t)bh * 64 + e) * NN + n0 + nb) = pk;
    }
}

// ---------------- reduce2: avw2 = relu(bn2(av2 @ w2^T + b2)) -> y[b][256][N] bf16 ----------------
__global__ __launch_bounds__(256) void k_red2(const float* __restrict__ av2_acc,
    const float* __restrict__ w2, const float* __restrict__ b2,
    const float* __restrict__ g2, const float* __restrict__ be2,
    const float* __restrict__ rm2, const float* __restrict__ rv2,
    bf16* __restrict__ y)
{
    __shared__ float a2l[64 * 65];
    __shared__ float w2l[64 * 65];
    __shared__ float sc[64], sh[64], bb[64];
    int n0 = blockIdx.x * 64, bh = blockIdx.y, h = bh & 3, b = bh >> 2;
    int tid = threadIdx.x;
    const float* ap = av2_acc + ((size_t)bh * NN + n0) * 64;
    for (int i = tid; i < 4096; i += 256) {
        a2l[(i >> 6) * 65 + (i & 63)] = ap[i];
        w2l[(i >> 6) * 65 + (i & 63)] = w2[i];
    }
    if (tid < 64) {
        int ch = h * 64 + tid;
        float s = g2[ch] * rsqrtf(rv2[ch] + 1e-5f);
        sc[tid] = s; sh[tid] = be2[ch] - rm2[ch] * s; bb[tid] = b2[tid];
    }
    __syncthreads();
    int nb = (tid & 15) * 4, eb = (tid >> 4) * 4;
    float s[4][4];
    #pragma unroll
    for (int i = 0; i < 4; ++i)
        #pragma unroll
        for (int j = 0; j < 4; ++j) s[i][j] = bb[eb + j];
    for (int d = 0; d < 64; ++d) {
        float a0 = a2l[(nb+0)*65+d], a1 = a2l[(nb+1)*65+d], a2 = a2l[(nb+2)*65+d], a3 = a2l[(nb+3)*65+d];
        float w0 = w2l[(eb+0)*65+d], w1v = w2l[(eb+1)*65+d], w2v = w2l[(eb+2)*65+d], w3 = w2l[(eb+3)*65+d];
        s[0][0]+=a0*w0; s[0][1]+=a0*w1v; s[0][2]+=a0*w2v; s[0][3]+=a0*w3;
        s[1][0]+=a1*w0; s[1][1]+=a1*w1v; s[1][2]+=a1*w2v; s[1][3]+=a1*w3;
        s[2][0]+=a2*w0; s[2][1]+=a2*w1v; s[2][2]+=a2*w2v; s[2][3]+=a2*w3;
        s[3][0]+=a3*w0; s[3][1]+=a3*w1v; s[3][2]+=a3*w2v; s[3][3]+=a3*w3;
    }
    #pragma unroll
    for (int j = 0; j < 4; ++j) {
        int e = eb + j;
        ushort4 pk;
        float v0 = fmaxf(s[0][j] * sc[e] + sh[e], 0.f);
        float v1 = fmaxf(s[1][j] * sc[e] + sh[e], 0.f);
        float v2 = fmaxf(s[2][j] * sc[e] + sh[e], 0.f);
        float v3 = fmaxf(s[3][j] * sc[e] + sh[e], 0.f);
        bf16 b0 = f2b(v0), b1b = f2b(v1), b2b = f2b(v2), b3 = f2b(v3);
        pk.x = *(unsigned short*)&b0; pk.y = *(unsigned short*)&b1b;
        pk.z = *(unsigned short*)&b2b; pk.w = *(unsigned short*)&b3;
        *reinterpret_cast<ushort4*>(y + ((size_t)b * 256 + h * 64 + e) * NN + n0 + nb) = pk;
    }
}

// ---------------- final 1x1 conv (f32 out), 2 n per thread ----------------
__global__ __launch_bounds__(256) void k_final(const bf16* __restrict__ y,
    const float* __restrict__ wf, const float* __restrict__ bf_,
    float* __restrict__ out)
{
    int t = blockIdx.x * 256 + threadIdx.x;
    int n = t * 2;
    if (n >= NN) return;
    int o = blockIdx.y;
    int b = blockIdx.z;
    float s0 = bf_[o], s1 = s0;
    const bf16* yp = y + (size_t)b * 256 * NN + n;
    const float* wp = wf + o * 256;
    #pragma unroll 8
    for (int k = 0; k < 256; ++k) {
        unsigned u = *reinterpret_cast<const unsigned*>(yp + (size_t)k * NN);
        float lo = __uint_as_float(u << 16);
        float hi = __uint_as_float(u & 0xffff0000u);
        s0 += wp[k] * lo;
        s1 += wp[k] * hi;
    }
    float* op = out + ((size_t)b * 64 + o) * NN + n;
    op[0] = s0;
    op[1] = s1;
}

extern "C" void kernel_launch(void* const* d_in, const int* in_sizes, int n_in,
                              void* d_out, int out_size, void* d_ws, size_t ws_size,
                              hipStream_t stream)
{
    const float* x   = (const float*)d_in[0];
    const float* wk  = (const float*)d_in[1];
    const float* bk  = (const float*)d_in[2];
    const float* wq  = (const float*)d_in[3];
    const float* bq  = (const float*)d_in[4];
    const float* wv  = (const float*)d_in[5];
    const float* bv  = (const float*)d_in[6];
    const float* w1  = (const float*)d_in[7];
    const float* b1  = (const float*)d_in[8];
    const float* g1  = (const float*)d_in[9];
    const float* be1 = (const float*)d_in[10];
    const float* rm1 = (const float*)d_in[11];
    const float* rv1 = (const float*)d_in[12];
    const float* w2  = (const float*)d_in[13];
    const float* b2  = (const float*)d_in[14];
    const float* g2  = (const float*)d_in[15];
    const float* be2 = (const float*)d_in[16];
    const float* rm2 = (const float*)d_in[17];
    const float* rv2 = (const float*)d_in[18];
    const float* wf  = (const float*)d_in[19];
    const float* bff = (const float*)d_in[20];
    float* out = (float*)d_out;

    char* ws = (char*)d_ws;
    bf16* kt   = (bf16*)ws;
    bf16* qt   = kt + (size_t)NBH * NN * 32;
    bf16* vt   = qt + (size_t)NBH * NN * 32;
    bf16* awts = vt + (size_t)NBH * 32 * NN;
    bf16* y    = awts + (size_t)NBH * 64 * NN;
    float* den     = (float*)(y + (size_t)2 * 256 * NN);
    float* av_acc  = den + (size_t)NBH * NN;
    float* av2_acc = av_acc + (size_t)NBH * NN * 32;

    k_zero  <<<dim3(2377),     256, 0, stream>>>(den, 608384);
    k_proj  <<<dim3(98, 3, 2), 256, 0, stream>>>(x, wk, bk, wq, bq, wv, bv, kt, qt, vt);
    k_stats <<<dim3(25, 7, 8), 256, 0, stream>>>(kt, qt, den);
    k_recip <<<dim3(98),       256, 0, stream>>>(den);
    k_scalev<<<dim3(7, 256),   256, 0, stream>>>(vt, den);
    k_av    <<<dim3(25, 7, 8), 256, 0, stream>>>(kt, qt, vt, av_acc);
    k_red1  <<<dim3(49, 8),    256, 0, stream>>>(av_acc, w1, b1, g1, be1, rm1, rv1, den, awts);
    k_av2   <<<dim3(25, 7, 8), 256, 0, stream>>>(kt, qt, awts, av2_acc);
    k_red2  <<<dim3(49, 8),    256, 0, stream>>>(av2_acc, w2, b2, g2, be2, rm2, rv2, y);
    k_final <<<dim3(7, 64, 2), 256, 0, stream>>>(y, wf, bff, out);
}

// Round 16
// 120.235 us; speedup vs baseline: 1.6678x; 1.1808x over previous
//
#include <hip/hip_runtime.h>
#include <hip/hip_bf16.h>

typedef __hip_bfloat16 bf16;
typedef __attribute__((ext_vector_type(8))) short bfrag;    // 8 x bf16 (16 B)
typedef __attribute__((ext_vector_type(4))) short s16x4;    // 4 x bf16 (8 B)
typedef __attribute__((ext_vector_type(4))) float f32x4;
typedef __attribute__((ext_vector_type(16))) float f32x16;

#define MFMA32(a,b,c) __builtin_amdgcn_mfma_f32_32x32x16_bf16((a),(b),(c),0,0,0)

__device__ __forceinline__ float b2f(bf16 x){ return __bfloat162float(x); }
__device__ __forceinline__ bf16 f2b(float x){ return __float2bfloat16(x); }
__device__ __forceinline__ float fexp2(float x){ return __builtin_amdgcn_exp2f(x); }

#define NN   3136   // 56*56 = 98 tiles of 32
#define NBH  8      // B * NH
#define NCH  7      // m-chunks
#define MCH  448    // m/n chunk = 14 tiles of 32 = 7 double-steps of 64
#define LDP  40     // LDS row stride for 32-col tiles (80 B; known-good)
#define LDPA 72     // LDS row stride for 64-col tiles (144 B)
#define LOG2E 1.44269504f

// ---------------- zero den ----------------
__global__ __launch_bounds__(256) void k_zero(float* __restrict__ p, int n4)
{
    int i = blockIdx.x * 256 + threadIdx.x;
    if (i < n4) reinterpret_cast<f32x4*>(p)[i] = (f32x4){0.f, 0.f, 0.f, 0.f};
}

// ---------------- QKV projections via MFMA ----------------
__global__ __launch_bounds__(256) void k_proj(
    const float* __restrict__ x,
    const float* __restrict__ wk, const float* __restrict__ bk,
    const float* __restrict__ wq, const float* __restrict__ bq,
    const float* __restrict__ wv, const float* __restrict__ bv,
    bf16* __restrict__ kt, bf16* __restrict__ qt, bf16* __restrict__ vt)
{
    __shared__ __align__(16) bf16 xT[32 * 72];
    __shared__ __align__(16) bf16 wT[128 * 72];
    int tid = threadIdx.x, w = tid >> 6, lane = tid & 63;
    int l31 = lane & 31, lsel = lane >> 5;
    int n0 = blockIdx.x * 32;
    int p  = blockIdx.y;     // 0=K 1=Q 2=V
    int b  = blockIdx.z;
    const float* wp = (p == 0) ? wk : ((p == 1) ? wq : wv);
    const float* bp = (p == 0) ? bk : ((p == 1) ? bq : bv);

    for (int i = tid; i < 2048; i += 256) {
        int c = i >> 5, j = i & 31;
        xT[j * 72 + c] = f2b(x[((size_t)b * 64 + c) * NN + n0 + j]);
    }
    for (int i = tid; i < 8192; i += 256) {
        int oc = i >> 6, c = i & 63;
        wT[oc * 72 + c] = f2b(wp[oc * 64 + c]);
    }
    __syncthreads();

    f32x16 s;
    #pragma unroll
    for (int r = 0; r < 16; ++r) s[r] = 0.f;
    #pragma unroll
    for (int k = 0; k < 4; ++k) {
        bfrag a  = *(const bfrag*)(&xT[l31 * 72 + k * 16 + lsel * 8]);
        bfrag bw = *(const bfrag*)(&wT[(w * 32 + l31) * 72 + k * 16 + lsel * 8]);
        s = MFMA32(a, bw, s);   // D[row=n][col=oc=l31]
    }
    float bias = bp[w * 32 + l31];
    size_t bh = (size_t)b * 4 + w;
    if (p == 2) {
        #pragma unroll
        for (int q = 0; q < 4; ++q) {
            s16x4 pk;
            #pragma unroll
            for (int i = 0; i < 4; ++i) {
                bf16 e = f2b(s[4 * q + i] + bias);
                pk[i] = *(short*)&e;
            }
            *(s16x4*)(vt + (bh * 32 + l31) * NN + n0 + 8 * q + 4 * lsel) = pk;
        }
    } else {
        bf16* dst = (p == 0) ? kt : qt;
        float sc = (p == 0) ? LOG2E : 1.0f;
        #pragma unroll
        for (int r = 0; r < 16; ++r) {
            int nl = (r & 3) + 8 * (r >> 2) + 4 * lsel;
            dst[(bh * NN + n0 + nl) * 32 + l31] = f2b((s[r] + bias) * sc);
        }
    }
}

// ---------------- k_stats: den[m] += sum_{n-chunk} exp2(S'[n,m]) ----------------
__global__ __launch_bounds__(256) void k_stats(const bf16* __restrict__ kt,
                                               const bf16* __restrict__ qt,
                                               float* __restrict__ den)
{
    __shared__ __align__(16) bf16 Kb[2][64 * LDP];
    int tid = threadIdx.x, w = tid >> 6, lane = tid & 63;
    int l31 = lane & 31, lsel = lane >> 5;
    int bh = blockIdx.z;
    int mt = blockIdx.x * 4 + w;
    bool act = (mt < 98);
    int m0 = (act ? mt : 97) * 32;
    int ns = blockIdx.y * MCH;

    const bf16* qp = qt + ((size_t)bh * NN + m0 + l31) * 32 + lsel * 8;
    bfrag qb0 = *(const bfrag*)qp;
    bfrag qb1 = *(const bfrag*)(qp + 16);
    const bf16* kt_bh = kt + (size_t)bh * NN * 32;

    int sr = tid >> 2, sc = (tid & 3) * 8;
    const bf16* sbase = kt_bh + (size_t)(ns + sr) * 32 + sc;
    int soff = sr * LDP + sc;

    *(bfrag*)(&Kb[0][soff]) = *(const bfrag*)sbase;
    __syncthreads();

    float dacc = 0.f;
    for (int t = 0; t < 7; ++t) {
        bfrag pre;
        bool hn = (t + 1 < 7);
        if (hn) pre = *(const bfrag*)(sbase + (size_t)(t + 1) * 2048);
        const bf16* kl = &Kb[t & 1][0];
        #pragma unroll
        for (int nt = 0; nt < 2; ++nt) {
            int ko = (l31 + 32 * nt) * LDP + lsel * 8;
            bfrag kb0 = *(const bfrag*)(kl + ko);
            bfrag kb1 = *(const bfrag*)(kl + ko + 16);
            f32x16 s;
            #pragma unroll
            for (int r = 0; r < 16; ++r) s[r] = 0.f;
            s = MFMA32(kb0, qb0, s);
            s = MFMA32(kb1, qb1, s);
            float ps = 0.f;
            #pragma unroll
            for (int r = 0; r < 16; ++r) ps += fexp2(s[r]);
            dacc += ps;
        }
        if (hn) *(bfrag*)(&Kb[(t + 1) & 1][soff]) = pre;
        __syncthreads();
    }
    dacc += __shfl_xor(dacc, 32);
    if (act && lane < 32) atomicAdd(&den[(size_t)bh * NN + m0 + l31], dacc);
}

__global__ __launch_bounds__(256) void k_recip(float* __restrict__ den)
{
    int i = blockIdx.x * 256 + threadIdx.x;
    if (i < NBH * NN) den[i] = 1.0f / den[i];
}

__global__ __launch_bounds__(256) void k_scalev(bf16* __restrict__ vt, const float* __restrict__ rden)
{
    int by = blockIdx.y;
    const float* rdp = rden + ((size_t)(by >> 5)) * NN;
    bf16* vp = vt + (size_t)by * NN;
    for (int m = blockIdx.x * MCH + threadIdx.x; m < blockIdx.x * MCH + MCH && m < NN; m += 256)
        vp[m] = f2b(b2f(vp[m]) * rdp[m]);
}

// ---------------- k_av: partial av to private slab (plain stores, no atomics) ----------------
__global__ __launch_bounds__(256) void k_av(const bf16* __restrict__ kt,
    const bf16* __restrict__ qt, const bf16* __restrict__ vtp,
    float* __restrict__ av_p)
{
    __shared__ __align__(16) bf16 Qb[2][64 * LDP];
    __shared__ __align__(16) bf16 Vb[2][32 * LDPA];
    int tid = threadIdx.x, w = tid >> 6, lane = tid & 63;
    int l31 = lane & 31, lsel = lane >> 5;
    int bh = blockIdx.z;
    int ntile = blockIdx.x * 4 + w;
    bool act = (ntile < 98);
    int n0 = (act ? ntile : 97) * 32;
    int ms = blockIdx.y * MCH;

    const bf16* kp = kt + ((size_t)bh * NN + n0 + l31) * 32 + lsel * 8;
    bfrag kb0 = *(const bfrag*)kp;
    bfrag kb1 = *(const bfrag*)(kp + 16);
    const bf16* qt_bh = qt + (size_t)bh * NN * 32;
    const bf16* vt_bh = vtp + (size_t)bh * 32 * NN;

    int qr = tid >> 2, qc = (tid & 3) * 8;
    const bf16* qsb = qt_bh + (size_t)(ms + qr) * 32 + qc;
    int qoff = qr * LDP + qc;
    int vr = tid >> 3, vc = (tid & 7) * 8;
    const bf16* vsb = vt_bh + (size_t)vr * NN + ms + vc;
    int voff = vr * LDPA + vc;

    *(bfrag*)(&Qb[0][qoff]) = *(const bfrag*)qsb;
    *(bfrag*)(&Vb[0][voff]) = *(const bfrag*)vsb;
    __syncthreads();

    f32x16 acc;
    #pragma unroll
    for (int r = 0; r < 16; ++r) acc[r] = 0.f;

    for (int t = 0; t < 7; ++t) {
        bfrag preQ, preV;
        bool hn = (t + 1 < 7);
        if (hn) {
            preQ = *(const bfrag*)(qsb + (size_t)(t + 1) * 2048);
            preV = *(const bfrag*)(vsb + (size_t)(t + 1) * 64);
        }
        const bf16* ql = &Qb[t & 1][0];
        const bf16* vl = &Vb[t & 1][0];
        #pragma unroll
        for (int mt2 = 0; mt2 < 2; ++mt2) {
            int qo = (l31 + 32 * mt2) * LDP + lsel * 8;
            bfrag q0 = *(const bfrag*)(ql + qo);
            bfrag q1 = *(const bfrag*)(ql + qo + 16);
            f32x16 s;
            #pragma unroll
            for (int r = 0; r < 16; ++r) s[r] = 0.f;
            s = MFMA32(q0, kb0, s);
            s = MFMA32(q1, kb1, s);
            union { unsigned short us[8]; bfrag v; } pa0, pa1;
            #pragma unroll
            for (int i = 0; i < 8; ++i) {
                bf16 e0 = f2b(fexp2(s[i]));
                bf16 e1 = f2b(fexp2(s[8 + i]));
                pa0.us[i] = *(unsigned short*)&e0;
                pa1.us[i] = *(unsigned short*)&e1;
            }
            const bf16* vrow = vl + l31 * LDPA + 32 * mt2 + lsel * 4;
            union { s16x4 h[2]; bfrag v; } vb0, vb1;
            vb0.h[0] = *(const s16x4*)(vrow);
            vb0.h[1] = *(const s16x4*)(vrow + 8);
            vb1.h[0] = *(const s16x4*)(vrow + 16);
            vb1.h[1] = *(const s16x4*)(vrow + 24);
            acc = MFMA32(pa0.v, vb0.v, acc);
            acc = MFMA32(pa1.v, vb1.v, acc);
        }
        if (hn) {
            *(bfrag*)(&Qb[(t + 1) & 1][qoff]) = preQ;
            *(bfrag*)(&Vb[(t + 1) & 1][voff]) = preV;
        }
        __syncthreads();
    }
    if (act) {
        float* dst = av_p + (size_t)blockIdx.y * ((size_t)NBH * NN * 32)
                   + ((size_t)bh * NN + n0) * 32 + l31;
        #pragma unroll
        for (int r = 0; r < 16; ++r) {
            int nl = (r & 3) + 8 * (r >> 2) + 4 * lsel;
            dst[(size_t)nl * 32] = acc[r];
        }
    }
}

// ---------------- k_av2: partial av2 to private slab (plain stores) ----------------
__global__ __launch_bounds__(256) void k_av2(const bf16* __restrict__ kt,
    const bf16* __restrict__ qt, const bf16* __restrict__ awts,
    float* __restrict__ av2_p)
{
    __shared__ __align__(16) bf16 Qb[2][64 * LDP];
    __shared__ __align__(16) bf16 Ab[2][64 * LDPA];
    int tid = threadIdx.x, w = tid >> 6, lane = tid & 63;
    int l31 = lane & 31, lsel = lane >> 5;
    int bh = blockIdx.z;
    int ntile = blockIdx.x * 4 + w;
    bool act = (ntile < 98);
    int n0 = (act ? ntile : 97) * 32;
    int ms = blockIdx.y * MCH;

    const bf16* kp = kt + ((size_t)bh * NN + n0 + l31) * 32 + lsel * 8;
    bfrag kb0 = *(const bfrag*)kp;
    bfrag kb1 = *(const bfrag*)(kp + 16);
    const bf16* qt_bh = qt + (size_t)bh * NN * 32;
    const bf16* aw_bh = awts + (size_t)bh * 64 * NN;

    int qr = tid >> 2, qc = (tid & 3) * 8;
    const bf16* qsb = qt_bh + (size_t)(ms + qr) * 32 + qc;
    int qoff = qr * LDP + qc;
    int ar0 = tid >> 3, acv = (tid & 7) * 8;
    const bf16* asb0 = aw_bh + (size_t)ar0 * NN + ms + acv;
    const bf16* asb1 = aw_bh + (size_t)(ar0 + 32) * NN + ms + acv;
    int aoff0 = ar0 * LDPA + acv;
    int aoff1 = (ar0 + 32) * LDPA + acv;

    *(bfrag*)(&Qb[0][qoff])  = *(const bfrag*)qsb;
    *(bfrag*)(&Ab[0][aoff0]) = *(const bfrag*)asb0;
    *(bfrag*)(&Ab[0][aoff1]) = *(const bfrag*)asb1;
    __syncthreads();

    f32x16 acc0, acc1;
    #pragma unroll
    for (int r = 0; r < 16; ++r) { acc0[r] = 0.f; acc1[r] = 0.f; }

    for (int t = 0; t < 7; ++t) {
        bfrag preQ, preA0, preA1;
        bool hn = (t + 1 < 7);
        if (hn) {
            preQ  = *(const bfrag*)(qsb  + (size_t)(t + 1) * 2048);
            preA0 = *(const bfrag*)(asb0 + (size_t)(t + 1) * 64);
            preA1 = *(const bfrag*)(asb1 + (size_t)(t + 1) * 64);
        }
        const bf16* ql = &Qb[t & 1][0];
        const bf16* al = &Ab[t & 1][0];
        #pragma unroll
        for (int mt2 = 0; mt2 < 2; ++mt2) {
            int qo = (l31 + 32 * mt2) * LDP + lsel * 8;
            bfrag q0 = *(const bfrag*)(ql + qo);
            bfrag q1 = *(const bfrag*)(ql + qo + 16);
            f32x16 s;
            #pragma unroll
            for (int r = 0; r < 16; ++r) s[r] = 0.f;
            s = MFMA32(q0, kb0, s);
            s = MFMA32(q1, kb1, s);
            union { unsigned short us[8]; bfrag v; } pa0, pa1;
            #pragma unroll
            for (int i = 0; i < 8; ++i) {
                bf16 e0 = f2b(fexp2(s[i]));
                bf16 e1 = f2b(fexp2(s[8 + i]));
                pa0.us[i] = *(unsigned short*)&e0;
                pa1.us[i] = *(unsigned short*)&e1;
            }
            const bf16* a0 = al + l31 * LDPA + 32 * mt2 + lsel * 4;
            const bf16* a1 = al + (l31 + 32) * LDPA + 32 * mt2 + lsel * 4;
            union { s16x4 h[2]; bfrag v; } e00, e01, e10, e11;
            e00.h[0] = *(const s16x4*)(a0);
            e00.h[1] = *(const s16x4*)(a0 + 8);
            e01.h[0] = *(const s16x4*)(a0 + 16);
            e01.h[1] = *(const s16x4*)(a0 + 24);
            e10.h[0] = *(const s16x4*)(a1);
            e10.h[1] = *(const s16x4*)(a1 + 8);
            e11.h[0] = *(const s16x4*)(a1 + 16);
            e11.h[1] = *(const s16x4*)(a1 + 24);
            acc0 = MFMA32(pa0.v, e00.v, acc0);
            acc0 = MFMA32(pa1.v, e01.v, acc0);
            acc1 = MFMA32(pa0.v, e10.v, acc1);
            acc1 = MFMA32(pa1.v, e11.v, acc1);
        }
        if (hn) {
            *(bfrag*)(&Qb[(t + 1) & 1][qoff])  = preQ;
            *(bfrag*)(&Ab[(t + 1) & 1][aoff0]) = preA0;
            *(bfrag*)(&Ab[(t + 1) & 1][aoff1]) = preA1;
        }
        __syncthreads();
    }
    if (act) {
        float* dst = av2_p + (size_t)blockIdx.y * ((size_t)NBH * NN * 64)
                   + ((size_t)bh * NN + n0) * 64 + l31;
        #pragma unroll
        for (int r = 0; r < 16; ++r) {
            int nl = (r & 3) + 8 * (r >> 2) + 4 * lsel;
            dst[(size_t)nl * 64]      = acc0[r];
            dst[(size_t)nl * 64 + 32] = acc1[r];
        }
    }
}

// ---------------- reduce1: sum 7 partials, bn1+relu+rden -> awts bf16 ----------------
__global__ __launch_bounds__(256) void k_red1(const float* __restrict__ av_p,
    const float* __restrict__ w1, const float* __restrict__ b1,
    const float* __restrict__ g1, const float* __restrict__ be1,
    const float* __restrict__ rm1, const float* __restrict__ rv1,
    const float* __restrict__ rds,
    bf16* __restrict__ awts)
{
    __shared__ float avl[64 * 33];
    __shared__ float w1l[64 * 33];
    __shared__ float sc[64], sh[64], bb[64];
    int n0 = blockIdx.x * 64, bh = blockIdx.y, h = bh & 3;
    int tid = threadIdx.x;
    const size_t cstride = (size_t)NBH * NN * 32;
    const float* ap = av_p + ((size_t)bh * NN + n0) * 32;
    for (int i = tid; i < 2048; i += 256) {
        float s = 0.f;
        #pragma unroll
        for (int c = 0; c < NCH; ++c) s += ap[(size_t)c * cstride + i];
        avl[(i >> 5) * 33 + (i & 31)] = s;
        w1l[(i >> 5) * 33 + (i & 31)] = w1[i];
    }
    if (tid < 64) {
        int ch = h * 64 + tid;
        float s = g1[ch] * rsqrtf(rv1[ch] + 1e-5f);
        sc[tid] = s; sh[tid] = be1[ch] - rm1[ch] * s; bb[tid] = b1[tid];
    }
    __syncthreads();
    int nb = (tid & 15) * 4, eb = (tid >> 4) * 4;
    float rsc[4];
    {
        const float* rp = rds + (size_t)bh * NN + n0 + nb;
        rsc[0] = rp[0]; rsc[1] = rp[1]; rsc[2] = rp[2]; rsc[3] = rp[3];
    }
    float s[4][4];
    #pragma unroll
    for (int i = 0; i < 4; ++i)
        #pragma unroll
        for (int j = 0; j < 4; ++j) s[i][j] = bb[eb + j];
    for (int d = 0; d < 32; ++d) {
        float a0 = avl[(nb+0)*33+d], a1 = avl[(nb+1)*33+d], a2 = avl[(nb+2)*33+d], a3 = avl[(nb+3)*33+d];
        float w0 = w1l[(eb+0)*33+d], w1v = w1l[(eb+1)*33+d], w2v = w1l[(eb+2)*33+d], w3 = w1l[(eb+3)*33+d];
        s[0][0]+=a0*w0; s[0][1]+=a0*w1v; s[0][2]+=a0*w2v; s[0][3]+=a0*w3;
        s[1][0]+=a1*w0; s[1][1]+=a1*w1v; s[1][2]+=a1*w2v; s[1][3]+=a1*w3;
        s[2][0]+=a2*w0; s[2][1]+=a2*w1v; s[2][2]+=a2*w2v; s[2][3]+=a2*w3;
        s[3][0]+=a3*w0; s[3][1]+=a3*w1v; s[3][2]+=a3*w2v; s[3][3]+=a3*w3;
    }
    #pragma unroll
    for (int j = 0; j < 4; ++j) {
        int e = eb + j;
        ushort4 pk;
        float v0 = fmaxf(s[0][j] * sc[e] + sh[e], 0.f) * rsc[0];
        float v1 = fmaxf(s[1][j] * sc[e] + sh[e], 0.f) * rsc[1];
        float v2 = fmaxf(s[2][j] * sc[e] + sh[e], 0.f) * rsc[2];
        float v3 = fmaxf(s[3][j] * sc[e] + sh[e], 0.f) * rsc[3];
        bf16 b0 = f2b(v0), b1b = f2b(v1), b2b = f2b(v2), b3 = f2b(v3);
        pk.x = *(unsigned short*)&b0; pk.y = *(unsigned short*)&b1b;
        pk.z = *(unsigned short*)&b2b; pk.w = *(unsigned short*)&b3;
        *reinterpret_cast<ushort4*>(awts + ((size_t)bh * 64 + e) * NN + n0 + nb) = pk;
    }
}

// ---------------- reduce2: sum 7 partials, bn2+relu -> y bf16 ----------------
__global__ __launch_bounds__(256) void k_red2(const float* __restrict__ av2_p,
    const float* __restrict__ w2, const float* __restrict__ b2,
    const float* __restrict__ g2, const float* __restrict__ be2,
    const float* __restrict__ rm2, const float* __restrict__ rv2,
    bf16* __restrict__ y)
{
    __shared__ float a2l[64 * 65];
    __shared__ float w2l[64 * 65];
    __shared__ float sc[64], sh[64], bb[64];
    int n0 = blockIdx.x * 64, bh = blockIdx.y, h = bh & 3, b = bh >> 2;
    int tid = threadIdx.x;
    const size_t cstride = (size_t)NBH * NN * 64;
    const float* ap = av2_p + ((size_t)bh * NN + n0) * 64;
    for (int i = tid; i < 4096; i += 256) {
        float s = 0.f;
        #pragma unroll
        for (int c = 0; c < NCH; ++c) s += ap[(size_t)c * cstride + i];
        a2l[(i >> 6) * 65 + (i & 63)] = s;
        w2l[(i >> 6) * 65 + (i & 63)] = w2[i];
    }
    if (tid < 64) {
        int ch = h * 64 + tid;
        float s = g2[ch] * rsqrtf(rv2[ch] + 1e-5f);
        sc[tid] = s; sh[tid] = be2[ch] - rm2[ch] * s; bb[tid] = b2[tid];
    }
    __syncthreads();
    int nb = (tid & 15) * 4, eb = (tid >> 4) * 4;
    float s[4][4];
    #pragma unroll
    for (int i = 0; i < 4; ++i)
        #pragma unroll
        for (int j = 0; j < 4; ++j) s[i][j] = bb[eb + j];
    for (int d = 0; d < 64; ++d) {
        float a0 = a2l[(nb+0)*65+d], a1 = a2l[(nb+1)*65+d], a2 = a2l[(nb+2)*65+d], a3 = a2l[(nb+3)*65+d];
        float w0 = w2l[(eb+0)*65+d], w1v = w2l[(eb+1)*65+d], w2v = w2l[(eb+2)*65+d], w3 = w2l[(eb+3)*65+d];
        s[0][0]+=a0*w0; s[0][1]+=a0*w1v; s[0][2]+=a0*w2v; s[0][3]+=a0*w3;
        s[1][0]+=a1*w0; s[1][1]+=a1*w1v; s[1][2]+=a1*w2v; s[1][3]+=a1*w3;
        s[2][0]+=a2*w0; s[2][1]+=a2*w1v; s[2][2]+=a2*w2v; s[2][3]+=a2*w3;
        s[3][0]+=a3*w0; s[3][1]+=a3*w1v; s[3][2]+=a3*w2v; s[3][3]+=a3*w3;
    }
    #pragma unroll
    for (int j = 0; j < 4; ++j) {
        int e = eb + j;
        ushort4 pk;
        float v0 = fmaxf(s[0][j] * sc[e] + sh[e], 0.f);
        float v1 = fmaxf(s[1][j] * sc[e] + sh[e], 0.f);
        float v2 = fmaxf(s[2][j] * sc[e] + sh[e], 0.f);
        float v3 = fmaxf(s[3][j] * sc[e] + sh[e], 0.f);
        bf16 b0 = f2b(v0), b1b = f2b(v1), b2b = f2b(v2), b3 = f2b(v3);
        pk.x = *(unsigned short*)&b0; pk.y = *(unsigned short*)&b1b;
        pk.z = *(unsigned short*)&b2b; pk.w = *(unsigned short*)&b3;
        *reinterpret_cast<ushort4*>(y + ((size_t)b * 256 + h * 64 + e) * NN + n0 + nb) = pk;
    }
}

// ---------------- final 1x1 conv (f32 out), 2 n per thread ----------------
__global__ __launch_bounds__(256) void k_final(const bf16* __restrict__ y,
    const float* __restrict__ wf, const float* __restrict__ bf_,
    float* __restrict__ out)
{
    int t = blockIdx.x * 256 + threadIdx.x;
    int n = t * 2;
    if (n >= NN) return;
    int o = blockIdx.y;
    int b = blockIdx.z;
    float s0 = bf_[o], s1 = s0;
    const bf16* yp = y + (size_t)b * 256 * NN + n;
    const float* wp = wf + o * 256;
    #pragma unroll 8
    for (int k = 0; k < 256; ++k) {
        unsigned u = *reinterpret_cast<const unsigned*>(yp + (size_t)k * NN);
        float lo = __uint_as_float(u << 16);
        float hi = __uint_as_float(u & 0xffff0000u);
        s0 += wp[k] * lo;
        s1 += wp[k] * hi;
    }
    float* op = out + ((size_t)b * 64 + o) * NN + n;
    op[0] = s0;
    op[1] = s1;
}

extern "C" void kernel_launch(void* const* d_in, const int* in_sizes, int n_in,
                              void* d_out, int out_size, void* d_ws, size_t ws_size,
                              hipStream_t stream)
{
    const float* x   = (const float*)d_in[0];
    const float* wk  = (const float*)d_in[1];
    const float* bk  = (const float*)d_in[2];
    const float* wq  = (const float*)d_in[3];
    const float* bq  = (const float*)d_in[4];
    const float* wv  = (const float*)d_in[5];
    const float* bv  = (const float*)d_in[6];
    const float* w1  = (const float*)d_in[7];
    const float* b1  = (const float*)d_in[8];
    const float* g1  = (const float*)d_in[9];
    const float* be1 = (const float*)d_in[10];
    const float* rm1 = (const float*)d_in[11];
    const float* rv1 = (const float*)d_in[12];
    const float* w2  = (const float*)d_in[13];
    const float* b2  = (const float*)d_in[14];
    const float* g2  = (const float*)d_in[15];
    const float* be2 = (const float*)d_in[16];
    const float* rm2 = (const float*)d_in[17];
    const float* rv2 = (const float*)d_in[18];
    const float* wf  = (const float*)d_in[19];
    const float* bff = (const float*)d_in[20];
    float* out = (float*)d_out;

    char* ws = (char*)d_ws;
    bf16* kt   = (bf16*)ws;
    bf16* qt   = kt + (size_t)NBH * NN * 32;
    bf16* vt   = qt + (size_t)NBH * NN * 32;
    bf16* awts = vt + (size_t)NBH * 32 * NN;
    bf16* y    = awts + (size_t)NBH * 64 * NN;
    float* den    = (float*)(y + (size_t)2 * 256 * NN);       // 25088 f32
    float* av_p   = den + (size_t)NBH * NN;                   // 7 x 802,816 f32 = 22.5 MB
    float* av2_p  = av_p + (size_t)NCH * NBH * NN * 32;       // 7 x 1,605,632 f32 = 45 MB

    k_zero  <<<dim3(25),       256, 0, stream>>>(den, 6272);
    k_proj  <<<dim3(98, 3, 2), 256, 0, stream>>>(x, wk, bk, wq, bq, wv, bv, kt, qt, vt);
    k_stats <<<dim3(25, 7, 8), 256, 0, stream>>>(kt, qt, den);
    k_recip <<<dim3(98),       256, 0, stream>>>(den);
    k_scalev<<<dim3(7, 256),   256, 0, stream>>>(vt, den);
    k_av    <<<dim3(25, 7, 8), 256, 0, stream>>>(kt, qt, vt, av_p);
    k_red1  <<<dim3(49, 8),    256, 0, stream>>>(av_p, w1, b1, g1, be1, rm1, rv1, den, awts);
    k_av2   <<<dim3(25, 7, 8), 256, 0, stream>>>(kt, qt, awts, av2_p);
    k_red2  <<<dim3(49, 8),    256, 0, stream>>>(av2_p, w2, b2, g2, be2, rm2, rv2, y);
    k_final <<<dim3(7, 64, 2), 256, 0, stream>>>(y, wf, bff, out);
}

// Round 17
// 111.231 us; speedup vs baseline: 1.8028x; 1.0809x over previous
//
#include <hip/hip_runtime.h>
#include <hip/hip_bf16.h>

typedef __hip_bfloat16 bf16;
typedef __attribute__((ext_vector_type(8))) short bfrag;    // 8 x bf16 (16 B)
typedef __attribute__((ext_vector_type(4))) short s16x4;    // 4 x bf16 (8 B)
typedef __attribute__((ext_vector_type(4))) float f32x4;
typedef __attribute__((ext_vector_type(16))) float f32x16;

#define MFMA32(a,b,c) __builtin_amdgcn_mfma_f32_32x32x16_bf16((a),(b),(c),0,0,0)

__device__ __forceinline__ float b2f(bf16 x){ return __bfloat162float(x); }
__device__ __forceinline__ bf16 f2b(float x){ return __float2bfloat16(x); }
__device__ __forceinline__ float fexp2(float x){ return __builtin_amdgcn_exp2f(x); }
__device__ __forceinline__ float us2f(unsigned short u){ unsigned v = (unsigned)u << 16; return __uint_as_float(v); }

#define NN   3136   // 56*56 = 98 tiles of 32
#define NBH  8      // B * NH
#define NCH  7      // m-chunks
#define MCH  448    // m/n chunk = 14 tiles of 32 = 7 double-steps of 64
#define LDP  40     // LDS row stride for 32-col tiles (80 B; known-good)
#define LDPA 72     // LDS row stride for 64-col tiles (144 B)
#define LOG2E 1.44269504f

// ---------------- zero den ----------------
__global__ __launch_bounds__(256) void k_zero(float* __restrict__ p, int n4)
{
    int i = blockIdx.x * 256 + threadIdx.x;
    if (i < n4) reinterpret_cast<f32x4*>(p)[i] = (f32x4){0.f, 0.f, 0.f, 0.f};
}

// ---------------- QKV projections via MFMA ----------------
__global__ __launch_bounds__(256) void k_proj(
    const float* __restrict__ x,
    const float* __restrict__ wk, const float* __restrict__ bk,
    const float* __restrict__ wq, const float* __restrict__ bq,
    const float* __restrict__ wv, const float* __restrict__ bv,
    bf16* __restrict__ kt, bf16* __restrict__ qt, bf16* __restrict__ vt)
{
    __shared__ __align__(16) bf16 xT[32 * 72];
    __shared__ __align__(16) bf16 wT[128 * 72];
    int tid = threadIdx.x, w = tid >> 6, lane = tid & 63;
    int l31 = lane & 31, lsel = lane >> 5;
    int n0 = blockIdx.x * 32;
    int p  = blockIdx.y;     // 0=K 1=Q 2=V
    int b  = blockIdx.z;
    const float* wp = (p == 0) ? wk : ((p == 1) ? wq : wv);
    const float* bp = (p == 0) ? bk : ((p == 1) ? bq : bv);

    for (int i = tid; i < 2048; i += 256) {
        int c = i >> 5, j = i & 31;
        xT[j * 72 + c] = f2b(x[((size_t)b * 64 + c) * NN + n0 + j]);
    }
    for (int i = tid; i < 8192; i += 256) {
        int oc = i >> 6, c = i & 63;
        wT[oc * 72 + c] = f2b(wp[oc * 64 + c]);
    }
    __syncthreads();

    f32x16 s;
    #pragma unroll
    for (int r = 0; r < 16; ++r) s[r] = 0.f;
    #pragma unroll
    for (int k = 0; k < 4; ++k) {
        bfrag a  = *(const bfrag*)(&xT[l31 * 72 + k * 16 + lsel * 8]);
        bfrag bw = *(const bfrag*)(&wT[(w * 32 + l31) * 72 + k * 16 + lsel * 8]);
        s = MFMA32(a, bw, s);   // D[row=n][col=oc=l31]
    }
    float bias = bp[w * 32 + l31];
    size_t bh = (size_t)b * 4 + w;
    if (p == 2) {
        #pragma unroll
        for (int q = 0; q < 4; ++q) {
            s16x4 pk;
            #pragma unroll
            for (int i = 0; i < 4; ++i) {
                bf16 e = f2b(s[4 * q + i] + bias);
                pk[i] = *(short*)&e;
            }
            *(s16x4*)(vt + (bh * 32 + l31) * NN + n0 + 8 * q + 4 * lsel) = pk;
        }
    } else {
        bf16* dst = (p == 0) ? kt : qt;
        float sc = (p == 0) ? LOG2E : 1.0f;
        #pragma unroll
        for (int r = 0; r < 16; ++r) {
            int nl = (r & 3) + 8 * (r >> 2) + 4 * lsel;
            dst[(bh * NN + n0 + nl) * 32 + l31] = f2b((s[r] + bias) * sc);
        }
    }
}

// ---------------- k_stats: den[m] += sum_{n-chunk} exp2(S'[n,m]) ----------------
__global__ __launch_bounds__(256) void k_stats(const bf16* __restrict__ kt,
                                               const bf16* __restrict__ qt,
                                               float* __restrict__ den)
{
    __shared__ __align__(16) bf16 Kb[2][64 * LDP];
    int tid = threadIdx.x, w = tid >> 6, lane = tid & 63;
    int l31 = lane & 31, lsel = lane >> 5;
    int bh = blockIdx.z;
    int mt = blockIdx.x * 4 + w;
    bool act = (mt < 98);
    int m0 = (act ? mt : 97) * 32;
    int ns = blockIdx.y * MCH;

    const bf16* qp = qt + ((size_t)bh * NN + m0 + l31) * 32 + lsel * 8;
    bfrag qb0 = *(const bfrag*)qp;
    bfrag qb1 = *(const bfrag*)(qp + 16);
    const bf16* kt_bh = kt + (size_t)bh * NN * 32;

    int sr = tid >> 2, sc = (tid & 3) * 8;
    const bf16* sbase = kt_bh + (size_t)(ns + sr) * 32 + sc;
    int soff = sr * LDP + sc;

    *(bfrag*)(&Kb[0][soff]) = *(const bfrag*)sbase;
    __syncthreads();

    float dacc = 0.f;
    for (int t = 0; t < 7; ++t) {
        bfrag pre;
        bool hn = (t + 1 < 7);
        if (hn) pre = *(const bfrag*)(sbase + (size_t)(t + 1) * 2048);
        const bf16* kl = &Kb[t & 1][0];
        #pragma unroll
        for (int nt = 0; nt < 2; ++nt) {
            int ko = (l31 + 32 * nt) * LDP + lsel * 8;
            bfrag kb0 = *(const bfrag*)(kl + ko);
            bfrag kb1 = *(const bfrag*)(kl + ko + 16);
            f32x16 s;
            #pragma unroll
            for (int r = 0; r < 16; ++r) s[r] = 0.f;
            s = MFMA32(kb0, qb0, s);
            s = MFMA32(kb1, qb1, s);
            float ps = 0.f;
            #pragma unroll
            for (int r = 0; r < 16; ++r) ps += fexp2(s[r]);
            dacc += ps;
        }
        if (hn) *(bfrag*)(&Kb[(t + 1) & 1][soff]) = pre;
        __syncthreads();
    }
    dacc += __shfl_xor(dacc, 32);
    if (act && lane < 32) atomicAdd(&den[(size_t)bh * NN + m0 + l31], dacc);
}

__global__ __launch_bounds__(256) void k_recip(float* __restrict__ den)
{
    int i = blockIdx.x * 256 + threadIdx.x;
    if (i < NBH * NN) den[i] = 1.0f / den[i];
}

// vt[bh][32][m] *= rden[bh][m]   (vectorized: 8 m per thread)
__global__ __launch_bounds__(256) void k_scalev(bf16* __restrict__ vt, const float* __restrict__ rden)
{
    int by = blockIdx.y;
    const float* rdp = rden + ((size_t)(by >> 5)) * NN;
    bf16* vp = vt + (size_t)by * NN;
    int i = blockIdx.x * 256 + threadIdx.x;   // 0..391 valid
    if (i < 392) {
        int m = i * 8;
        union { bfrag v; unsigned short us[8]; } u;
        u.v = *(const bfrag*)(vp + m);
        #pragma unroll
        for (int j = 0; j < 8; ++j) {
            bf16 e = f2b(us2f(u.us[j]) * rdp[m + j]);
            u.us[j] = *(unsigned short*)&e;
        }
        *(bfrag*)(vp + m) = u.v;
    }
}

// ---------------- k_av: partial av to private slab (bf16 stores) ----------------
__global__ __launch_bounds__(256) void k_av(const bf16* __restrict__ kt,
    const bf16* __restrict__ qt, const bf16* __restrict__ vtp,
    bf16* __restrict__ av_p)
{
    __shared__ __align__(16) bf16 Qb[2][64 * LDP];
    __shared__ __align__(16) bf16 Vb[2][32 * LDPA];
    int tid = threadIdx.x, w = tid >> 6, lane = tid & 63;
    int l31 = lane & 31, lsel = lane >> 5;
    int bh = blockIdx.z;
    int ntile = blockIdx.x * 4 + w;
    bool act = (ntile < 98);
    int n0 = (act ? ntile : 97) * 32;
    int ms = blockIdx.y * MCH;

    const bf16* kp = kt + ((size_t)bh * NN + n0 + l31) * 32 + lsel * 8;
    bfrag kb0 = *(const bfrag*)kp;
    bfrag kb1 = *(const bfrag*)(kp + 16);
    const bf16* qt_bh = qt + (size_t)bh * NN * 32;
    const bf16* vt_bh = vtp + (size_t)bh * 32 * NN;

    int qr = tid >> 2, qc = (tid & 3) * 8;
    const bf16* qsb = qt_bh + (size_t)(ms + qr) * 32 + qc;
    int qoff = qr * LDP + qc;
    int vr = tid >> 3, vc = (tid & 7) * 8;
    const bf16* vsb = vt_bh + (size_t)vr * NN + ms + vc;
    int voff = vr * LDPA + vc;

    *(bfrag*)(&Qb[0][qoff]) = *(const bfrag*)qsb;
    *(bfrag*)(&Vb[0][voff]) = *(const bfrag*)vsb;
    __syncthreads();

    f32x16 acc;
    #pragma unroll
    for (int r = 0; r < 16; ++r) acc[r] = 0.f;

    for (int t = 0; t < 7; ++t) {
        bfrag preQ, preV;
        bool hn = (t + 1 < 7);
        if (hn) {
            preQ = *(const bfrag*)(qsb + (size_t)(t + 1) * 2048);
            preV = *(const bfrag*)(vsb + (size_t)(t + 1) * 64);
        }
        const bf16* ql = &Qb[t & 1][0];
        const bf16* vl = &Vb[t & 1][0];
        #pragma unroll
        for (int mt2 = 0; mt2 < 2; ++mt2) {
            int qo = (l31 + 32 * mt2) * LDP + lsel * 8;
            bfrag q0 = *(const bfrag*)(ql + qo);
            bfrag q1 = *(const bfrag*)(ql + qo + 16);
            f32x16 s;
            #pragma unroll
            for (int r = 0; r < 16; ++r) s[r] = 0.f;
            s = MFMA32(q0, kb0, s);
            s = MFMA32(q1, kb1, s);
            union { unsigned short us[8]; bfrag v; } pa0, pa1;
            #pragma unroll
            for (int i = 0; i < 8; ++i) {
                bf16 e0 = f2b(fexp2(s[i]));
                bf16 e1 = f2b(fexp2(s[8 + i]));
                pa0.us[i] = *(unsigned short*)&e0;
                pa1.us[i] = *(unsigned short*)&e1;
            }
            const bf16* vrow = vl + l31 * LDPA + 32 * mt2 + lsel * 4;
            union { s16x4 h[2]; bfrag v; } vb0, vb1;
            vb0.h[0] = *(const s16x4*)(vrow);
            vb0.h[1] = *(const s16x4*)(vrow + 8);
            vb1.h[0] = *(const s16x4*)(vrow + 16);
            vb1.h[1] = *(const s16x4*)(vrow + 24);
            acc = MFMA32(pa0.v, vb0.v, acc);
            acc = MFMA32(pa1.v, vb1.v, acc);
        }
        if (hn) {
            *(bfrag*)(&Qb[(t + 1) & 1][qoff]) = preQ;
            *(bfrag*)(&Vb[(t + 1) & 1][voff]) = preV;
        }
        __syncthreads();
    }
    if (act) {
        bf16* dst = av_p + (size_t)blockIdx.y * ((size_t)NBH * NN * 32)
                  + ((size_t)bh * NN + n0) * 32 + l31;
        #pragma unroll
        for (int r = 0; r < 16; ++r) {
            int nl = (r & 3) + 8 * (r >> 2) + 4 * lsel;
            dst[(size_t)nl * 32] = f2b(acc[r]);
        }
    }
}

// ---------------- k_av2: partial av2 to private slab (bf16 stores) ----------------
__global__ __launch_bounds__(256) void k_av2(const bf16* __restrict__ kt,
    const bf16* __restrict__ qt, const bf16* __restrict__ awts,
    bf16* __restrict__ av2_p)
{
    __shared__ __align__(16) bf16 Qb[2][64 * LDP];
    __shared__ __align__(16) bf16 Ab[2][64 * LDPA];
    int tid = threadIdx.x, w = tid >> 6, lane = tid & 63;
    int l31 = lane & 31, lsel = lane >> 5;
    int bh = blockIdx.z;
    int ntile = blockIdx.x * 4 + w;
    bool act = (ntile < 98);
    int n0 = (act ? ntile : 97) * 32;
    int ms = blockIdx.y * MCH;

    const bf16* kp = kt + ((size_t)bh * NN + n0 + l31) * 32 + lsel * 8;
    bfrag kb0 = *(const bfrag*)kp;
    bfrag kb1 = *(const bfrag*)(kp + 16);
    const bf16* qt_bh = qt + (size_t)bh * NN * 32;
    const bf16* aw_bh = awts + (size_t)bh * 64 * NN;

    int qr = tid >> 2, qc = (tid & 3) * 8;
    const bf16* qsb = qt_bh + (size_t)(ms + qr) * 32 + qc;
    int qoff = qr * LDP + qc;
    int ar0 = tid >> 3, acv = (tid & 7) * 8;
    const bf16* asb0 = aw_bh + (size_t)ar0 * NN + ms + acv;
    const bf16* asb1 = aw_bh + (size_t)(ar0 + 32) * NN + ms + acv;
    int aoff0 = ar0 * LDPA + acv;
    int aoff1 = (ar0 + 32) * LDPA + acv;

    *(bfrag*)(&Qb[0][qoff])  = *(const bfrag*)qsb;
    *(bfrag*)(&Ab[0][aoff0]) = *(const bfrag*)asb0;
    *(bfrag*)(&Ab[0][aoff1]) = *(const bfrag*)asb1;
    __syncthreads();

    f32x16 acc0, acc1;
    #pragma unroll
    for (int r = 0; r < 16; ++r) { acc0[r] = 0.f; acc1[r] = 0.f; }

    for (int t = 0; t < 7; ++t) {
        bfrag preQ, preA0, preA1;
        bool hn = (t + 1 < 7);
        if (hn) {
            preQ  = *(const bfrag*)(qsb  + (size_t)(t + 1) * 2048);
            preA0 = *(const bfrag*)(asb0 + (size_t)(t + 1) * 64);
            preA1 = *(const bfrag*)(asb1 + (size_t)(t + 1) * 64);
        }
        const bf16* ql = &Qb[t & 1][0];
        const bf16* al = &Ab[t & 1][0];
        #pragma unroll
        for (int mt2 = 0; mt2 < 2; ++mt2) {
            int qo = (l31 + 32 * mt2) * LDP + lsel * 8;
            bfrag q0 = *(const bfrag*)(ql + qo);
            bfrag q1 = *(const bfrag*)(ql + qo + 16);
            f32x16 s;
            #pragma unroll
            for (int r = 0; r < 16; ++r) s[r] = 0.f;
            s = MFMA32(q0, kb0, s);
            s = MFMA32(q1, kb1, s);
            union { unsigned short us[8]; bfrag v; } pa0, pa1;
            #pragma unroll
            for (int i = 0; i < 8; ++i) {
                bf16 e0 = f2b(fexp2(s[i]));
                bf16 e1 = f2b(fexp2(s[8 + i]));
                pa0.us[i] = *(unsigned short*)&e0;
                pa1.us[i] = *(unsigned short*)&e1;
            }
            const bf16* a0 = al + l31 * LDPA + 32 * mt2 + lsel * 4;
            const bf16* a1 = al + (l31 + 32) * LDPA + 32 * mt2 + lsel * 4;
            union { s16x4 h[2]; bfrag v; } e00, e01, e10, e11;
            e00.h[0] = *(const s16x4*)(a0);
            e00.h[1] = *(const s16x4*)(a0 + 8);
            e01.h[0] = *(const s16x4*)(a0 + 16);
            e01.h[1] = *(const s16x4*)(a0 + 24);
            e10.h[0] = *(const s16x4*)(a1);
            e10.h[1] = *(const s16x4*)(a1 + 8);
            e11.h[0] = *(const s16x4*)(a1 + 16);
            e11.h[1] = *(const s16x4*)(a1 + 24);
            acc0 = MFMA32(pa0.v, e00.v, acc0);
            acc0 = MFMA32(pa1.v, e01.v, acc0);
            acc1 = MFMA32(pa0.v, e10.v, acc1);
            acc1 = MFMA32(pa1.v, e11.v, acc1);
        }
        if (hn) {
            *(bfrag*)(&Qb[(t + 1) & 1][qoff])  = preQ;
            *(bfrag*)(&Ab[(t + 1) & 1][aoff0]) = preA0;
            *(bfrag*)(&Ab[(t + 1) & 1][aoff1]) = preA1;
        }
        __syncthreads();
    }
    if (act) {
        bf16* dst = av2_p + (size_t)blockIdx.y * ((size_t)NBH * NN * 64)
                  + ((size_t)bh * NN + n0) * 64 + l31;
        #pragma unroll
        for (int r = 0; r < 16; ++r) {
            int nl = (r & 3) + 8 * (r >> 2) + 4 * lsel;
            dst[(size_t)nl * 64]      = f2b(acc0[r]);
            dst[(size_t)nl * 64 + 32] = f2b(acc1[r]);
        }
    }
}

// ---------------- reduce1: sum 7 bf16 partials, bn1+relu+rden -> awts bf16 ----------------
__global__ __launch_bounds__(256) void k_red1(const bf16* __restrict__ av_p,
    const float* __restrict__ w1, const float* __restrict__ b1,
    const float* __restrict__ g1, const float* __restrict__ be1,
    const float* __restrict__ rm1, const float* __restrict__ rv1,
    const float* __restrict__ rds,
    bf16* __restrict__ awts)
{
    __shared__ float avl[64 * 33];
    __shared__ float w1l[64 * 33];
    __shared__ float sc[64], sh[64], bb[64];
    int n0 = blockIdx.x * 64, bh = blockIdx.y, h = bh & 3;
    int tid = threadIdx.x;
    const size_t cstride = (size_t)NBH * NN * 32;
    const bf16* ap = av_p + ((size_t)bh * NN + n0) * 32;
    {
        int nr = tid >> 2, e8 = (tid & 3) * 8;
        int base = nr * 32 + e8;
        float s8[8];
        #pragma unroll
        for (int j = 0; j < 8; ++j) s8[j] = 0.f;
        #pragma unroll
        for (int c = 0; c < NCH; ++c) {
            union { bfrag v; unsigned short us[8]; } u;
            u.v = *(const bfrag*)(ap + (size_t)c * cstride + base);
            #pragma unroll
            for (int j = 0; j < 8; ++j) s8[j] += us2f(u.us[j]);
        }
        #pragma unroll
        for (int j = 0; j < 8; ++j) avl[nr * 33 + e8 + j] = s8[j];
    }
    for (int i = tid; i < 2048; i += 256)
        w1l[(i >> 5) * 33 + (i & 31)] = w1[i];
    if (tid < 64) {
        int ch = h * 64 + tid;
        float s = g1[ch] * rsqrtf(rv1[ch] + 1e-5f);
        sc[tid] = s; sh[tid] = be1[ch] - rm1[ch] * s; bb[tid] = b1[tid];
    }
    __syncthreads();
    int nb = (tid & 15) * 4, eb = (tid >> 4) * 4;
    float rsc[4];
    {
        const float* rp = rds + (size_t)bh * NN + n0 + nb;
        rsc[0] = rp[0]; rsc[1] = rp[1]; rsc[2] = rp[2]; rsc[3] = rp[3];
    }
    float s[4][4];
    #pragma unroll
    for (int i = 0; i < 4; ++i)
        #pragma unroll
        for (int j = 0; j < 4; ++j) s[i][j] = bb[eb + j];
    for (int d = 0; d < 32; ++d) {
        float a0 = avl[(nb+0)*33+d], a1 = avl[(nb+1)*33+d], a2 = avl[(nb+2)*33+d], a3 = avl[(nb+3)*33+d];
        float w0 = w1l[(eb+0)*33+d], w1v = w1l[(eb+1)*33+d], w2v = w1l[(eb+2)*33+d], w3 = w1l[(eb+3)*33+d];
        s[0][0]+=a0*w0; s[0][1]+=a0*w1v; s[0][2]+=a0*w2v; s[0][3]+=a0*w3;
        s[1][0]+=a1*w0; s[1][1]+=a1*w1v; s[1][2]+=a1*w2v; s[1][3]+=a1*w3;
        s[2][0]+=a2*w0; s[2][1]+=a2*w1v; s[2][2]+=a2*w2v; s[2][3]+=a2*w3;
        s[3][0]+=a3*w0; s[3][1]+=a3*w1v; s[3][2]+=a3*w2v; s[3][3]+=a3*w3;
    }
    #pragma unroll
    for (int j = 0; j < 4; ++j) {
        int e = eb + j;
        ushort4 pk;
        float v0 = fmaxf(s[0][j] * sc[e] + sh[e], 0.f) * rsc[0];
        float v1 = fmaxf(s[1][j] * sc[e] + sh[e], 0.f) * rsc[1];
        float v2 = fmaxf(s[2][j] * sc[e] + sh[e], 0.f) * rsc[2];
        float v3 = fmaxf(s[3][j] * sc[e] + sh[e], 0.f) * rsc[3];
        bf16 b0 = f2b(v0), b1b = f2b(v1), b2b = f2b(v2), b3 = f2b(v3);
        pk.x = *(unsigned short*)&b0; pk.y = *(unsigned short*)&b1b;
        pk.z = *(unsigned short*)&b2b; pk.w = *(unsigned short*)&b3;
        *reinterpret_cast<ushort4*>(awts + ((size_t)bh * 64 + e) * NN + n0 + nb) = pk;
    }
}

// ---------------- reduce2: sum 7 bf16 partials, bn2+relu -> y bf16 ----------------
__global__ __launch_bounds__(256) void k_red2(const bf16* __restrict__ av2_p,
    const float* __restrict__ w2, const float* __restrict__ b2,
    const float* __restrict__ g2, const float* __restrict__ be2,
    const float* __restrict__ rm2, const float* __restrict__ rv2,
    bf16* __restrict__ y)
{
    __shared__ float a2l[64 * 65];
    __shared__ float w2l[64 * 65];
    __shared__ float sc[64], sh[64], bb[64];
    int n0 = blockIdx.x * 64, bh = blockIdx.y, h = bh & 3, b = bh >> 2;
    int tid = threadIdx.x;
    const size_t cstride = (size_t)NBH * NN * 64;
    const bf16* ap = av2_p + ((size_t)bh * NN + n0) * 64;
    #pragma unroll
    for (int it = 0; it < 2; ++it) {
        int idx = it * 256 + tid;
        int nr = idx >> 3, e8 = (idx & 7) * 8;
        int base = nr * 64 + e8;
        float s8[8];
        #pragma unroll
        for (int j = 0; j < 8; ++j) s8[j] = 0.f;
        #pragma unroll
        for (int c = 0; c < NCH; ++c) {
            union { bfrag v; unsigned short us[8]; } u;
            u.v = *(const bfrag*)(ap + (size_t)c * cstride + base);
            #pragma unroll
            for (int j = 0; j < 8; ++j) s8[j] += us2f(u.us[j]);
        }
        #pragma unroll
        for (int j = 0; j < 8; ++j) a2l[nr * 65 + e8 + j] = s8[j];
    }
    for (int i = tid; i < 4096; i += 256)
        w2l[(i >> 6) * 65 + (i & 63)] = w2[i];
    if (tid < 64) {
        int ch = h * 64 + tid;
        float s = g2[ch] * rsqrtf(rv2[ch] + 1e-5f);
        sc[tid] = s; sh[tid] = be2[ch] - rm2[ch] * s; bb[tid] = b2[tid];
    }
    __syncthreads();
    int nb = (tid & 15) * 4, eb = (tid >> 4) * 4;
    float s[4][4];
    #pragma unroll
    for (int i = 0; i < 4; ++i)
        #pragma unroll
        for (int j = 0; j < 4; ++j) s[i][j] = bb[eb + j];
    for (int d = 0; d < 64; ++d) {
        float a0 = a2l[(nb+0)*65+d], a1 = a2l[(nb+1)*65+d], a2 = a2l[(nb+2)*65+d], a3 = a2l[(nb+3)*65+d];
        float w0 = w2l[(eb+0)*65+d], w1v = w2l[(eb+1)*65+d], w2v = w2l[(eb+2)*65+d], w3 = w2l[(eb+3)*65+d];
        s[0][0]+=a0*w0; s[0][1]+=a0*w1v; s[0][2]+=a0*w2v; s[0][3]+=a0*w3;
        s[1][0]+=a1*w0; s[1][1]+=a1*w1v; s[1][2]+=a1*w2v; s[1][3]+=a1*w3;
        s[2][0]+=a2*w0; s[2][1]+=a2*w1v; s[2][2]+=a2*w2v; s[2][3]+=a2*w3;
        s[3][0]+=a3*w0; s[3][1]+=a3*w1v; s[3][2]+=a3*w2v; s[3][3]+=a3*w3;
    }
    #pragma unroll
    for (int j = 0; j < 4; ++j) {
        int e = eb + j;
        ushort4 pk;
        float v0 = fmaxf(s[0][j] * sc[e] + sh[e], 0.f);
        float v1 = fmaxf(s[1][j] * sc[e] + sh[e], 0.f);
        float v2 = fmaxf(s[2][j] * sc[e] + sh[e], 0.f);
        float v3 = fmaxf(s[3][j] * sc[e] + sh[e], 0.f);
        bf16 b0 = f2b(v0), b1b = f2b(v1), b2b = f2b(v2), b3 = f2b(v3);
        pk.x = *(unsigned short*)&b0; pk.y = *(unsigned short*)&b1b;
        pk.z = *(unsigned short*)&b2b; pk.w = *(unsigned short*)&b3;
        *reinterpret_cast<ushort4*>(y + ((size_t)b * 256 + h * 64 + e) * NN + n0 + nb) = pk;
    }
}

// ---------------- final 1x1 conv (f32 out), 2 n per thread ----------------
__global__ __launch_bounds__(256) void k_final(const bf16* __restrict__ y,
    const float* __restrict__ wf, const float* __restrict__ bf_,
    float* __restrict__ out)
{
    int t = blockIdx.x * 256 + threadIdx.x;
    int n = t * 2;
    if (n >= NN) return;
    int o = blockIdx.y;
    int b = blockIdx.z;
    float s0 = bf_[o], s1 = s0;
    const bf16* yp = y + (size_t)b * 256 * NN + n;
    const float* wp = wf + o * 256;
    #pragma unroll 16
    for (int k = 0; k < 256; ++k) {
        unsigned u = *reinterpret_cast<const unsigned*>(yp + (size_t)k * NN);
        float lo = __uint_as_float(u << 16);
        float hi = __uint_as_float(u & 0xffff0000u);
        s0 += wp[k] * lo;
        s1 += wp[k] * hi;
    }
    float* op = out + ((size_t)b * 64 + o) * NN + n;
    op[0] = s0;
    op[1] = s1;
}

extern "C" void kernel_launch(void* const* d_in, const int* in_sizes, int n_in,
                              void* d_out, int out_size, void* d_ws, size_t ws_size,
                              hipStream_t stream)
{
    const float* x   = (const float*)d_in[0];
    const float* wk  = (const float*)d_in[1];
    const float* bk  = (const float*)d_in[2];
    const float* wq  = (const float*)d_in[3];
    const float* bq  = (const float*)d_in[4];
    const float* wv  = (const float*)d_in[5];
    const float* bv  = (const float*)d_in[6];
    const float* w1  = (const float*)d_in[7];
    const float* b1  = (const float*)d_in[8];
    const float* g1  = (const float*)d_in[9];
    const float* be1 = (const float*)d_in[10];
    const float* rm1 = (const float*)d_in[11];
    const float* rv1 = (const float*)d_in[12];
    const float* w2  = (const float*)d_in[13];
    const float* b2  = (const float*)d_in[14];
    const float* g2  = (const float*)d_in[15];
    const float* be2 = (const float*)d_in[16];
    const float* rm2 = (const float*)d_in[17];
    const float* rv2 = (const float*)d_in[18];
    const float* wf  = (const float*)d_in[19];
    const float* bff = (const float*)d_in[20];
    float* out = (float*)d_out;

    char* ws = (char*)d_ws;
    bf16* kt   = (bf16*)ws;
    bf16* qt   = kt + (size_t)NBH * NN * 32;
    bf16* vt   = qt + (size_t)NBH * NN * 32;
    bf16* awts = vt + (size_t)NBH * 32 * NN;
    bf16* y    = awts + (size_t)NBH * 64 * NN;
    float* den = (float*)(y + (size_t)2 * 256 * NN);          // 25088 f32
    bf16* av_p  = (bf16*)(den + (size_t)NBH * NN);            // 7 x 802,816 bf16 = 11.2 MB
    bf16* av2_p = av_p + (size_t)NCH * NBH * NN * 32;         // 7 x 1,605,632 bf16 = 22.5 MB

    k_zero  <<<dim3(25),       256, 0, stream>>>(den, 6272);
    k_proj  <<<dim3(98, 3, 2), 256, 0, stream>>>(x, wk, bk, wq, bq, wv, bv, kt, qt, vt);
    k_stats <<<dim3(25, 7, 8), 256, 0, stream>>>(kt, qt, den);
    k_recip <<<dim3(98),       256, 0, stream>>>(den);
    k_scalev<<<dim3(2, 256),   256, 0, stream>>>(vt, den);
    k_av    <<<dim3(25, 7, 8), 256, 0, stream>>>(kt, qt, vt, av_p);
    k_red1  <<<dim3(49, 8),    256, 0, stream>>>(av_p, w1, b1, g1, be1, rm1, rv1, den, awts);
    k_av2   <<<dim3(25, 7, 8), 256, 0, stream>>>(kt, qt, awts, av2_p);
    k_red2  <<<dim3(49, 8),    256, 0, stream>>>(av2_p, w2, b2, g2, be2, rm2, rv2, y);
    k_final <<<dim3(7, 64, 2), 256, 0, stream>>>(y, wf, bff, out);
}

// Round 18
// 103.579 us; speedup vs baseline: 1.9360x; 1.0739x over previous
//
#include <hip/hip_runtime.h>
#include <hip/hip_bf16.h>

typedef __hip_bfloat16 bf16;
typedef __attribute__((ext_vector_type(8))) short bfrag;    // 8 x bf16 (16 B)
typedef __attribute__((ext_vector_type(4))) short s16x4;    // 4 x bf16 (8 B)
typedef __attribute__((ext_vector_type(4))) float f32x4;
typedef __attribute__((ext_vector_type(16))) float f32x16;

#define MFMA32(a,b,c) __builtin_amdgcn_mfma_f32_32x32x16_bf16((a),(b),(c),0,0,0)

__device__ __forceinline__ float b2f(bf16 x){ return __bfloat162float(x); }
__device__ __forceinline__ bf16 f2b(float x){ return __float2bfloat16(x); }
__device__ __forceinline__ float fexp2(float x){ return __builtin_amdgcn_exp2f(x); }
__device__ __forceinline__ float us2f(unsigned short u){ unsigned v = (unsigned)u << 16; return __uint_as_float(v); }

#define NN   3136   // 56*56 = 98 tiles of 32
#define NBH  8      // B * NH
#define NCH  7      // m-chunks
#define MCH  448    // m/n chunk = 14 tiles of 32 = 7 double-steps of 64
#define LDP  40     // LDS row stride for 32-col tiles (80 B; known-good)
#define LDPA 72     // LDS row stride for 64-col tiles (144 B)
#define LDW  272    // LDS row stride for 256-col wf tile (544 B, 16B-multiple)
#define LOG2E 1.44269504f

// ---------------- zero den ----------------
__global__ __launch_bounds__(256) void k_zero(float* __restrict__ p, int n4)
{
    int i = blockIdx.x * 256 + threadIdx.x;
    if (i < n4) reinterpret_cast<f32x4*>(p)[i] = (f32x4){0.f, 0.f, 0.f, 0.f};
}

// ---------------- QKV projections via MFMA ----------------
__global__ __launch_bounds__(256) void k_proj(
    const float* __restrict__ x,
    const float* __restrict__ wk, const float* __restrict__ bk,
    const float* __restrict__ wq, const float* __restrict__ bq,
    const float* __restrict__ wv, const float* __restrict__ bv,
    bf16* __restrict__ kt, bf16* __restrict__ qt, bf16* __restrict__ vt)
{
    __shared__ __align__(16) bf16 xT[32 * 72];
    __shared__ __align__(16) bf16 wT[128 * 72];
    int tid = threadIdx.x, w = tid >> 6, lane = tid & 63;
    int l31 = lane & 31, lsel = lane >> 5;
    int n0 = blockIdx.x * 32;
    int p  = blockIdx.y;     // 0=K 1=Q 2=V
    int b  = blockIdx.z;
    const float* wp = (p == 0) ? wk : ((p == 1) ? wq : wv);
    const float* bp = (p == 0) ? bk : ((p == 1) ? bq : bv);

    for (int i = tid; i < 2048; i += 256) {
        int c = i >> 5, j = i & 31;
        xT[j * 72 + c] = f2b(x[((size_t)b * 64 + c) * NN + n0 + j]);
    }
    for (int i = tid; i < 8192; i += 256) {
        int oc = i >> 6, c = i & 63;
        wT[oc * 72 + c] = f2b(wp[oc * 64 + c]);
    }
    __syncthreads();

    f32x16 s;
    #pragma unroll
    for (int r = 0; r < 16; ++r) s[r] = 0.f;
    #pragma unroll
    for (int k = 0; k < 4; ++k) {
        bfrag a  = *(const bfrag*)(&xT[l31 * 72 + k * 16 + lsel * 8]);
        bfrag bw = *(const bfrag*)(&wT[(w * 32 + l31) * 72 + k * 16 + lsel * 8]);
        s = MFMA32(a, bw, s);   // D[row=n][col=oc=l31]
    }
    float bias = bp[w * 32 + l31];
    size_t bh = (size_t)b * 4 + w;
    if (p == 2) {
        #pragma unroll
        for (int q = 0; q < 4; ++q) {
            s16x4 pk;
            #pragma unroll
            for (int i = 0; i < 4; ++i) {
                bf16 e = f2b(s[4 * q + i] + bias);
                pk[i] = *(short*)&e;
            }
            *(s16x4*)(vt + (bh * 32 + l31) * NN + n0 + 8 * q + 4 * lsel) = pk;
        }
    } else {
        bf16* dst = (p == 0) ? kt : qt;
        float sc = (p == 0) ? LOG2E : 1.0f;
        #pragma unroll
        for (int r = 0; r < 16; ++r) {
            int nl = (r & 3) + 8 * (r >> 2) + 4 * lsel;
            dst[(bh * NN + n0 + nl) * 32 + l31] = f2b((s[r] + bias) * sc);
        }
    }
}

// ---------------- k_stats: den[m] += sum_{n-chunk} exp2(S'[n,m]) ----------------
__global__ __launch_bounds__(256) void k_stats(const bf16* __restrict__ kt,
                                               const bf16* __restrict__ qt,
                                               float* __restrict__ den)
{
    __shared__ __align__(16) bf16 Kb[2][64 * LDP];
    int tid = threadIdx.x, w = tid >> 6, lane = tid & 63;
    int l31 = lane & 31, lsel = lane >> 5;
    int bh = blockIdx.z;
    int mt = blockIdx.x * 4 + w;
    bool act = (mt < 98);
    int m0 = (act ? mt : 97) * 32;
    int ns = blockIdx.y * MCH;

    const bf16* qp = qt + ((size_t)bh * NN + m0 + l31) * 32 + lsel * 8;
    bfrag qb0 = *(const bfrag*)qp;
    bfrag qb1 = *(const bfrag*)(qp + 16);
    const bf16* kt_bh = kt + (size_t)bh * NN * 32;

    int sr = tid >> 2, sc = (tid & 3) * 8;
    const bf16* sbase = kt_bh + (size_t)(ns + sr) * 32 + sc;
    int soff = sr * LDP + sc;

    *(bfrag*)(&Kb[0][soff]) = *(const bfrag*)sbase;
    __syncthreads();

    float dacc = 0.f;
    for (int t = 0; t < 7; ++t) {
        bfrag pre;
        bool hn = (t + 1 < 7);
        if (hn) pre = *(const bfrag*)(sbase + (size_t)(t + 1) * 2048);
        const bf16* kl = &Kb[t & 1][0];
        #pragma unroll
        for (int nt = 0; nt < 2; ++nt) {
            int ko = (l31 + 32 * nt) * LDP + lsel * 8;
            bfrag kb0 = *(const bfrag*)(kl + ko);
            bfrag kb1 = *(const bfrag*)(kl + ko + 16);
            f32x16 s;
            #pragma unroll
            for (int r = 0; r < 16; ++r) s[r] = 0.f;
            s = MFMA32(kb0, qb0, s);
            s = MFMA32(kb1, qb1, s);
            float ps = 0.f;
            #pragma unroll
            for (int r = 0; r < 16; ++r) ps += fexp2(s[r]);
            dacc += ps;
        }
        if (hn) *(bfrag*)(&Kb[(t + 1) & 1][soff]) = pre;
        __syncthreads();
    }
    dacc += __shfl_xor(dacc, 32);
    if (act && lane < 32) atomicAdd(&den[(size_t)bh * NN + m0 + l31], dacc);
}

__global__ __launch_bounds__(256) void k_recip(float* __restrict__ den)
{
    int i = blockIdx.x * 256 + threadIdx.x;
    if (i < NBH * NN) den[i] = 1.0f / den[i];
}

// vt[bh][32][m] *= rden[bh][m]
__global__ __launch_bounds__(256) void k_scalev(bf16* __restrict__ vt, const float* __restrict__ rden)
{
    int by = blockIdx.y;
    const float* rdp = rden + ((size_t)(by >> 5)) * NN;
    bf16* vp = vt + (size_t)by * NN;
    int i = blockIdx.x * 256 + threadIdx.x;
    if (i < 392) {
        int m = i * 8;
        union { bfrag v; unsigned short us[8]; } u;
        u.v = *(const bfrag*)(vp + m);
        #pragma unroll
        for (int j = 0; j < 8; ++j) {
            bf16 e = f2b(us2f(u.us[j]) * rdp[m + j]);
            u.us[j] = *(unsigned short*)&e;
        }
        *(bfrag*)(vp + m) = u.v;
    }
}

// ---------------- k_av: partial av to private slab (bf16 stores) ----------------
__global__ __launch_bounds__(256) void k_av(const bf16* __restrict__ kt,
    const bf16* __restrict__ qt, const bf16* __restrict__ vtp,
    bf16* __restrict__ av_p)
{
    __shared__ __align__(16) bf16 Qb[2][64 * LDP];
    __shared__ __align__(16) bf16 Vb[2][32 * LDPA];
    int tid = threadIdx.x, w = tid >> 6, lane = tid & 63;
    int l31 = lane & 31, lsel = lane >> 5;
    int bh = blockIdx.z;
    int ntile = blockIdx.x * 4 + w;
    bool act = (ntile < 98);
    int n0 = (act ? ntile : 97) * 32;
    int ms = blockIdx.y * MCH;

    const bf16* kp = kt + ((size_t)bh * NN + n0 + l31) * 32 + lsel * 8;
    bfrag kb0 = *(const bfrag*)kp;
    bfrag kb1 = *(const bfrag*)(kp + 16);
    const bf16* qt_bh = qt + (size_t)bh * NN * 32;
    const bf16* vt_bh = vtp + (size_t)bh * 32 * NN;

    int qr = tid >> 2, qc = (tid & 3) * 8;
    const bf16* qsb = qt_bh + (size_t)(ms + qr) * 32 + qc;
    int qoff = qr * LDP + qc;
    int vr = tid >> 3, vc = (tid & 7) * 8;
    const bf16* vsb = vt_bh + (size_t)vr * NN + ms + vc;
    int voff = vr * LDPA + vc;

    *(bfrag*)(&Qb[0][qoff]) = *(const bfrag*)qsb;
    *(bfrag*)(&Vb[0][voff]) = *(const bfrag*)vsb;
    __syncthreads();

    f32x16 acc;
    #pragma unroll
    for (int r = 0; r < 16; ++r) acc[r] = 0.f;

    for (int t = 0; t < 7; ++t) {
        bfrag preQ, preV;
        bool hn = (t + 1 < 7);
        if (hn) {
            preQ = *(const bfrag*)(qsb + (size_t)(t + 1) * 2048);
            preV = *(const bfrag*)(vsb + (size_t)(t + 1) * 64);
        }
        const bf16* ql = &Qb[t & 1][0];
        const bf16* vl = &Vb[t & 1][0];
        #pragma unroll
        for (int mt2 = 0; mt2 < 2; ++mt2) {
            int qo = (l31 + 32 * mt2) * LDP + lsel * 8;
            bfrag q0 = *(const bfrag*)(ql + qo);
            bfrag q1 = *(const bfrag*)(ql + qo + 16);
            f32x16 s;
            #pragma unroll
            for (int r = 0; r < 16; ++r) s[r] = 0.f;
            s = MFMA32(q0, kb0, s);
            s = MFMA32(q1, kb1, s);
            union { unsigned short us[8]; bfrag v; } pa0, pa1;
            #pragma unroll
            for (int i = 0; i < 8; ++i) {
                bf16 e0 = f2b(fexp2(s[i]));
                bf16 e1 = f2b(fexp2(s[8 + i]));
                pa0.us[i] = *(unsigned short*)&e0;
                pa1.us[i] = *(unsigned short*)&e1;
            }
            const bf16* vrow = vl + l31 * LDPA + 32 * mt2 + lsel * 4;
            union { s16x4 h[2]; bfrag v; } vb0, vb1;
            vb0.h[0] = *(const s16x4*)(vrow);
            vb0.h[1] = *(const s16x4*)(vrow + 8);
            vb1.h[0] = *(const s16x4*)(vrow + 16);
            vb1.h[1] = *(const s16x4*)(vrow + 24);
            acc = MFMA32(pa0.v, vb0.v, acc);
            acc = MFMA32(pa1.v, vb1.v, acc);
        }
        if (hn) {
            *(bfrag*)(&Qb[(t + 1) & 1][qoff]) = preQ;
            *(bfrag*)(&Vb[(t + 1) & 1][voff]) = preV;
        }
        __syncthreads();
    }
    if (act) {
        bf16* dst = av_p + (size_t)blockIdx.y * ((size_t)NBH * NN * 32)
                  + ((size_t)bh * NN + n0) * 32 + l31;
        #pragma unroll
        for (int r = 0; r < 16; ++r) {
            int nl = (r & 3) + 8 * (r >> 2) + 4 * lsel;
            dst[(size_t)nl * 32] = f2b(acc[r]);
        }
    }
}

// ---------------- k_av2: partial av2 to private slab (bf16 stores) ----------------
__global__ __launch_bounds__(256) void k_av2(const bf16* __restrict__ kt,
    const bf16* __restrict__ qt, const bf16* __restrict__ awts,
    bf16* __restrict__ av2_p)
{
    __shared__ __align__(16) bf16 Qb[2][64 * LDP];
    __shared__ __align__(16) bf16 Ab[2][64 * LDPA];
    int tid = threadIdx.x, w = tid >> 6, lane = tid & 63;
    int l31 = lane & 31, lsel = lane >> 5;
    int bh = blockIdx.z;
    int ntile = blockIdx.x * 4 + w;
    bool act = (ntile < 98);
    int n0 = (act ? ntile : 97) * 32;
    int ms = blockIdx.y * MCH;

    const bf16* kp = kt + ((size_t)bh * NN + n0 + l31) * 32 + lsel * 8;
    bfrag kb0 = *(const bfrag*)kp;
    bfrag kb1 = *(const bfrag*)(kp + 16);
    const bf16* qt_bh = qt + (size_t)bh * NN * 32;
    const bf16* aw_bh = awts + (size_t)bh * 64 * NN;

    int qr = tid >> 2, qc = (tid & 3) * 8;
    const bf16* qsb = qt_bh + (size_t)(ms + qr) * 32 + qc;
    int qoff = qr * LDP + qc;
    int ar0 = tid >> 3, acv = (tid & 7) * 8;
    const bf16* asb0 = aw_bh + (size_t)ar0 * NN + ms + acv;
    const bf16* asb1 = aw_bh + (size_t)(ar0 + 32) * NN + ms + acv;
    int aoff0 = ar0 * LDPA + acv;
    int aoff1 = (ar0 + 32) * LDPA + acv;

    *(bfrag*)(&Qb[0][qoff])  = *(const bfrag*)qsb;
    *(bfrag*)(&Ab[0][aoff0]) = *(const bfrag*)asb0;
    *(bfrag*)(&Ab[0][aoff1]) = *(const bfrag*)asb1;
    __syncthreads();

    f32x16 acc0, acc1;
    #pragma unroll
    for (int r = 0; r < 16; ++r) { acc0[r] = 0.f; acc1[r] = 0.f; }

    for (int t = 0; t < 7; ++t) {
        bfrag preQ, preA0, preA1;
        bool hn = (t + 1 < 7);
        if (hn) {
            preQ  = *(const bfrag*)(qsb  + (size_t)(t + 1) * 2048);
            preA0 = *(const bfrag*)(asb0 + (size_t)(t + 1) * 64);
            preA1 = *(const bfrag*)(asb1 + (size_t)(t + 1) * 64);
        }
        const bf16* ql = &Qb[t & 1][0];
        const bf16* al = &Ab[t & 1][0];
        #pragma unroll
        for (int mt2 = 0; mt2 < 2; ++mt2) {
            int qo = (l31 + 32 * mt2) * LDP + lsel * 8;
            bfrag q0 = *(const bfrag*)(ql + qo);
            bfrag q1 = *(const bfrag*)(ql + qo + 16);
            f32x16 s;
            #pragma unroll
            for (int r = 0; r < 16; ++r) s[r] = 0.f;
            s = MFMA32(q0, kb0, s);
            s = MFMA32(q1, kb1, s);
            union { unsigned short us[8]; bfrag v; } pa0, pa1;
            #pragma unroll
            for (int i = 0; i < 8; ++i) {
                bf16 e0 = f2b(fexp2(s[i]));
                bf16 e1 = f2b(fexp2(s[8 + i]));
                pa0.us[i] = *(unsigned short*)&e0;
                pa1.us[i] = *(unsigned short*)&e1;
            }
            const bf16* a0 = al + l31 * LDPA + 32 * mt2 + lsel * 4;
            const bf16* a1 = al + (l31 + 32) * LDPA + 32 * mt2 + lsel * 4;
            union { s16x4 h[2]; bfrag v; } e00, e01, e10, e11;
            e00.h[0] = *(const s16x4*)(a0);
            e00.h[1] = *(const s16x4*)(a0 + 8);
            e01.h[0] = *(const s16x4*)(a0 + 16);
            e01.h[1] = *(const s16x4*)(a0 + 24);
            e10.h[0] = *(const s16x4*)(a1);
            e10.h[1] = *(const s16x4*)(a1 + 8);
            e11.h[0] = *(const s16x4*)(a1 + 16);
            e11.h[1] = *(const s16x4*)(a1 + 24);
            acc0 = MFMA32(pa0.v, e00.v, acc0);
            acc0 = MFMA32(pa1.v, e01.v, acc0);
            acc1 = MFMA32(pa0.v, e10.v, acc1);
            acc1 = MFMA32(pa1.v, e11.v, acc1);
        }
        if (hn) {
            *(bfrag*)(&Qb[(t + 1) & 1][qoff])  = preQ;
            *(bfrag*)(&Ab[(t + 1) & 1][aoff0]) = preA0;
            *(bfrag*)(&Ab[(t + 1) & 1][aoff1]) = preA1;
        }
        __syncthreads();
    }
    if (act) {
        bf16* dst = av2_p + (size_t)blockIdx.y * ((size_t)NBH * NN * 64)
                  + ((size_t)bh * NN + n0) * 64 + l31;
        #pragma unroll
        for (int r = 0; r < 16; ++r) {
            int nl = (r & 3) + 8 * (r >> 2) + 4 * lsel;
            dst[(size_t)nl * 64]      = f2b(acc0[r]);
            dst[(size_t)nl * 64 + 32] = f2b(acc1[r]);
        }
    }
}

// ---------------- reduce1: sum 7 bf16 partials, bn1+relu+rden -> awts bf16 ----------------
__global__ __launch_bounds__(256) void k_red1(const bf16* __restrict__ av_p,
    const float* __restrict__ w1, const float* __restrict__ b1,
    const float* __restrict__ g1, const float* __restrict__ be1,
    const float* __restrict__ rm1, const float* __restrict__ rv1,
    const float* __restrict__ rds,
    bf16* __restrict__ awts)
{
    __shared__ float avl[64 * 33];
    __shared__ float w1l[64 * 33];
    __shared__ float sc[64], sh[64], bb[64];
    int n0 = blockIdx.x * 64, bh = blockIdx.y, h = bh & 3;
    int tid = threadIdx.x;
    const size_t cstride = (size_t)NBH * NN * 32;
    const bf16* ap = av_p + ((size_t)bh * NN + n0) * 32;
    {
        int nr = tid >> 2, e8 = (tid & 3) * 8;
        int base = nr * 32 + e8;
        float s8[8];
        #pragma unroll
        for (int j = 0; j < 8; ++j) s8[j] = 0.f;
        #pragma unroll
        for (int c = 0; c < NCH; ++c) {
            union { bfrag v; unsigned short us[8]; } u;
            u.v = *(const bfrag*)(ap + (size_t)c * cstride + base);
            #pragma unroll
            for (int j = 0; j < 8; ++j) s8[j] += us2f(u.us[j]);
        }
        #pragma unroll
        for (int j = 0; j < 8; ++j) avl[nr * 33 + e8 + j] = s8[j];
    }
    for (int i = tid; i < 2048; i += 256)
        w1l[(i >> 5) * 33 + (i & 31)] = w1[i];
    if (tid < 64) {
        int ch = h * 64 + tid;
        float s = g1[ch] * rsqrtf(rv1[ch] + 1e-5f);
        sc[tid] = s; sh[tid] = be1[ch] - rm1[ch] * s; bb[tid] = b1[tid];
    }
    __syncthreads();
    int nb = (tid & 15) * 4, eb = (tid >> 4) * 4;
    float rsc[4];
    {
        const float* rp = rds + (size_t)bh * NN + n0 + nb;
        rsc[0] = rp[0]; rsc[1] = rp[1]; rsc[2] = rp[2]; rsc[3] = rp[3];
    }
    float s[4][4];
    #pragma unroll
    for (int i = 0; i < 4; ++i)
        #pragma unroll
        for (int j = 0; j < 4; ++j) s[i][j] = bb[eb + j];
    for (int d = 0; d < 32; ++d) {
        float a0 = avl[(nb+0)*33+d], a1 = avl[(nb+1)*33+d], a2 = avl[(nb+2)*33+d], a3 = avl[(nb+3)*33+d];
        float w0 = w1l[(eb+0)*33+d], w1v = w1l[(eb+1)*33+d], w2v = w1l[(eb+2)*33+d], w3 = w1l[(eb+3)*33+d];
        s[0][0]+=a0*w0; s[0][1]+=a0*w1v; s[0][2]+=a0*w2v; s[0][3]+=a0*w3;
        s[1][0]+=a1*w0; s[1][1]+=a1*w1v; s[1][2]+=a1*w2v; s[1][3]+=a1*w3;
        s[2][0]+=a2*w0; s[2][1]+=a2*w1v; s[2][2]+=a2*w2v; s[2][3]+=a2*w3;
        s[3][0]+=a3*w0; s[3][1]+=a3*w1v; s[3][2]+=a3*w2v; s[3][3]+=a3*w3;
    }
    #pragma unroll
    for (int j = 0; j < 4; ++j) {
        int e = eb + j;
        ushort4 pk;
        float v0 = fmaxf(s[0][j] * sc[e] + sh[e], 0.f) * rsc[0];
        float v1 = fmaxf(s[1][j] * sc[e] + sh[e], 0.f) * rsc[1];
        float v2 = fmaxf(s[2][j] * sc[e] + sh[e], 0.f) * rsc[2];
        float v3 = fmaxf(s[3][j] * sc[e] + sh[e], 0.f) * rsc[3];
        bf16 b0 = f2b(v0), b1b = f2b(v1), b2b = f2b(v2), b3 = f2b(v3);
        pk.x = *(unsigned short*)&b0; pk.y = *(unsigned short*)&b1b;
        pk.z = *(unsigned short*)&b2b; pk.w = *(unsigned short*)&b3;
        *reinterpret_cast<ushort4*>(awts + ((size_t)bh * 64 + e) * NN + n0 + nb) = pk;
    }
}

// ---------------- reduce2: sum 7 bf16 partials, bn2+relu -> yt[b][n][256] bf16 ----------------
__global__ __launch_bounds__(256) void k_red2(const bf16* __restrict__ av2_p,
    const float* __restrict__ w2, const float* __restrict__ b2,
    const float* __restrict__ g2, const float* __restrict__ be2,
    const float* __restrict__ rm2, const float* __restrict__ rv2,
    bf16* __restrict__ yt)
{
    __shared__ float a2l[64 * 65];
    __shared__ float w2l[64 * 65];
    __shared__ float sc[64], sh[64], bb[64];
    int n0 = blockIdx.x * 64, bh = blockIdx.y, h = bh & 3, b = bh >> 2;
    int tid = threadIdx.x;
    const size_t cstride = (size_t)NBH * NN * 64;
    const bf16* ap = av2_p + ((size_t)bh * NN + n0) * 64;
    #pragma unroll
    for (int it = 0; it < 2; ++it) {
        int idx = it * 256 + tid;
        int nr = idx >> 3, e8 = (idx & 7) * 8;
        int base = nr * 64 + e8;
        float s8[8];
        #pragma unroll
        for (int j = 0; j < 8; ++j) s8[j] = 0.f;
        #pragma unroll
        for (int c = 0; c < NCH; ++c) {
            union { bfrag v; unsigned short us[8]; } u;
            u.v = *(const bfrag*)(ap + (size_t)c * cstride + base);
            #pragma unroll
            for (int j = 0; j < 8; ++j) s8[j] += us2f(u.us[j]);
        }
        #pragma unroll
        for (int j = 0; j < 8; ++j) a2l[nr * 65 + e8 + j] = s8[j];
    }
    for (int i = tid; i < 4096; i += 256)
        w2l[(i >> 6) * 65 + (i & 63)] = w2[i];
    if (tid < 64) {
        int ch = h * 64 + tid;
        float s = g2[ch] * rsqrtf(rv2[ch] + 1e-5f);
        sc[tid] = s; sh[tid] = be2[ch] - rm2[ch] * s; bb[tid] = b2[tid];
    }
    __syncthreads();
    int nb = (tid & 15) * 4, eb = (tid >> 4) * 4;
    float s[4][4];
    #pragma unroll
    for (int i = 0; i < 4; ++i)
        #pragma unroll
        for (int j = 0; j < 4; ++j) s[i][j] = bb[eb + j];
    for (int d = 0; d < 64; ++d) {
        float a0 = a2l[(nb+0)*65+d], a1 = a2l[(nb+1)*65+d], a2 = a2l[(nb+2)*65+d], a3 = a2l[(nb+3)*65+d];
        float w0 = w2l[(eb+0)*65+d], w1v = w2l[(eb+1)*65+d], w2v = w2l[(eb+2)*65+d], w3 = w2l[(eb+3)*65+d];
        s[0][0]+=a0*w0; s[0][1]+=a0*w1v; s[0][2]+=a0*w2v; s[0][3]+=a0*w3;
        s[1][0]+=a1*w0; s[1][1]+=a1*w1v; s[1][2]+=a1*w2v; s[1][3]+=a1*w3;
        s[2][0]+=a2*w0; s[2][1]+=a2*w1v; s[2][2]+=a2*w2v; s[2][3]+=a2*w3;
        s[3][0]+=a3*w0; s[3][1]+=a3*w1v; s[3][2]+=a3*w2v; s[3][3]+=a3*w3;
    }
    // write transposed: yt[b][n][256ch], 4 ch per ushort4, ch = h*64 + eb + j
    #pragma unroll
    for (int i = 0; i < 4; ++i) {
        ushort4 pk;
        float v0 = fmaxf(s[i][0] * sc[eb+0] + sh[eb+0], 0.f);
        float v1 = fmaxf(s[i][1] * sc[eb+1] + sh[eb+1], 0.f);
        float v2 = fmaxf(s[i][2] * sc[eb+2] + sh[eb+2], 0.f);
        float v3 = fmaxf(s[i][3] * sc[eb+3] + sh[eb+3], 0.f);
        bf16 b0 = f2b(v0), b1b = f2b(v1), b2b = f2b(v2), b3 = f2b(v3);
        pk.x = *(unsigned short*)&b0; pk.y = *(unsigned short*)&b1b;
        pk.z = *(unsigned short*)&b2b; pk.w = *(unsigned short*)&b3;
        *reinterpret_cast<ushort4*>(yt + ((size_t)b * NN + n0 + nb + i) * 256 + h * 64 + eb) = pk;
    }
}

// ---------------- final 1x1 conv via MFMA: out[b,o,n] = wf[o,:] . yt[b,n,:] + bias ----------------
// A = wf rows o (LDS bf16), B = yt rows n (direct global frags), D[row=o][col=n].
__global__ __launch_bounds__(256) void k_finalM(const bf16* __restrict__ yt,
    const float* __restrict__ wf, const float* __restrict__ bf_,
    float* __restrict__ out)
{
    __shared__ __align__(16) bf16 wfb[32 * LDW];
    __shared__ float red[4 * 16 * 64];
    int tid = threadIdx.x, w = tid >> 6, lane = tid & 63;
    int l31 = lane & 31, lsel = lane >> 5;
    int n0 = blockIdx.x * 32;
    int b  = blockIdx.y;
    int o0 = blockIdx.z * 32;

    for (int i = tid; i < 8192; i += 256) {
        int o = i >> 8, k = i & 255;
        wfb[o * LDW + k] = f2b(wf[(size_t)(o0 + o) * 256 + k]);
    }
    __syncthreads();

    const bf16* yb = yt + ((size_t)b * NN + n0 + l31) * 256 + w * 64 + lsel * 8;
    const bf16* wb = &wfb[l31 * LDW + w * 64 + lsel * 8];
    f32x16 s;
    #pragma unroll
    for (int r = 0; r < 16; ++r) s[r] = 0.f;
    #pragma unroll
    for (int kk = 0; kk < 4; ++kk) {
        bfrag a  = *(const bfrag*)(wb + kk * 16);
        bfrag bv = *(const bfrag*)(yb + kk * 16);
        s = MFMA32(a, bv, s);   // D[row=o][col=n=l31]
    }
    float* rp = &red[(w * 16) * 64 + lane];
    #pragma unroll
    for (int r = 0; r < 16; ++r) rp[r * 64] = s[r];
    __syncthreads();

    for (int idx = tid; idx < 1024; idx += 256) {
        int ln = idx & 63, r = idx >> 6;
        float v = red[r * 64 + ln] + red[(16 + r) * 64 + ln]
                + red[(32 + r) * 64 + ln] + red[(48 + r) * 64 + ln];
        int ol = (r & 3) + 8 * (r >> 2) + 4 * (ln >> 5);
        int o = o0 + ol;
        out[((size_t)b * 64 + o) * NN + n0 + (ln & 31)] = v + bf_[o];
    }
}

extern "C" void kernel_launch(void* const* d_in, const int* in_sizes, int n_in,
                              void* d_out, int out_size, void* d_ws, size_t ws_size,
                              hipStream_t stream)
{
    const float* x   = (const float*)d_in[0];
    const float* wk  = (const float*)d_in[1];
    const float* bk  = (const float*)d_in[2];
    const float* wq  = (const float*)d_in[3];
    const float* bq  = (const float*)d_in[4];
    const float* wv  = (const float*)d_in[5];
    const float* bv  = (const float*)d_in[6];
    const float* w1  = (const float*)d_in[7];
    const float* b1  = (const float*)d_in[8];
    const float* g1  = (const float*)d_in[9];
    const float* be1 = (const float*)d_in[10];
    const float* rm1 = (const float*)d_in[11];
    const float* rv1 = (const float*)d_in[12];
    const float* w2  = (const float*)d_in[13];
    const float* b2  = (const float*)d_in[14];
    const float* g2  = (const float*)d_in[15];
    const float* be2 = (const float*)d_in[16];
    const float* rm2 = (const float*)d_in[17];
    const float* rv2 = (const float*)d_in[18];
    const float* wf  = (const float*)d_in[19];
    const float* bff = (const float*)d_in[20];
    float* out = (float*)d_out;

    char* ws = (char*)d_ws;
    bf16* kt   = (bf16*)ws;
    bf16* qt   = kt + (size_t)NBH * NN * 32;
    bf16* vt   = qt + (size_t)NBH * NN * 32;
    bf16* awts = vt + (size_t)NBH * 32 * NN;
    bf16* yt   = awts + (size_t)NBH * 64 * NN;
    float* den = (float*)(yt + (size_t)2 * NN * 256);
    bf16* av_p  = (bf16*)(den + (size_t)NBH * NN);
    bf16* av2_p = av_p + (size_t)NCH * NBH * NN * 32;

    k_zero  <<<dim3(25),       256, 0, stream>>>(den, 6272);
    k_proj  <<<dim3(98, 3, 2), 256, 0, stream>>>(x, wk, bk, wq, bq, wv, bv, kt, qt, vt);
    k_stats <<<dim3(25, 7, 8), 256, 0, stream>>>(kt, qt, den);
    k_recip <<<dim3(98),       256, 0, stream>>>(den);
    k_scalev<<<dim3(2, 256),   256, 0, stream>>>(vt, den);
    k_av    <<<dim3(25, 7, 8), 256, 0, stream>>>(kt, qt, vt, av_p);
    k_red1  <<<dim3(49, 8),    256, 0, stream>>>(av_p, w1, b1, g1, be1, rm1, rv1, den, awts);
    k_av2   <<<dim3(25, 7, 8), 256, 0, stream>>>(kt, qt, awts, av2_p);
    k_red2  <<<dim3(49, 8),    256, 0, stream>>>(av2_p, w2, b2, g2, be2, rm2, rv2, yt);
    k_finalM<<<dim3(98, 2, 2), 256, 0, stream>>>(yt, wf, bff, out);
}